// Round 3
// baseline (153.957 us; speedup 1.0000x reference)
//
#include <hip/hip_runtime.h>
#include <stdint.h>

#define SC 192      // coarse samples (128 + 64)
#define SF 128      // fine (importance) samples
#define NT 192      // threads per block = 3 waves (1 coarse sample/thread)
#define PACK_NT 128

// LDS weight-image offsets (floats)
#define WD1   0     // 96  (3x32 row-major)
#define BD1   96    // 32
#define WD2   128   // 32
#define BD2   160   // 1
#define BC2   161   // 3
#define NV4   164   // 32 x float4: (bc1[n], Wc1[32][n], Wc1[33][n], Wc1[34][n])
#define SWS   292   // staged floats (73 float4s)

#define KINV  296   // ws float offset: 9 floats, row-major inv(K)
#define WS_FRAG_OFF  2048   // byte offset of Wc1 fp16 A-frags in d_ws (2048 B)
#define WS_FRAG2_OFF 4096   // byte offset of Wc2 fp16 A-frag (1024 B)
#define WS_NEED      6144

#define HSTRIDE 40  // ushort stride for H rows (80 B rows -> bank-friendly)
#define RGBS 4

using half8 = __attribute__((ext_vector_type(8))) _Float16;
using f32x4 = __attribute__((ext_vector_type(4))) float;
using f32x2 = __attribute__((ext_vector_type(2))) float;

#define LO2(v) __builtin_shufflevector(v, v, 0, 1)
#define HI2(v) __builtin_shufflevector(v, v, 2, 3)

__device__ __forceinline__ float zlog_c(int t) {
  return (t < 128) ? (-1.0f + (float)t * 0.0078125f)
                   : ((float)(t - 128) * 0.015625f);
}
__device__ __forceinline__ float delta_c(int t) {
  if (t >= SC - 1) return 0.0f;
  return zlog_c(t + 1) - zlog_c(t);
}

__device__ __forceinline__ float fast_rcp(float x) { return __builtin_amdgcn_rcpf(x); }
__device__ __forceinline__ float fast_rsq(float x) { return __builtin_amdgcn_rsqf(x); }
__device__ __forceinline__ float exp10_f(float x) { return __expf(x * 2.30258509299f); }
__device__ __forceinline__ float softplus_f(float x) {
  return fmaxf(x, 0.0f) + __logf(1.0f + __expf(-fabsf(x)));
}

// v_pk_fma_f32: 2x fp32 FMA in one VOP3P instruction (identical fma rounding)
__device__ __forceinline__ f32x2 pk_fma(f32x2 a, f32x2 b, f32x2 c) {
  f32x2 d;
  asm("v_pk_fma_f32 %0, %1, %2, %3" : "=v"(d) : "v"(a), "v"(b), "v"(c));
  return d;
}

// fp16 helpers: pk2h = 1 HW instr (v_cvt_pkrtz_f16_f32); f2h = RTN scalar convert
__device__ __forceinline__ uint32_t pk2h(float a, float b) {
  auto p = __builtin_amdgcn_cvt_pkrtz(a, b);
  uint32_t u; __builtin_memcpy(&u, &p, 4); return u;
}
__device__ __forceinline__ unsigned short f2h(float f) {
  _Float16 h = (_Float16)f;
  unsigned short us; __builtin_memcpy(&us, &h, 2); return us;
}

__device__ __forceinline__ float4 ldsf4(const float* p) { return *(const float4*)p; }
__device__ __forceinline__ f32x4 ldsv4(const float* p) { return *(const f32x4*)p; }

// ---- DPP cross-lane (VALU pipe, no LDS): gfx9 row_shr / row_bcast sequence ----
template <int CTRL, int RMASK, int BMASK>
__device__ __forceinline__ float dpp_mov(float x, float oldv) {
  return __int_as_float(__builtin_amdgcn_update_dpp(
      __float_as_int(oldv), __float_as_int(x), CTRL, RMASK, BMASK, false));
}
__device__ __forceinline__ float dpp_scan_add(float v) {
  v += dpp_mov<0x111, 0xf, 0xf>(v, 0.0f);   // row_shr:1
  v += dpp_mov<0x112, 0xf, 0xf>(v, 0.0f);   // row_shr:2
  v += dpp_mov<0x114, 0xf, 0xf>(v, 0.0f);   // row_shr:4
  v += dpp_mov<0x118, 0xf, 0xf>(v, 0.0f);   // row_shr:8
  v += dpp_mov<0x142, 0xa, 0xf>(v, 0.0f);   // row_bcast:15 -> rows 1,3
  v += dpp_mov<0x143, 0xc, 0xf>(v, 0.0f);   // row_bcast:31 -> rows 2,3
  return v;
}
__device__ __forceinline__ float dpp_scan_mul(float v) {
  v *= dpp_mov<0x111, 0xf, 0xf>(v, 1.0f);
  v *= dpp_mov<0x112, 0xf, 0xf>(v, 1.0f);
  v *= dpp_mov<0x114, 0xf, 0xf>(v, 1.0f);
  v *= dpp_mov<0x118, 0xf, 0xf>(v, 1.0f);
  v *= dpp_mov<0x142, 0xa, 0xf>(v, 1.0f);
  v *= dpp_mov<0x143, 0xc, 0xf>(v, 1.0f);
  return v;
}

// JAX threefry2x32 with key = (0, 42)
__device__ __forceinline__ void threefry2x32_k42(uint32_t& x0, uint32_t& x1) {
  const uint32_t ks0 = 0u, ks1 = 42u;
  const uint32_t ks2 = ks0 ^ ks1 ^ 0x1BD11BDAu;
  const uint32_t ks[3] = {ks0, ks1, ks2};
  const int rot[2][4] = {{13, 15, 26, 6}, {17, 29, 16, 24}};
  x0 += ks[0];
  x1 += ks[1];
#pragma unroll
  for (int i = 0; i < 5; ++i) {
#pragma unroll
    for (int j = 0; j < 4; ++j) {
      x0 += x1;
      const int r = rot[i & 1][j];
      x1 = (x1 << r) | (x1 >> (32 - r));
      x1 ^= x0;
    }
    x0 += ks[(i + 1) % 3];
    x1 += ks[(i + 2) % 3] + (uint32_t)(i + 1);
  }
}

// ---- pre-pack kernel: weight image + K-inverse + fp16 A-frags ----
__global__ __launch_bounds__(PACK_NT) void pack_weights(
    const float* __restrict__ K,
    const float* __restrict__ Wd1, const float* __restrict__ bd1,
    const float* __restrict__ Wd2, const float* __restrict__ bd2,
    const float* __restrict__ Wc1, const float* __restrict__ bc1,
    const float* __restrict__ Wc2, const float* __restrict__ bc2,
    float* __restrict__ wsf) {
  const int t = threadIdx.x;
  for (int i = t; i < 96; i += PACK_NT) wsf[WD1 + i] = Wd1[i];
  for (int i = t; i < 32; i += PACK_NT) { wsf[BD1 + i] = bd1[i]; wsf[WD2 + i] = Wd2[i]; }
  if (t == 0) {
    wsf[BD2] = bd2[0];
    wsf[BC2 + 0] = bc2[0]; wsf[BC2 + 1] = bc2[1]; wsf[BC2 + 2] = bc2[2];
    // K-inverse (ray-independent)
    const float k00 = K[0], k01 = K[1], k02 = K[2];
    const float k10 = K[3], k11 = K[4], k12 = K[5];
    const float k20 = K[6], k21 = K[7], k22 = K[8];
    const float det = k00 * (k11 * k22 - k12 * k21)
                    - k01 * (k10 * k22 - k12 * k20)
                    + k02 * (k10 * k21 - k11 * k20);
    const float id = 1.0f / det;
    wsf[KINV + 0] =  (k11 * k22 - k12 * k21) * id;
    wsf[KINV + 1] = -(k01 * k22 - k02 * k21) * id;
    wsf[KINV + 2] =  (k01 * k12 - k02 * k11) * id;
    wsf[KINV + 3] = -(k10 * k22 - k12 * k20) * id;
    wsf[KINV + 4] =  (k00 * k22 - k02 * k20) * id;
    wsf[KINV + 5] = -(k00 * k12 - k02 * k10) * id;
    wsf[KINV + 6] =  (k10 * k21 - k11 * k20) * id;
    wsf[KINV + 7] = -(k00 * k21 - k01 * k20) * id;
    wsf[KINV + 8] =  (k00 * k11 - k01 * k10) * id;
  }
  if (t < 32) {
    wsf[NV4 + t * 4 + 0] = bc1[t];
    wsf[NV4 + t * 4 + 1] = Wc1[32 * 32 + t];
    wsf[NV4 + t * 4 + 2] = Wc1[33 * 32 + t];
    wsf[NV4 + t * 4 + 3] = Wc1[34 * 32 + t];
  }
  // Wc1[0:32][:] fp16 A-frags: frag[lane*2 + nt]; A[m=n][k], lane: n=nt*16+(lane&15), k=quad*8+j
  if (t < 64) {
    const int q_s = t >> 4;
    uint4* frag = (uint4*)((char*)wsf + WS_FRAG_OFF);
#pragma unroll
    for (int nt = 0; nt < 2; ++nt) {
      const int n_s = nt * 16 + (t & 15);
      uint32_t hw[4];
#pragma unroll
      for (int j2 = 0; j2 < 4; ++j2) {
        const int k = q_s * 8 + j2 * 2;
        hw[j2] = (uint32_t)f2h(Wc1[k * 32 + n_s])
               | ((uint32_t)f2h(Wc1[(k + 1) * 32 + n_s]) << 16);
      }
      frag[t * 2 + nt] = make_uint4(hw[0], hw[1], hw[2], hw[3]);
    }
    // Wc2 A-frag for layer-2 MFMA, k-permuted to match layer-1 C layout:
    // position k = q*8+j holds hidden h = (j<4 ? q*4+j : 16+q*4+(j-4)); rows m>=3 are 0
    {
      const int m = t & 15, q = t >> 4;
      uint32_t hw2[4];
#pragma unroll
      for (int jp = 0; jp < 4; ++jp) {
        const int j0 = jp * 2, j1 = j0 + 1;
        const int ha = (j0 < 4) ? q * 4 + j0 : 16 + q * 4 + (j0 - 4);
        const int hb = (j1 < 4) ? q * 4 + j1 : 16 + q * 4 + (j1 - 4);
        const float va = (m < 3) ? Wc2[ha * 3 + m] : 0.0f;
        const float vb = (m < 3) ? Wc2[hb * 3 + m] : 0.0f;
        hw2[jp] = (uint32_t)f2h(va) | ((uint32_t)f2h(vb) << 16);
      }
      ((uint4*)((char*)wsf + WS_FRAG2_OFF))[t] = make_uint4(hw2[0], hw2[1], hw2[2], hw2[3]);
    }
  }
}

template <bool USE_WS>
__global__ __launch_bounds__(NT, 7) void nerf_fwd(
    const float* __restrict__ hh, const float* __restrict__ ww,
    const float* __restrict__ K, const float* __restrict__ E,
    const float* __restrict__ bg,
    const float* __restrict__ Wd1, const float* __restrict__ bd1,
    const float* __restrict__ Wd2, const float* __restrict__ bd2,
    const float* __restrict__ Wc1, const float* __restrict__ bc1,
    const float* __restrict__ Wc2, const float* __restrict__ bc2,
    const float* __restrict__ wsf,
    float* __restrict__ out, int n_rays) {
  const int ray = blockIdx.x;
  const int t = threadIdx.x;   // 0..191 — one coarse sample per thread
  const int lane = t & 63;
  const int wv = t >> 6;       // 0,1,2 — wave w owns coarse segment w
  const int quad = lane >> 4;

  __shared__ __align__(16) float sw[SWS];
  // phase-union: coarse {s_w, s_cdf} then fine H (fp16)
  __shared__ __align__(16) unsigned char u_buf[SF * HSTRIDE * 2];  // 10240 B
  float* const s_w   = (float*)u_buf;                 // 192 floats
  float* const s_cdf = (float*)(u_buf + 768);         // 192 floats
  unsigned short* const s_hf = (unsigned short*)u_buf;
  __shared__ float s_rgb[SF * RGBS];
  __shared__ float s_zlf[SF];
  __shared__ float s_tot[8];
  __shared__ float s_red[16];

  // ---- stage weight image into LDS ----
  if constexpr (USE_WS) {
    const float4* wsrc = (const float4*)wsf;
    float4* sdst = (float4*)sw;
    for (int i = t; i < SWS / 4; i += NT) sdst[i] = wsrc[i];
  } else {
    for (int i = t; i < 96; i += NT) sw[WD1 + i] = Wd1[i];
    for (int i = t; i < 32; i += NT) { sw[BD1 + i] = bd1[i]; sw[WD2 + i] = Wd2[i]; }
    if (t == 0) {
      sw[BD2] = bd2[0];
      sw[BC2 + 0] = bc2[0]; sw[BC2 + 1] = bc2[1]; sw[BC2 + 2] = bc2[2];
    }
    if (t < 32) {
      sw[NV4 + t * 4 + 0] = bc1[t];
      sw[NV4 + t * 4 + 1] = Wc1[32 * 32 + t];
      sw[NV4 + t * 4 + 2] = Wc1[33 * 32 + t];
      sw[NV4 + t * 4 + 3] = Wc1[34 * 32 + t];
    }
  }

  // ---- ray setup (block-uniform) ----
  float i00, i01, i02, i10, i11, i12, i20, i21, i22;
  if constexpr (USE_WS) {
    i00 = wsf[KINV + 0]; i01 = wsf[KINV + 1]; i02 = wsf[KINV + 2];
    i10 = wsf[KINV + 3]; i11 = wsf[KINV + 4]; i12 = wsf[KINV + 5];
    i20 = wsf[KINV + 6]; i21 = wsf[KINV + 7]; i22 = wsf[KINV + 8];
  } else {
    const float k00 = K[0], k01 = K[1], k02 = K[2];
    const float k10 = K[3], k11 = K[4], k12 = K[5];
    const float k20 = K[6], k21 = K[7], k22 = K[8];
    const float det = k00 * (k11 * k22 - k12 * k21)
                    - k01 * (k10 * k22 - k12 * k20)
                    + k02 * (k10 * k21 - k11 * k20);
    const float id = 1.0f / det;
    i00 =  (k11 * k22 - k12 * k21) * id;
    i01 = -(k01 * k22 - k02 * k21) * id;
    i02 =  (k01 * k12 - k02 * k11) * id;
    i10 = -(k10 * k22 - k12 * k20) * id;
    i11 =  (k00 * k22 - k02 * k20) * id;
    i12 = -(k00 * k12 - k02 * k10) * id;
    i20 =  (k10 * k21 - k11 * k20) * id;
    i21 = -(k00 * k21 - k01 * k20) * id;
    i22 =  (k00 * k11 - k01 * k10) * id;
  }

  const float dwx = ww[ray] + 0.5f;
  const float dwy = hh[ray] + 0.5f;
  const float cx = i00 * dwx + i01 * dwy + i02;
  const float cy = i10 * dwx + i11 * dwy + i12;
  const float cz = i20 * dwx + i21 * dwy + i22;
  const float* Er = E + (size_t)ray * 16;
  const float ox = Er[3], oy = Er[7], oz = Er[11];
  const float dx = Er[0] * cx + Er[1] * cy + Er[2] * cz;
  const float dy = Er[4] * cx + Er[5] * cy + Er[6] * cz;
  const float dz = Er[8] * cx + Er[9] * cy + Er[10] * cz;
  const float inv_nrm = fast_rsq(dx * dx + dy * dy + dz * dz);
  const float ndx = dx * inv_nrm, ndy = dy * inv_nrm, ndz = dz * inv_nrm;

  __syncthreads();   // weights staged

  // ---- coarse pass: exactly ONE sample per thread (balanced across 3 waves) ----
  const float bd2v = sw[BD2];
  float v0;
  {
    const float z = exp10_f(zlog_c(t));
    float px = ox + dx * z, py = oy + dy * z, pz = oz + dz * z;
    const float d2 = px * px + py * py + pz * pz;
    if (d2 > 1.0f) {
      const float invd = fast_rsq(d2);
      const float sc = (2.0f - invd) * invd;
      px *= sc; py *= sc; pz *= sc;
    }
    const f32x2 pxp = {px, px}, pyp = {py, py}, pzp = {pz, pz};
    f32x2 aP = {bd2v, 0.0f};
#pragma unroll
    for (int c = 0; c < 8; ++c) {
      const int k4 = c * 4;
      const f32x4 w0 = ldsv4(sw + WD1 + k4);
      const f32x4 w1 = ldsv4(sw + WD1 + 32 + k4);
      const f32x4 w2 = ldsv4(sw + WD1 + 64 + k4);
      const f32x4 b  = ldsv4(sw + BD1 + k4);
      const f32x4 wd = ldsv4(sw + WD2 + k4);
      f32x2 v, h;
      v = pk_fma(pzp, LO2(w2), pk_fma(pyp, LO2(w1), pk_fma(pxp, LO2(w0), LO2(b))));
      h.x = fmaxf(v.x, 0.0f); h.y = fmaxf(v.y, 0.0f);
      aP = pk_fma(h, LO2(wd), aP);
      v = pk_fma(pzp, HI2(w2), pk_fma(pyp, HI2(w1), pk_fma(pxp, HI2(w0), HI2(b))));
      h.x = fmaxf(v.x, 0.0f); h.y = fmaxf(v.y, 0.0f);
      aP = pk_fma(h, HI2(wd), aP);
    }
    v0 = __expf(-softplus_f(aP.x + aP.y) * delta_c(t));
  }

  // parallel cumprod of (1-alpha): 3 concurrent wave-scans
  float i0 = dpp_scan_mul(v0);
  if (lane == 63) s_tot[wv] = i0;
  __syncthreads();
  {
    const float pre = (wv == 0) ? 1.0f
                    : ((wv == 1) ? s_tot[0] : s_tot[0] * s_tot[1]);
    // a * exclusive = (1-v)/v * inclusive = (rcp(v)-1) * inclusive
    s_w[t] = (fast_rcp(v0) - 1.0f) * i0 * pre;
  }
  __syncthreads();

  // reweight (one element per thread)
  float wre;
  {
    const float wm = (t > 0) ? s_w[t - 1] : 0.0f;
    const float w0 = s_w[t];
    const float wp = (t < SC - 1) ? s_w[t + 1] : 0.0f;
    wre = 0.5f * (fmaxf(wm, w0) + fmaxf(w0, wp)) + (0.02f / 192.0f);
    wre *= (t < 128) ? (128.0f / 192.0f) : (64.0f / 192.0f);
  }

  // parallel cumsum -> normalized CDF: 3 concurrent wave-scans
  float s0 = dpp_scan_add(wre);
  if (lane == 63) s_tot[4 + wv] = s0;
  __syncthreads();
  {
    const float T0 = s_tot[4], T1 = s_tot[5], T2 = s_tot[6];
    const float inv_total = fast_rcp(T0 + T1 + T2);
    const float pre = (wv == 0) ? 0.0f : ((wv == 1) ? T0 : T0 + T1);
    s_cdf[t] = (s0 + pre) * inv_total;
  }
  __syncthreads();

  // ---- importance sampling (fine samples: threads 0..127; wave 2 skips) ----
  float zlf = 0.0f, zf = 0.0f;
  if (t < SF) {
    // 24-ary round-1 probes at FIXED indices: issued before threefry so their
    // LDS latency hides under ~100 VALU cycles of RNG compute.
    float cA[7];
#pragma unroll
    for (int i = 0; i < 7; ++i) cA[i] = s_cdf[24 * i + 24];   // value at m = 24i+23

    const uint32_t total = (uint32_t)n_rays * 128u;
    const uint32_t halfc = total >> 1;
    const uint32_t j = (uint32_t)ray * 128u + (uint32_t)t;
    uint32_t x0, x1;
    const bool first = (j < halfc);
    if (first) { x0 = j; x1 = j + halfc; } else { x0 = j - halfc; x1 = j; }
    threefry2x32_k42(x0, x1);
    const uint32_t bits = first ? x0 : x1;
    const float fr = __uint_as_float((bits >> 9) | 0x3f800000u) - 1.0f;

    float u = (float)t * 0.0078125f + fr * 0.0078125f;
    u = u * (s_cdf[190] - s_cdf[1]) + s_cdf[1];

    // searchsorted(right) over s_cdf[1..189]: lo = #{m in [0,189] : s_cdf[1+m] <= u}
    int start = 0;
#pragma unroll
    for (int i = 0; i < 7; ++i) start += (cA[i] <= u) ? 24 : 0;
    // round 2: 3-ary within the 24-block (probes at m = start+3i+2)
    float cB[7];
#pragma unroll
    for (int i = 0; i < 7; ++i) cB[i] = s_cdf[start + 3 * i + 3];
    int st2 = start;
#pragma unroll
    for (int i = 0; i < 7; ++i) st2 += (cB[i] <= u) ? 3 : 0;
    // round 3: neighborhood fetch (all independent) + cndmask select of cb/ca
    const float p0 = s_cdf[st2];
    const float p1 = s_cdf[st2 + 1];
    const float p2 = s_cdf[st2 + 2];
    const float p3 = s_cdf[st2 + 3];
    const int k = ((p1 <= u) ? 1 : 0) + ((p2 <= u) ? 1 : 0);
    const int lo = st2 + k;
    const int inds = lo + 1;
    const float cb = (k == 0) ? p0 : ((k == 1) ? p1 : p2);
    const float ca = (k == 0) ? p1 : ((k == 1) ? p2 : p3);
    const float tt = (u - cb) * fast_rcp(ca - cb);
    const float zb = 0.5f * (zlog_c(inds - 1) + zlog_c(inds));
    const float za = 0.5f * (zlog_c(inds) + zlog_c(inds + 1));
    zlf = zb + (za - zb) * tt;
    s_zlf[t] = zlf;
    zf = exp10_f(zlf);
  }
  __syncthreads();   // last s_cdf read — union area now free for s_hf

  // ---- Wc1 + Wc2 A-frags (fp16) — all 3 waves (wave 2 needs them for color) ----
  half8 Whi0, Whi1, W2f;
  if constexpr (USE_WS) {
    const uint4* frag = (const uint4*)((const char*)wsf + WS_FRAG_OFF);
    uint4 q0 = frag[lane * 2 + 0];
    uint4 q1 = frag[lane * 2 + 1];
    uint4 q2 = ((const uint4*)((const char*)wsf + WS_FRAG2_OFF))[lane];
    __builtin_memcpy(&Whi0, &q0, 16);
    __builtin_memcpy(&Whi1, &q1, 16);
    __builtin_memcpy(&W2f, &q2, 16);
  } else {
#pragma unroll
    for (int nt = 0; nt < 2; ++nt) {
      const int n_s = nt * 16 + (lane & 15);
      uint32_t hw[4];
#pragma unroll
      for (int j2 = 0; j2 < 4; ++j2) {
        const int k = quad * 8 + j2 * 2;
        hw[j2] = (uint32_t)f2h(Wc1[k * 32 + n_s])
               | ((uint32_t)f2h(Wc1[(k + 1) * 32 + n_s]) << 16);
      }
      uint4 q = make_uint4(hw[0], hw[1], hw[2], hw[3]);
      if (nt == 0) __builtin_memcpy(&Whi0, &q, 16);
      else         __builtin_memcpy(&Whi1, &q, 16);
    }
    {
      const int m = lane & 15;
      uint32_t hw2[4];
#pragma unroll
      for (int jp = 0; jp < 4; ++jp) {
        const int j0 = jp * 2, j1 = j0 + 1;
        const int ha = (j0 < 4) ? quad * 4 + j0 : 16 + quad * 4 + (j0 - 4);
        const int hb = (j1 < 4) ? quad * 4 + j1 : 16 + quad * 4 + (j1 - 4);
        const float va = (m < 3) ? Wc2[ha * 3 + m] : 0.0f;
        const float vb = (m < 3) ? Wc2[hb * 3 + m] : 0.0f;
        hw2[jp] = (uint32_t)f2h(va) | ((uint32_t)f2h(vb) << 16);
      }
      uint4 q2 = make_uint4(hw2[0], hw2[1], hw2[2], hw2[3]);
      __builtin_memcpy(&W2f, &q2, 16);
    }
  }

  // ---- fine density (threads 0..127); h -> LDS as fp16 (HW pack) ----
  float sigf = 0.0f;
  if (t < SF) {
    float px = ox + dx * zf, py = oy + dy * zf, pz = oz + dz * zf;
    const float d2 = px * px + py * py + pz * pz;
    if (d2 > 1.0f) {
      const float invd = fast_rsq(d2);
      const float sc = (2.0f - invd) * invd;
      px *= sc; py *= sc; pz *= sc;
    }
    const f32x2 pxp = {px, px}, pyp = {py, py}, pzp = {pz, pz};
    f32x2 sP = {bd2v, 0.0f};
    uint4 tmp;
#pragma unroll
    for (int c = 0; c < 8; ++c) {
      const int k4 = c * 4;
      const f32x4 w0 = ldsv4(sw + WD1 + k4);
      const f32x4 w1 = ldsv4(sw + WD1 + 32 + k4);
      const f32x4 w2 = ldsv4(sw + WD1 + 64 + k4);
      const f32x4 b  = ldsv4(sw + BD1 + k4);
      const f32x4 wd = ldsv4(sw + WD2 + k4);
      f32x2 v, hlo, hhi;
      v = pk_fma(pzp, LO2(w2), pk_fma(pyp, LO2(w1), pk_fma(pxp, LO2(w0), LO2(b))));
      hlo.x = fmaxf(v.x, 0.0f); hlo.y = fmaxf(v.y, 0.0f);
      sP = pk_fma(hlo, LO2(wd), sP);
      v = pk_fma(pzp, HI2(w2), pk_fma(pyp, HI2(w1), pk_fma(pxp, HI2(w0), HI2(b))));
      hhi.x = fmaxf(v.x, 0.0f); hhi.y = fmaxf(v.y, 0.0f);
      sP = pk_fma(hhi, HI2(wd), sP);
      const uint32_t pA = pk2h(hlo.x, hlo.y), pB = pk2h(hhi.x, hhi.y);
      if ((c & 1) == 0) { tmp.x = pA; tmp.y = pB; }
      else {
        tmp.z = pA; tmp.w = pB;
        *(uint4*)(s_hf + t * HSTRIDE + (c >> 1) * 8) = tmp;
      }
    }
    sigf = softplus_f(sP.x + sP.y);
  }
  __syncthreads();   // h staged for MFMA

  // ---- fine color via MFMA chain; 8 row-tiles distributed 3/3/2 over waves ----
  {
    // per-lane dv values (block-uniform per hidden unit) -> layer-1 acc init
    float dvv[2][4];
#pragma unroll
    for (int nt = 0; nt < 2; ++nt)
#pragma unroll
      for (int r = 0; r < 4; ++r) {
        const int n = nt * 16 + quad * 4 + r;
        const float4 nv = ldsf4(sw + NV4 + n * 4);
        dvv[nt][r] = nv.x + ndx * nv.y + ndy * nv.z + ndz * nv.w;
      }
    // layer-2 acc init: bias bc2 on quad0 rows 0..2
    f32x4 c2init;
    {
      const float b0 = sw[BC2 + 0], b1 = sw[BC2 + 1], b2 = sw[BC2 + 2];
      const bool q0 = (quad == 0);
      c2init[0] = q0 ? b0 : 0.0f;
      c2init[1] = q0 ? b1 : 0.0f;
      c2init[2] = q0 ? b2 : 0.0f;
      c2init[3] = 0.0f;
    }

#pragma unroll
    for (int kk = 0; kk < 3; ++kk) {
      const int tile = wv + kk * 3;   // wave-uniform
      if (tile < 8) {
        const int sbase = tile * 16;
        const int srow = sbase + (lane & 15);
        const half8 Hf = *(const half8*)(s_hf + srow * HSTRIDE + quad * 8);

        f32x4 acc0 = {dvv[0][0], dvv[0][1], dvv[0][2], dvv[0][3]};
        f32x4 acc1 = {dvv[1][0], dvv[1][1], dvv[1][2], dvv[1][3]};
        acc0 = __builtin_amdgcn_mfma_f32_16x16x32_f16(Whi0, Hf, acc0, 0, 0, 0);
        acc1 = __builtin_amdgcn_mfma_f32_16x16x32_f16(Whi1, Hf, acc1, 0, 0, 0);

        // relu + fp16 pack -> B-frag for layer-2 (k-permutation matches W2f)
        const uint32_t b20 = pk2h(fmaxf(acc0[0], 0.0f), fmaxf(acc0[1], 0.0f));
        const uint32_t b21 = pk2h(fmaxf(acc0[2], 0.0f), fmaxf(acc0[3], 0.0f));
        const uint32_t b22 = pk2h(fmaxf(acc1[0], 0.0f), fmaxf(acc1[1], 0.0f));
        const uint32_t b23 = pk2h(fmaxf(acc1[2], 0.0f), fmaxf(acc1[3], 0.0f));
        const uint4 qq = make_uint4(b20, b21, b22, b23);
        half8 B2; __builtin_memcpy(&B2, &qq, 16);

        f32x4 aC = c2init;
        aC = __builtin_amdgcn_mfma_f32_16x16x32_f16(W2f, B2, aC, 0, 0, 0);

        // quad0 lanes hold rgb rows 0..2 for sample sbase+(lane&15)
        if (quad == 0) {
          const int s = sbase + (lane & 15);
          float4 og;
          og.x = fast_rcp(1.0f + __expf(-aC[0]));
          og.y = fast_rcp(1.0f + __expf(-aC[1]));
          og.z = fast_rcp(1.0f + __expf(-aC[2]));
          og.w = 0.0f;
          *(float4*)(s_rgb + s * RGBS) = og;
        }
      }
    }
  }

  // ---- fine alpha + parallel cumprod over 128 (waves 0,1; DPP scan) ----
  float vf = 1.0f, fi = 1.0f;
  if (t < SF) {
    const float deltaf = (t < SF - 1) ? (s_zlf[t + 1] - zlf) : 0.0f;
    vf = __expf(-sigf * deltaf);
    fi = dpp_scan_mul(vf);
    if (lane == 63) s_tot[wv] = fi;
  }
  __syncthreads();   // also makes s_rgb visible

  if (t < SF) {
    const float wf = (fast_rcp(vf) - 1.0f) * fi * (wv ? s_tot[0] : 1.0f);

    // ---- outputs ----
    float* o_w   = out + (size_t)n_rays * 3;
    float* o_z   = out + (size_t)n_rays * (3 + 128);

    o_w[(size_t)ray * 128 + t] = wf;
    o_z[(size_t)ray * 128 + t] = (zlf + 1.0f) * 0.5f;

    float r0 = wf * s_rgb[t * RGBS + 0];
    float r1 = wf * s_rgb[t * RGBS + 1];
    float r2 = wf * s_rgb[t * RGBS + 2];
    float r3 = wf, r4 = wf * fast_rcp(zf);
    // DPP scan-based reduce: lane 63 holds the wave total
    r0 = dpp_scan_add(r0);
    r1 = dpp_scan_add(r1);
    r2 = dpp_scan_add(r2);
    r3 = dpp_scan_add(r3);
    r4 = dpp_scan_add(r4);
    if (lane == 63) {
      float* p = &s_red[wv * 5];
      p[0] = r0; p[1] = r1; p[2] = r2; p[3] = r3; p[4] = r4;
    }
  }
  __syncthreads();
  if (t == 0) {
    float* o_img = out;
    float* o_inv = out + (size_t)n_rays * (3 + 256);
    const float accw = s_red[3] + s_red[8];
    const float bgw = 1.0f - accw;
    o_img[(size_t)ray * 3 + 0] = (s_red[0] + s_red[5]) + bgw * bg[0];
    o_img[(size_t)ray * 3 + 1] = (s_red[1] + s_red[6]) + bgw * bg[1];
    o_img[(size_t)ray * 3 + 2] = (s_red[2] + s_red[7]) + bgw * bg[2];
    o_inv[ray] = s_red[4] + s_red[9];
  }
}

extern "C" void kernel_launch(void* const* d_in, const int* in_sizes, int n_in,
                              void* d_out, int out_size, void* d_ws, size_t ws_size,
                              hipStream_t stream) {
  const float* h   = (const float*)d_in[1];
  const float* w   = (const float*)d_in[2];
  const float* K   = (const float*)d_in[3];
  const float* E   = (const float*)d_in[4];
  const float* bg  = (const float*)d_in[5];
  const float* Wd1 = (const float*)d_in[6];
  const float* bd1 = (const float*)d_in[7];
  const float* Wd2 = (const float*)d_in[8];
  const float* bd2 = (const float*)d_in[9];
  const float* Wc1 = (const float*)d_in[10];
  const float* bc1 = (const float*)d_in[11];
  const float* Wc2 = (const float*)d_in[12];
  const float* bc2 = (const float*)d_in[13];
  const int n_rays = in_sizes[1];
  float* wsf = (float*)d_ws;

  if (ws_size >= WS_NEED) {
    pack_weights<<<1, PACK_NT, 0, stream>>>(K, Wd1, bd1, Wd2, bd2, Wc1, bc1, Wc2, bc2, wsf);
    nerf_fwd<true><<<n_rays, NT, 0, stream>>>(h, w, K, E, bg, Wd1, bd1, Wd2, bd2,
                                              Wc1, bc1, Wc2, bc2, wsf,
                                              (float*)d_out, n_rays);
  } else {
    nerf_fwd<false><<<n_rays, NT, 0, stream>>>(h, w, K, E, bg, Wd1, bd1, Wd2, bd2,
                                               Wc1, bc1, Wc2, bc2, nullptr,
                                               (float*)d_out, n_rays);
  }
}

// Round 4
// 148.498 us; speedup vs baseline: 1.0368x; 1.0368x over previous
//
#include <hip/hip_runtime.h>
#include <stdint.h>

#define SC 192      // coarse samples (128 + 64)
#define SF 128      // fine (importance) samples
#define NT 128      // threads per block = 2 waves
#define PACK_NT 128

// LDS weight-image offsets (floats)
#define WD1   0     // 96  (3x32 row-major)
#define BD1   96    // 32
#define WD2   128   // 32
#define BD2   160   // 1
#define BC2   161   // 3
#define NV4   164   // 32 x float4: (bc1[n], Wc1[32][n], Wc1[33][n], Wc1[34][n])
#define ZD    292   // 192 x float2: (z = 10^zlog_c(i), delta_c(i))  [8B aligned: 292*4=1168]
#define ZMID  676   // 192 floats: 0.5*(zlog_c(i)+zlog_c(i+1)) for i<191
#define SWTOT 868   // staged floats (217 float4s)

#define KINV  896   // ws float offset: 9 floats, row-major inv(K) (not staged to LDS)
#define WS_FRAG_OFF  4096   // byte offset of Wc1 fp16 A-frags in d_ws (2048 B)
#define WS_FRAG2_OFF 6144   // byte offset of Wc2 fp16 A-frag (1024 B)
#define WS_NEED      8192

#define HSTRIDE 40  // ushort stride for H rows (80 B rows -> bank-friendly)
#define RGBS 4

using half8 = __attribute__((ext_vector_type(8))) _Float16;
using f32x4 = __attribute__((ext_vector_type(4))) float;
using f32x2 = __attribute__((ext_vector_type(2))) float;

#define LO2(v) __builtin_shufflevector(v, v, 0, 1)
#define HI2(v) __builtin_shufflevector(v, v, 2, 3)

__device__ __forceinline__ float zlog_c(int t) {
  return (t < 128) ? (-1.0f + (float)t * 0.0078125f)
                   : ((float)(t - 128) * 0.015625f);
}
__device__ __forceinline__ float delta_c(int t) {
  if (t >= SC - 1) return 0.0f;
  return zlog_c(t + 1) - zlog_c(t);
}

__device__ __forceinline__ float fast_rcp(float x) { return __builtin_amdgcn_rcpf(x); }
__device__ __forceinline__ float fast_rsq(float x) { return __builtin_amdgcn_rsqf(x); }
__device__ __forceinline__ float exp10_f(float x) { return __expf(x * 2.30258509299f); }
__device__ __forceinline__ float softplus_f(float x) {
  return fmaxf(x, 0.0f) + __logf(1.0f + __expf(-fabsf(x)));
}

// packed dual fp32 FMA: native vector fma -> LLVM selects v_pk_fma_f32 (gfx90a+)
// and can schedule/fold freely (no inline-asm register pinning). Same fma rounding.
__device__ __forceinline__ f32x2 pk_fma(f32x2 a, f32x2 b, f32x2 c) {
  return __builtin_elementwise_fma(a, b, c);
}

// fp16 helpers: pk2h = 1 HW instr (v_cvt_pkrtz_f16_f32); f2h = RTN scalar convert
__device__ __forceinline__ uint32_t pk2h(float a, float b) {
  auto p = __builtin_amdgcn_cvt_pkrtz(a, b);
  uint32_t u; __builtin_memcpy(&u, &p, 4); return u;
}
__device__ __forceinline__ unsigned short f2h(float f) {
  _Float16 h = (_Float16)f;
  unsigned short us; __builtin_memcpy(&us, &h, 2); return us;
}

__device__ __forceinline__ float4 ldsf4(const float* p) { return *(const float4*)p; }
__device__ __forceinline__ f32x4 ldsv4(const float* p) { return *(const f32x4*)p; }

// ---- DPP cross-lane (VALU pipe, no LDS): gfx9 row_shr / row_bcast sequence ----
template <int CTRL, int RMASK, int BMASK>
__device__ __forceinline__ float dpp_mov(float x, float oldv) {
  return __int_as_float(__builtin_amdgcn_update_dpp(
      __float_as_int(oldv), __float_as_int(x), CTRL, RMASK, BMASK, false));
}
__device__ __forceinline__ float dpp_scan_add(float v) {
  v += dpp_mov<0x111, 0xf, 0xf>(v, 0.0f);   // row_shr:1
  v += dpp_mov<0x112, 0xf, 0xf>(v, 0.0f);   // row_shr:2
  v += dpp_mov<0x114, 0xf, 0xf>(v, 0.0f);   // row_shr:4
  v += dpp_mov<0x118, 0xf, 0xf>(v, 0.0f);   // row_shr:8
  v += dpp_mov<0x142, 0xa, 0xf>(v, 0.0f);   // row_bcast:15 -> rows 1,3
  v += dpp_mov<0x143, 0xc, 0xf>(v, 0.0f);   // row_bcast:31 -> rows 2,3
  return v;
}
__device__ __forceinline__ float dpp_scan_mul(float v) {
  v *= dpp_mov<0x111, 0xf, 0xf>(v, 1.0f);
  v *= dpp_mov<0x112, 0xf, 0xf>(v, 1.0f);
  v *= dpp_mov<0x114, 0xf, 0xf>(v, 1.0f);
  v *= dpp_mov<0x118, 0xf, 0xf>(v, 1.0f);
  v *= dpp_mov<0x142, 0xa, 0xf>(v, 1.0f);
  v *= dpp_mov<0x143, 0xc, 0xf>(v, 1.0f);
  return v;
}

// JAX threefry2x32 with key = (0, 42)
__device__ __forceinline__ void threefry2x32_k42(uint32_t& x0, uint32_t& x1) {
  const uint32_t ks0 = 0u, ks1 = 42u;
  const uint32_t ks2 = ks0 ^ ks1 ^ 0x1BD11BDAu;
  const uint32_t ks[3] = {ks0, ks1, ks2};
  const int rot[2][4] = {{13, 15, 26, 6}, {17, 29, 16, 24}};
  x0 += ks[0];
  x1 += ks[1];
#pragma unroll
  for (int i = 0; i < 5; ++i) {
#pragma unroll
    for (int j = 0; j < 4; ++j) {
      x0 += x1;
      const int r = rot[i & 1][j];
      x1 = (x1 << r) | (x1 >> (32 - r));
      x1 ^= x0;
    }
    x0 += ks[(i + 1) % 3];
    x1 += ks[(i + 2) % 3] + (uint32_t)(i + 1);
  }
}

// ---- pre-pack kernel: weight image + z/delta tables + K-inverse + fp16 A-frags ----
__global__ __launch_bounds__(PACK_NT) void pack_weights(
    const float* __restrict__ K,
    const float* __restrict__ Wd1, const float* __restrict__ bd1,
    const float* __restrict__ Wd2, const float* __restrict__ bd2,
    const float* __restrict__ Wc1, const float* __restrict__ bc1,
    const float* __restrict__ Wc2, const float* __restrict__ bc2,
    float* __restrict__ wsf) {
  const int t = threadIdx.x;
  for (int i = t; i < 96; i += PACK_NT) wsf[WD1 + i] = Wd1[i];
  for (int i = t; i < 32; i += PACK_NT) { wsf[BD1 + i] = bd1[i]; wsf[WD2 + i] = Wd2[i]; }
  // z/delta table (input-independent; same device expressions as the old in-kernel
  // computation -> bitwise-identical values downstream)
  for (int i = t; i < 192; i += PACK_NT) {
    wsf[ZD + 2 * i + 0] = exp10_f(zlog_c(i));
    wsf[ZD + 2 * i + 1] = delta_c(i);
    wsf[ZMID + i] = (i < 191) ? 0.5f * (zlog_c(i) + zlog_c(i + 1)) : 0.0f;
  }
  if (t == 0) {
    wsf[BD2] = bd2[0];
    wsf[BC2 + 0] = bc2[0]; wsf[BC2 + 1] = bc2[1]; wsf[BC2 + 2] = bc2[2];
    // K-inverse (ray-independent)
    const float k00 = K[0], k01 = K[1], k02 = K[2];
    const float k10 = K[3], k11 = K[4], k12 = K[5];
    const float k20 = K[6], k21 = K[7], k22 = K[8];
    const float det = k00 * (k11 * k22 - k12 * k21)
                    - k01 * (k10 * k22 - k12 * k20)
                    + k02 * (k10 * k21 - k11 * k20);
    const float id = 1.0f / det;
    wsf[KINV + 0] =  (k11 * k22 - k12 * k21) * id;
    wsf[KINV + 1] = -(k01 * k22 - k02 * k21) * id;
    wsf[KINV + 2] =  (k01 * k12 - k02 * k11) * id;
    wsf[KINV + 3] = -(k10 * k22 - k12 * k20) * id;
    wsf[KINV + 4] =  (k00 * k22 - k02 * k20) * id;
    wsf[KINV + 5] = -(k00 * k12 - k02 * k10) * id;
    wsf[KINV + 6] =  (k10 * k21 - k11 * k20) * id;
    wsf[KINV + 7] = -(k00 * k21 - k01 * k20) * id;
    wsf[KINV + 8] =  (k00 * k11 - k01 * k10) * id;
  }
  if (t < 32) {
    wsf[NV4 + t * 4 + 0] = bc1[t];
    wsf[NV4 + t * 4 + 1] = Wc1[32 * 32 + t];
    wsf[NV4 + t * 4 + 2] = Wc1[33 * 32 + t];
    wsf[NV4 + t * 4 + 3] = Wc1[34 * 32 + t];
  }
  // Wc1[0:32][:] fp16 A-frags: frag[lane*2 + nt]; A[m=n][k], lane: n=nt*16+(lane&15), k=quad*8+j
  if (t < 64) {
    const int q_s = t >> 4;
    uint4* frag = (uint4*)((char*)wsf + WS_FRAG_OFF);
#pragma unroll
    for (int nt = 0; nt < 2; ++nt) {
      const int n_s = nt * 16 + (t & 15);
      uint32_t hw[4];
#pragma unroll
      for (int j2 = 0; j2 < 4; ++j2) {
        const int k = q_s * 8 + j2 * 2;
        hw[j2] = (uint32_t)f2h(Wc1[k * 32 + n_s])
               | ((uint32_t)f2h(Wc1[(k + 1) * 32 + n_s]) << 16);
      }
      frag[t * 2 + nt] = make_uint4(hw[0], hw[1], hw[2], hw[3]);
    }
    // Wc2 A-frag for layer-2 MFMA, k-permuted to match layer-1 C layout:
    // position k = q*8+j holds hidden h = (j<4 ? q*4+j : 16+q*4+(j-4)); rows m>=3 are 0
    {
      const int m = t & 15, q = t >> 4;
      uint32_t hw2[4];
#pragma unroll
      for (int jp = 0; jp < 4; ++jp) {
        const int j0 = jp * 2, j1 = j0 + 1;
        const int ha = (j0 < 4) ? q * 4 + j0 : 16 + q * 4 + (j0 - 4);
        const int hb = (j1 < 4) ? q * 4 + j1 : 16 + q * 4 + (j1 - 4);
        const float va = (m < 3) ? Wc2[ha * 3 + m] : 0.0f;
        const float vb = (m < 3) ? Wc2[hb * 3 + m] : 0.0f;
        hw2[jp] = (uint32_t)f2h(va) | ((uint32_t)f2h(vb) << 16);
      }
      ((uint4*)((char*)wsf + WS_FRAG2_OFF))[t] = make_uint4(hw2[0], hw2[1], hw2[2], hw2[3]);
    }
  }
}

template <bool USE_WS>
__global__ __launch_bounds__(NT, 5) void nerf_fwd(
    const float* __restrict__ hh, const float* __restrict__ ww,
    const float* __restrict__ K, const float* __restrict__ E,
    const float* __restrict__ bg,
    const float* __restrict__ Wd1, const float* __restrict__ bd1,
    const float* __restrict__ Wd2, const float* __restrict__ bd2,
    const float* __restrict__ Wc1, const float* __restrict__ bc1,
    const float* __restrict__ Wc2, const float* __restrict__ bc2,
    const float* __restrict__ wsf,
    float* __restrict__ out, int n_rays) {
  const int ray = blockIdx.x;
  const int t = threadIdx.x;
  const int lane = t & 63;
  const int wv = t >> 6;   // 0 or 1
  const int quad = lane >> 4;

  __shared__ __align__(16) float sw[SWTOT];
  // phase-union: coarse {s_w, s_cdf} then fine H (fp16)
  __shared__ __align__(16) unsigned char u_buf[SF * HSTRIDE * 2];  // 10240 B
  float* const s_w   = (float*)u_buf;
  float* const s_cdf = (float*)(u_buf + 768);
  unsigned short* const s_hf = (unsigned short*)u_buf;
  __shared__ float s_rgb[SF * RGBS];
  __shared__ float s_zlf[SF];
  __shared__ float s_tot[8];
  __shared__ float s_red[16];

  // ---- stage weight image + tables into LDS ----
  if constexpr (USE_WS) {
    const float4* wsrc = (const float4*)wsf;
    float4* sdst = (float4*)sw;
    for (int i = t; i < SWTOT / 4; i += NT) sdst[i] = wsrc[i];
  } else {
    for (int i = t; i < 96; i += NT) sw[WD1 + i] = Wd1[i];
    for (int i = t; i < 32; i += NT) { sw[BD1 + i] = bd1[i]; sw[WD2 + i] = Wd2[i]; }
    for (int i = t; i < 192; i += NT) {
      sw[ZD + 2 * i + 0] = exp10_f(zlog_c(i));
      sw[ZD + 2 * i + 1] = delta_c(i);
      sw[ZMID + i] = (i < 191) ? 0.5f * (zlog_c(i) + zlog_c(i + 1)) : 0.0f;
    }
    if (t == 0) {
      sw[BD2] = bd2[0];
      sw[BC2 + 0] = bc2[0]; sw[BC2 + 1] = bc2[1]; sw[BC2 + 2] = bc2[2];
    }
    if (t < 32) {
      sw[NV4 + t * 4 + 0] = bc1[t];
      sw[NV4 + t * 4 + 1] = Wc1[32 * 32 + t];
      sw[NV4 + t * 4 + 2] = Wc1[33 * 32 + t];
      sw[NV4 + t * 4 + 3] = Wc1[34 * 32 + t];
    }
  }

  // ---- ray setup (block-uniform) ----
  float i00, i01, i02, i10, i11, i12, i20, i21, i22;
  if constexpr (USE_WS) {
    i00 = wsf[KINV + 0]; i01 = wsf[KINV + 1]; i02 = wsf[KINV + 2];
    i10 = wsf[KINV + 3]; i11 = wsf[KINV + 4]; i12 = wsf[KINV + 5];
    i20 = wsf[KINV + 6]; i21 = wsf[KINV + 7]; i22 = wsf[KINV + 8];
  } else {
    const float k00 = K[0], k01 = K[1], k02 = K[2];
    const float k10 = K[3], k11 = K[4], k12 = K[5];
    const float k20 = K[6], k21 = K[7], k22 = K[8];
    const float det = k00 * (k11 * k22 - k12 * k21)
                    - k01 * (k10 * k22 - k12 * k20)
                    + k02 * (k10 * k21 - k11 * k20);
    const float id = 1.0f / det;
    i00 =  (k11 * k22 - k12 * k21) * id;
    i01 = -(k01 * k22 - k02 * k21) * id;
    i02 =  (k01 * k12 - k02 * k11) * id;
    i10 = -(k10 * k22 - k12 * k20) * id;
    i11 =  (k00 * k22 - k02 * k20) * id;
    i12 = -(k00 * k12 - k02 * k10) * id;
    i20 =  (k10 * k21 - k11 * k20) * id;
    i21 = -(k00 * k21 - k01 * k20) * id;
    i22 =  (k00 * k11 - k01 * k10) * id;
  }

  const float dwx = ww[ray] + 0.5f;
  const float dwy = hh[ray] + 0.5f;
  const float cx = i00 * dwx + i01 * dwy + i02;
  const float cy = i10 * dwx + i11 * dwy + i12;
  const float cz = i20 * dwx + i21 * dwy + i22;
  const float* Er = E + (size_t)ray * 16;
  const float ox = Er[3], oy = Er[7], oz = Er[11];
  const float dx = Er[0] * cx + Er[1] * cy + Er[2] * cz;
  const float dy = Er[4] * cx + Er[5] * cy + Er[6] * cz;
  const float dz = Er[8] * cx + Er[9] * cy + Er[10] * cz;
  const float inv_nrm = fast_rsq(dx * dx + dy * dy + dz * dz);
  const float ndx = dx * inv_nrm, ndy = dy * inv_nrm, ndz = dz * inv_nrm;

  __syncthreads();   // weights + tables staged

  // ---- coarse pass: e0 = t (all threads); e1 = 128+t (wave 0 only, FUSED loop) ----
  const float bd2v = sw[BD2];
  const float2 zdA = *(const float2*)(sw + ZD + 2 * t);   // (z, delta) for e0
  float2 zdB = make_float2(0.0f, 0.0f);
  float v0, v1e = 1.0f;
  {
    float px0, py0, pz0, px1 = 0.f, py1 = 0.f, pz1 = 0.f;
    {
      const float z = zdA.x;
      px0 = ox + dx * z; py0 = oy + dy * z; pz0 = oz + dz * z;
      const float d2 = px0 * px0 + py0 * py0 + pz0 * pz0;
      if (d2 > 1.0f) {
        const float invd = fast_rsq(d2);
        const float sc = (2.0f - invd) * invd;
        px0 *= sc; py0 *= sc; pz0 *= sc;
      }
    }
    if (wv == 0) {
      zdB = *(const float2*)(sw + ZD + 2 * (128 + t));
      const float z = zdB.x;
      px1 = ox + dx * z; py1 = oy + dy * z; pz1 = oz + dz * z;
      const float d2 = px1 * px1 + py1 * py1 + pz1 * pz1;
      if (d2 > 1.0f) {
        const float invd = fast_rsq(d2);
        const float sc = (2.0f - invd) * invd;
        px1 *= sc; py1 *= sc; pz1 *= sc;
      }
    }
    // packed dual-FMA over hidden-unit pairs; acc halves keep the even/odd-unit
    // grouping (bitwise-identical density)
    const f32x2 px0p = {px0, px0}, py0p = {py0, py0}, pz0p = {pz0, pz0};
    f32x2 a0P = {bd2v, 0.0f};
    if (wv == 0) {  // wave-uniform branch: fused 2-sample loop (weights loaded once)
      const f32x2 px1p = {px1, px1}, py1p = {py1, py1}, pz1p = {pz1, pz1};
      f32x2 a1P = {bd2v, 0.0f};
#pragma unroll
      for (int c = 0; c < 8; ++c) {
        const int k4 = c * 4;
        const f32x4 w0 = ldsv4(sw + WD1 + k4);
        const f32x4 w1 = ldsv4(sw + WD1 + 32 + k4);
        const f32x4 w2 = ldsv4(sw + WD1 + 64 + k4);
        const f32x4 b  = ldsv4(sw + BD1 + k4);
        const f32x4 wd = ldsv4(sw + WD2 + k4);
        f32x2 v, h;
        v = pk_fma(pz0p, LO2(w2), pk_fma(py0p, LO2(w1), pk_fma(px0p, LO2(w0), LO2(b))));
        h.x = fmaxf(v.x, 0.0f); h.y = fmaxf(v.y, 0.0f);
        a0P = pk_fma(h, LO2(wd), a0P);
        v = pk_fma(pz0p, HI2(w2), pk_fma(py0p, HI2(w1), pk_fma(px0p, HI2(w0), HI2(b))));
        h.x = fmaxf(v.x, 0.0f); h.y = fmaxf(v.y, 0.0f);
        a0P = pk_fma(h, HI2(wd), a0P);
        v = pk_fma(pz1p, LO2(w2), pk_fma(py1p, LO2(w1), pk_fma(px1p, LO2(w0), LO2(b))));
        h.x = fmaxf(v.x, 0.0f); h.y = fmaxf(v.y, 0.0f);
        a1P = pk_fma(h, LO2(wd), a1P);
        v = pk_fma(pz1p, HI2(w2), pk_fma(py1p, HI2(w1), pk_fma(px1p, HI2(w0), HI2(b))));
        h.x = fmaxf(v.x, 0.0f); h.y = fmaxf(v.y, 0.0f);
        a1P = pk_fma(h, HI2(wd), a1P);
      }
      v1e = __expf(-softplus_f(a1P.x + a1P.y) * zdB.y);
    } else {
#pragma unroll
      for (int c = 0; c < 8; ++c) {
        const int k4 = c * 4;
        const f32x4 w0 = ldsv4(sw + WD1 + k4);
        const f32x4 w1 = ldsv4(sw + WD1 + 32 + k4);
        const f32x4 w2 = ldsv4(sw + WD1 + 64 + k4);
        const f32x4 b  = ldsv4(sw + BD1 + k4);
        const f32x4 wd = ldsv4(sw + WD2 + k4);
        f32x2 v, h;
        v = pk_fma(pz0p, LO2(w2), pk_fma(py0p, LO2(w1), pk_fma(px0p, LO2(w0), LO2(b))));
        h.x = fmaxf(v.x, 0.0f); h.y = fmaxf(v.y, 0.0f);
        a0P = pk_fma(h, LO2(wd), a0P);
        v = pk_fma(pz0p, HI2(w2), pk_fma(py0p, HI2(w1), pk_fma(px0p, HI2(w0), HI2(b))));
        h.x = fmaxf(v.x, 0.0f); h.y = fmaxf(v.y, 0.0f);
        a0P = pk_fma(h, HI2(wd), a0P);
      }
    }
    v0 = __expf(-softplus_f(a0P.x + a0P.y) * zdA.y);
  }

  // parallel cumprod of (1-alpha) — DPP scan (VALU pipe)
  float i0 = dpp_scan_mul(v0);
  float i1 = 1.0f;
  if (wv == 0) i1 = dpp_scan_mul(v1e);
  if (lane == 63) s_tot[wv] = i0;
  if (wv == 0 && lane == 63) s_tot[2] = i1;
  __syncthreads();
  {
    const float preC1 = s_tot[0];
    const float preC2 = s_tot[0] * s_tot[1];
    // a * exclusive = (1-v)/v * inclusive = (rcp(v)-1) * inclusive
    s_w[t] = (fast_rcp(v0) - 1.0f) * i0 * (wv ? preC1 : 1.0f);
    if (wv == 0) {
      s_w[128 + t] = (fast_rcp(v1e) - 1.0f) * i1 * preC2;
    }
  }
  __syncthreads();

  // reweight
  float wre0, wre1 = 0.0f;
  {
    const float wm = (t > 0) ? s_w[t - 1] : 0.0f;
    const float w0 = s_w[t];
    const float wp = s_w[t + 1];
    wre0 = 0.5f * (fmaxf(wm, w0) + fmaxf(w0, wp)) + (0.02f / 192.0f);
    wre0 *= (t < 128) ? (128.0f / 192.0f) : (64.0f / 192.0f);
  }
  if (wv == 0) {
    const int e = 128 + t;
    const float wm = s_w[e - 1];
    const float w0 = s_w[e];
    const float wp = (e < SC - 1) ? s_w[e + 1] : 0.0f;
    wre1 = 0.5f * (fmaxf(wm, w0) + fmaxf(w0, wp)) + (0.02f / 192.0f);
    wre1 *= (64.0f / 192.0f);
  }

  // parallel cumsum -> normalized CDF — DPP scan
  float s0 = dpp_scan_add(wre0);
  float s1 = 0.0f;
  if (wv == 0) s1 = dpp_scan_add(wre1);
  if (lane == 63) s_tot[4 + wv] = s0;
  if (wv == 0 && lane == 63) s_tot[6] = s1;
  __syncthreads();
  {
    const float T0 = s_tot[4], T1 = s_tot[5], T2 = s_tot[6];
    const float inv_total = fast_rcp(T0 + T1 + T2);
    s_cdf[t] = (s0 + (wv ? T0 : 0.0f)) * inv_total;
    if (wv == 0) s_cdf[128 + t] = (s1 + T0 + T1) * inv_total;
  }
  __syncthreads();

  // ---- importance sampling ----
  float zlf, zf;
  {
    // 24-ary round-1 probes at FIXED indices: issued before threefry so their
    // LDS latency hides under ~100 VALU cycles of RNG compute.
    float cA[7];
#pragma unroll
    for (int i = 0; i < 7; ++i) cA[i] = s_cdf[24 * i + 24];   // value at m = 24i+23

    const uint32_t total = (uint32_t)n_rays * 128u;
    const uint32_t halfc = total >> 1;
    const uint32_t j = (uint32_t)ray * 128u + (uint32_t)t;
    uint32_t x0, x1;
    const bool first = (j < halfc);
    if (first) { x0 = j; x1 = j + halfc; } else { x0 = j - halfc; x1 = j; }
    threefry2x32_k42(x0, x1);
    const uint32_t bits = first ? x0 : x1;
    const float fr = __uint_as_float((bits >> 9) | 0x3f800000u) - 1.0f;

    float u = (float)t * 0.0078125f + fr * 0.0078125f;
    u = u * (s_cdf[190] - s_cdf[1]) + s_cdf[1];

    // searchsorted(right) over s_cdf[1..189]: lo = #{m in [0,189] : s_cdf[1+m] <= u}
    int start = 0;
#pragma unroll
    for (int i = 0; i < 7; ++i) start += (cA[i] <= u) ? 24 : 0;
    // round 2: 3-ary within the 24-block (probes at m = start+3i+2)
    float cB[7];
#pragma unroll
    for (int i = 0; i < 7; ++i) cB[i] = s_cdf[start + 3 * i + 3];
    int st2 = start;
#pragma unroll
    for (int i = 0; i < 7; ++i) st2 += (cB[i] <= u) ? 3 : 0;
    // round 3: neighborhood fetch (all independent) + cndmask select of cb/ca
    const float p0 = s_cdf[st2];
    const float p1 = s_cdf[st2 + 1];
    const float p2 = s_cdf[st2 + 2];
    const float p3 = s_cdf[st2 + 3];
    const int k = ((p1 <= u) ? 1 : 0) + ((p2 <= u) ? 1 : 0);
    const int lo = st2 + k;
    const int inds = lo + 1;
    const float cb = (k == 0) ? p0 : ((k == 1) ? p1 : p2);
    const float ca = (k == 0) ? p1 : ((k == 1) ? p2 : p3);
    const float tt = (u - cb) * fast_rcp(ca - cb);
    const float zb = sw[ZMID + inds - 1];
    const float za = sw[ZMID + inds];
    zlf = zb + (za - zb) * tt;
    s_zlf[t] = zlf;
    zf = exp10_f(zlf);
  }
  __syncthreads();   // last s_cdf read — union area now free for s_hf

  // ---- Wc1 + Wc2 A-frags (fp16) ----
  half8 Whi0, Whi1, W2f;
  if constexpr (USE_WS) {
    const uint4* frag = (const uint4*)((const char*)wsf + WS_FRAG_OFF);
    uint4 q0 = frag[lane * 2 + 0];
    uint4 q1 = frag[lane * 2 + 1];
    uint4 q2 = ((const uint4*)((const char*)wsf + WS_FRAG2_OFF))[lane];
    __builtin_memcpy(&Whi0, &q0, 16);
    __builtin_memcpy(&Whi1, &q1, 16);
    __builtin_memcpy(&W2f, &q2, 16);
  } else {
#pragma unroll
    for (int nt = 0; nt < 2; ++nt) {
      const int n_s = nt * 16 + (lane & 15);
      uint32_t hw[4];
#pragma unroll
      for (int j2 = 0; j2 < 4; ++j2) {
        const int k = quad * 8 + j2 * 2;
        hw[j2] = (uint32_t)f2h(Wc1[k * 32 + n_s])
               | ((uint32_t)f2h(Wc1[(k + 1) * 32 + n_s]) << 16);
      }
      uint4 q = make_uint4(hw[0], hw[1], hw[2], hw[3]);
      if (nt == 0) __builtin_memcpy(&Whi0, &q, 16);
      else         __builtin_memcpy(&Whi1, &q, 16);
    }
    {
      const int m = lane & 15;
      uint32_t hw2[4];
#pragma unroll
      for (int jp = 0; jp < 4; ++jp) {
        const int j0 = jp * 2, j1 = j0 + 1;
        const int ha = (j0 < 4) ? quad * 4 + j0 : 16 + quad * 4 + (j0 - 4);
        const int hb = (j1 < 4) ? quad * 4 + j1 : 16 + quad * 4 + (j1 - 4);
        const float va = (m < 3) ? Wc2[ha * 3 + m] : 0.0f;
        const float vb = (m < 3) ? Wc2[hb * 3 + m] : 0.0f;
        hw2[jp] = (uint32_t)f2h(va) | ((uint32_t)f2h(vb) << 16);
      }
      uint4 q2 = make_uint4(hw2[0], hw2[1], hw2[2], hw2[3]);
      __builtin_memcpy(&W2f, &q2, 16);
    }
  }

  // ---- fine density per-thread; h -> LDS as fp16 (HW pack) ----
  float sigf, vf;
  {
    float px = ox + dx * zf, py = oy + dy * zf, pz = oz + dz * zf;
    const float d2 = px * px + py * py + pz * pz;
    if (d2 > 1.0f) {
      const float invd = fast_rsq(d2);
      const float sc = (2.0f - invd) * invd;
      px *= sc; py *= sc; pz *= sc;
    }
    const f32x2 pxp = {px, px}, pyp = {py, py}, pzp = {pz, pz};
    f32x2 sP = {bd2v, 0.0f};
    uint4 tmp;
#pragma unroll
    for (int c = 0; c < 8; ++c) {
      const int k4 = c * 4;
      const f32x4 w0 = ldsv4(sw + WD1 + k4);
      const f32x4 w1 = ldsv4(sw + WD1 + 32 + k4);
      const f32x4 w2 = ldsv4(sw + WD1 + 64 + k4);
      const f32x4 b  = ldsv4(sw + BD1 + k4);
      const f32x4 wd = ldsv4(sw + WD2 + k4);
      f32x2 v, hlo, hhi;
      v = pk_fma(pzp, LO2(w2), pk_fma(pyp, LO2(w1), pk_fma(pxp, LO2(w0), LO2(b))));
      hlo.x = fmaxf(v.x, 0.0f); hlo.y = fmaxf(v.y, 0.0f);
      sP = pk_fma(hlo, LO2(wd), sP);
      v = pk_fma(pzp, HI2(w2), pk_fma(pyp, HI2(w1), pk_fma(pxp, HI2(w0), HI2(b))));
      hhi.x = fmaxf(v.x, 0.0f); hhi.y = fmaxf(v.y, 0.0f);
      sP = pk_fma(hhi, HI2(wd), sP);
      const uint32_t pA = pk2h(hlo.x, hlo.y), pB = pk2h(hhi.x, hhi.y);
      if ((c & 1) == 0) { tmp.x = pA; tmp.y = pB; }
      else {
        tmp.z = pA; tmp.w = pB;
        *(uint4*)(s_hf + t * HSTRIDE + (c >> 1) * 8) = tmp;
      }
    }
    sigf = softplus_f(sP.x + sP.y);
  }
  __syncthreads();   // h staged for MFMA

  // ---- fine color via MFMA chain: a1 = Wc1^T.H (dv in acc), rgb = Wc2^T.relu(a1) ----
  {
    // per-lane dv values (block-uniform per hidden unit) -> layer-1 acc init
    float dvv[2][4];
#pragma unroll
    for (int nt = 0; nt < 2; ++nt)
#pragma unroll
      for (int r = 0; r < 4; ++r) {
        const int n = nt * 16 + quad * 4 + r;
        const float4 nv = ldsf4(sw + NV4 + n * 4);
        dvv[nt][r] = nv.x + ndx * nv.y + ndy * nv.z + ndz * nv.w;
      }
    // layer-2 acc init: bias bc2 on quad0 rows 0..2
    f32x4 c2init;
    {
      const float b0 = sw[BC2 + 0], b1 = sw[BC2 + 1], b2 = sw[BC2 + 2];
      const bool q0 = (quad == 0);
      c2init[0] = q0 ? b0 : 0.0f;
      c2init[1] = q0 ? b1 : 0.0f;
      c2init[2] = q0 ? b2 : 0.0f;
      c2init[3] = 0.0f;
    }

#pragma unroll
    for (int mt = 0; mt < 4; ++mt) {
      const int sbase = wv * 64 + mt * 16;
      const int srow = sbase + (lane & 15);
      const half8 Hf = *(const half8*)(s_hf + srow * HSTRIDE + quad * 8);

      f32x4 acc0 = {dvv[0][0], dvv[0][1], dvv[0][2], dvv[0][3]};
      f32x4 acc1 = {dvv[1][0], dvv[1][1], dvv[1][2], dvv[1][3]};
      acc0 = __builtin_amdgcn_mfma_f32_16x16x32_f16(Whi0, Hf, acc0, 0, 0, 0);
      acc1 = __builtin_amdgcn_mfma_f32_16x16x32_f16(Whi1, Hf, acc1, 0, 0, 0);

      // relu + fp16 pack -> B-frag for layer-2 (k-permutation matches W2f)
      const uint32_t b20 = pk2h(fmaxf(acc0[0], 0.0f), fmaxf(acc0[1], 0.0f));
      const uint32_t b21 = pk2h(fmaxf(acc0[2], 0.0f), fmaxf(acc0[3], 0.0f));
      const uint32_t b22 = pk2h(fmaxf(acc1[0], 0.0f), fmaxf(acc1[1], 0.0f));
      const uint32_t b23 = pk2h(fmaxf(acc1[2], 0.0f), fmaxf(acc1[3], 0.0f));
      const uint4 qq = make_uint4(b20, b21, b22, b23);
      half8 B2; __builtin_memcpy(&B2, &qq, 16);

      f32x4 aC = c2init;
      aC = __builtin_amdgcn_mfma_f32_16x16x32_f16(W2f, B2, aC, 0, 0, 0);

      // quad0 lanes hold rgb rows 0..2 for sample sbase+(lane&15)
      if (quad == 0) {
        const int s = sbase + (lane & 15);
        float4 og;
        og.x = fast_rcp(1.0f + __expf(-aC[0]));
        og.y = fast_rcp(1.0f + __expf(-aC[1]));
        og.z = fast_rcp(1.0f + __expf(-aC[2]));
        og.w = 0.0f;
        *(float4*)(s_rgb + s * RGBS) = og;
      }
    }
  }

  // ---- fine alpha + parallel cumprod over 128 (DPP scan) ----
  const float deltaf = (t < SF - 1) ? (s_zlf[t + 1] - zlf) : 0.0f;
  vf = __expf(-sigf * deltaf);
  float fi = dpp_scan_mul(vf);
  if (lane == 63) s_tot[wv] = fi;
  __syncthreads();   // also makes s_rgb visible
  const float wf = (fast_rcp(vf) - 1.0f) * fi * (wv ? s_tot[0] : 1.0f);

  // ---- outputs ----
  float* o_img = out;
  float* o_w   = out + (size_t)n_rays * 3;
  float* o_z   = out + (size_t)n_rays * (3 + 128);
  float* o_inv = out + (size_t)n_rays * (3 + 256);

  o_w[(size_t)ray * 128 + t] = wf;
  o_z[(size_t)ray * 128 + t] = (zlf + 1.0f) * 0.5f;

  float r0 = wf * s_rgb[t * RGBS + 0];
  float r1 = wf * s_rgb[t * RGBS + 1];
  float r2 = wf * s_rgb[t * RGBS + 2];
  float r3 = wf, r4 = wf * fast_rcp(zf);
  // DPP scan-based reduce: lane 63 holds the wave total
  r0 = dpp_scan_add(r0);
  r1 = dpp_scan_add(r1);
  r2 = dpp_scan_add(r2);
  r3 = dpp_scan_add(r3);
  r4 = dpp_scan_add(r4);
  if (lane == 63) {
    float* p = &s_red[wv * 5];
    p[0] = r0; p[1] = r1; p[2] = r2; p[3] = r3; p[4] = r4;
  }
  __syncthreads();
  if (t == 0) {
    const float accw = s_red[3] + s_red[8];
    const float bgw = 1.0f - accw;
    o_img[(size_t)ray * 3 + 0] = (s_red[0] + s_red[5]) + bgw * bg[0];
    o_img[(size_t)ray * 3 + 1] = (s_red[1] + s_red[6]) + bgw * bg[1];
    o_img[(size_t)ray * 3 + 2] = (s_red[2] + s_red[7]) + bgw * bg[2];
    o_inv[ray] = s_red[4] + s_red[9];
  }
}

extern "C" void kernel_launch(void* const* d_in, const int* in_sizes, int n_in,
                              void* d_out, int out_size, void* d_ws, size_t ws_size,
                              hipStream_t stream) {
  const float* h   = (const float*)d_in[1];
  const float* w   = (const float*)d_in[2];
  const float* K   = (const float*)d_in[3];
  const float* E   = (const float*)d_in[4];
  const float* bg  = (const float*)d_in[5];
  const float* Wd1 = (const float*)d_in[6];
  const float* bd1 = (const float*)d_in[7];
  const float* Wd2 = (const float*)d_in[8];
  const float* bd2 = (const float*)d_in[9];
  const float* Wc1 = (const float*)d_in[10];
  const float* bc1 = (const float*)d_in[11];
  const float* Wc2 = (const float*)d_in[12];
  const float* bc2 = (const float*)d_in[13];
  const int n_rays = in_sizes[1];
  float* wsf = (float*)d_ws;

  if (ws_size >= WS_NEED) {
    pack_weights<<<1, PACK_NT, 0, stream>>>(K, Wd1, bd1, Wd2, bd2, Wc1, bc1, Wc2, bc2, wsf);
    nerf_fwd<true><<<n_rays, NT, 0, stream>>>(h, w, K, E, bg, Wd1, bd1, Wd2, bd2,
                                              Wc1, bc1, Wc2, bc2, wsf,
                                              (float*)d_out, n_rays);
  } else {
    nerf_fwd<false><<<n_rays, NT, 0, stream>>>(h, w, K, E, bg, Wd1, bd1, Wd2, bd2,
                                               Wc1, bc1, Wc2, bc2, nullptr,
                                               (float*)d_out, n_rays);
  }
}

// Round 5
// 144.375 us; speedup vs baseline: 1.0664x; 1.0286x over previous
//
#include <hip/hip_runtime.h>
#include <stdint.h>

#define SC 192      // coarse samples (128 + 64)
#define SF 128      // fine (importance) samples
#define NT 128      // threads per block = 2 waves
#define PACK_NT 128

// LDS weight-image offsets (floats)
#define WD1   0     // 96  (3x32 row-major)
#define BD1   96    // 32
#define WD2   128   // 32
#define BD2   160   // 1
#define BC2   161   // 3
#define NV4   164   // 32 x float4: (bc1[n], Wc1[32][n], Wc1[33][n], Wc1[34][n])
#define ZD    292   // 192 x float2: (z = 10^zlog_c(i), delta_c(i))
#define ZMID  676   // 192 floats: 0.5*(zlog_c(i)+zlog_c(i+1)) for i<191
#define SWTOT 868   // staged floats (217 float4s)

#define KINV  896   // ws float offset: 9 floats, row-major inv(K)
// fp16 MFMA A-frag tables in d_ws (64 lanes each)
#define WS_F_WD1 4096   // 128 x uint4: lane*2 -> {Wd1 units 0-15, units 16-31}, bias at k=3
#define WS_F_WC1 6144   // 128 x uint4: k-permuted Wc1 frags (match B2 layout)
#define WS_F_WD2 8192   // 64 x uint4: row0 = Wd2 k-permuted
#define WS_F_W2  9216   // 64 x uint4: rows 0-2 = Wc2 k-permuted
#define WS_NEED  10240

#define RGBS 4

using half8 = __attribute__((ext_vector_type(8))) _Float16;
using f32x4 = __attribute__((ext_vector_type(4))) float;
using f32x2 = __attribute__((ext_vector_type(2))) float;

#define LO2(v) __builtin_shufflevector(v, v, 0, 1)
#define HI2(v) __builtin_shufflevector(v, v, 2, 3)

__device__ __forceinline__ float zlog_c(int t) {
  return (t < 128) ? (-1.0f + (float)t * 0.0078125f)
                   : ((float)(t - 128) * 0.015625f);
}
__device__ __forceinline__ float delta_c(int t) {
  if (t >= SC - 1) return 0.0f;
  return zlog_c(t + 1) - zlog_c(t);
}

__device__ __forceinline__ float fast_rcp(float x) { return __builtin_amdgcn_rcpf(x); }
__device__ __forceinline__ float fast_rsq(float x) { return __builtin_amdgcn_rsqf(x); }
__device__ __forceinline__ float exp10_f(float x) { return __expf(x * 2.30258509299f); }
__device__ __forceinline__ float softplus_f(float x) {
  return fmaxf(x, 0.0f) + __logf(1.0f + __expf(-fabsf(x)));
}

// packed dual fp32 FMA (native -> v_pk_fma_f32, same fma rounding)
__device__ __forceinline__ f32x2 pk_fma(f32x2 a, f32x2 b, f32x2 c) {
  return __builtin_elementwise_fma(a, b, c);
}

// fp16 helpers
__device__ __forceinline__ uint32_t pk2h(float a, float b) {
  auto p = __builtin_amdgcn_cvt_pkrtz(a, b);
  uint32_t u; __builtin_memcpy(&u, &p, 4); return u;
}
__device__ __forceinline__ unsigned short f2h(float f) {
  _Float16 h = (_Float16)f;
  unsigned short us; __builtin_memcpy(&us, &h, 2); return us;
}

__device__ __forceinline__ float4 ldsf4(const float* p) { return *(const float4*)p; }
__device__ __forceinline__ f32x4 ldsv4(const float* p) { return *(const f32x4*)p; }

// k-permutation shared by all layer-2-style A-frags: frag position (q, j)
// holds source index (j<4 ? 4q+j : 16+4q+(j-4)) — matches B2 built from acc0/acc1.
__device__ __forceinline__ int kperm(int q, int j) {
  return (j < 4) ? (q * 4 + j) : (16 + q * 4 + (j - 4));
}

// ---- DPP cross-lane scans ----
template <int CTRL, int RMASK, int BMASK>
__device__ __forceinline__ float dpp_mov(float x, float oldv) {
  return __int_as_float(__builtin_amdgcn_update_dpp(
      __float_as_int(oldv), __float_as_int(x), CTRL, RMASK, BMASK, false));
}
__device__ __forceinline__ float dpp_scan_add(float v) {
  v += dpp_mov<0x111, 0xf, 0xf>(v, 0.0f);
  v += dpp_mov<0x112, 0xf, 0xf>(v, 0.0f);
  v += dpp_mov<0x114, 0xf, 0xf>(v, 0.0f);
  v += dpp_mov<0x118, 0xf, 0xf>(v, 0.0f);
  v += dpp_mov<0x142, 0xa, 0xf>(v, 0.0f);
  v += dpp_mov<0x143, 0xc, 0xf>(v, 0.0f);
  return v;
}
__device__ __forceinline__ float dpp_scan_mul(float v) {
  v *= dpp_mov<0x111, 0xf, 0xf>(v, 1.0f);
  v *= dpp_mov<0x112, 0xf, 0xf>(v, 1.0f);
  v *= dpp_mov<0x114, 0xf, 0xf>(v, 1.0f);
  v *= dpp_mov<0x118, 0xf, 0xf>(v, 1.0f);
  v *= dpp_mov<0x142, 0xa, 0xf>(v, 1.0f);
  v *= dpp_mov<0x143, 0xc, 0xf>(v, 1.0f);
  return v;
}

// JAX threefry2x32 with key = (0, 42)
__device__ __forceinline__ void threefry2x32_k42(uint32_t& x0, uint32_t& x1) {
  const uint32_t ks0 = 0u, ks1 = 42u;
  const uint32_t ks2 = ks0 ^ ks1 ^ 0x1BD11BDAu;
  const uint32_t ks[3] = {ks0, ks1, ks2};
  const int rot[2][4] = {{13, 15, 26, 6}, {17, 29, 16, 24}};
  x0 += ks[0];
  x1 += ks[1];
#pragma unroll
  for (int i = 0; i < 5; ++i) {
#pragma unroll
    for (int j = 0; j < 4; ++j) {
      x0 += x1;
      const int r = rot[i & 1][j];
      x1 = (x1 << r) | (x1 >> (32 - r));
      x1 ^= x0;
    }
    x0 += ks[(i + 1) % 3];
    x1 += ks[(i + 2) % 3] + (uint32_t)(i + 1);
  }
}

// value of Wd1-layer A-frag at (k, unit): k<3 -> Wd1[k][n], k==3 -> bd1[n], else 0
__device__ __forceinline__ float wd1_val(const float* Wd1, const float* bd1, int k, int n) {
  if (k < 3) return Wd1[k * 32 + n];
  if (k == 3) return bd1[n];
  return 0.0f;
}

// ---- pre-pack kernel ----
__global__ __launch_bounds__(PACK_NT) void pack_weights(
    const float* __restrict__ K,
    const float* __restrict__ Wd1, const float* __restrict__ bd1,
    const float* __restrict__ Wd2, const float* __restrict__ bd2,
    const float* __restrict__ Wc1, const float* __restrict__ bc1,
    const float* __restrict__ Wc2, const float* __restrict__ bc2,
    float* __restrict__ wsf) {
  const int t = threadIdx.x;
  for (int i = t; i < 96; i += PACK_NT) wsf[WD1 + i] = Wd1[i];
  for (int i = t; i < 32; i += PACK_NT) { wsf[BD1 + i] = bd1[i]; wsf[WD2 + i] = Wd2[i]; }
  for (int i = t; i < 192; i += PACK_NT) {
    wsf[ZD + 2 * i + 0] = exp10_f(zlog_c(i));
    wsf[ZD + 2 * i + 1] = delta_c(i);
    wsf[ZMID + i] = (i < 191) ? 0.5f * (zlog_c(i) + zlog_c(i + 1)) : 0.0f;
  }
  if (t == 0) {
    wsf[BD2] = bd2[0];
    wsf[BC2 + 0] = bc2[0]; wsf[BC2 + 1] = bc2[1]; wsf[BC2 + 2] = bc2[2];
    const float k00 = K[0], k01 = K[1], k02 = K[2];
    const float k10 = K[3], k11 = K[4], k12 = K[5];
    const float k20 = K[6], k21 = K[7], k22 = K[8];
    const float det = k00 * (k11 * k22 - k12 * k21)
                    - k01 * (k10 * k22 - k12 * k20)
                    + k02 * (k10 * k21 - k11 * k20);
    const float id = 1.0f / det;
    wsf[KINV + 0] =  (k11 * k22 - k12 * k21) * id;
    wsf[KINV + 1] = -(k01 * k22 - k02 * k21) * id;
    wsf[KINV + 2] =  (k01 * k12 - k02 * k11) * id;
    wsf[KINV + 3] = -(k10 * k22 - k12 * k20) * id;
    wsf[KINV + 4] =  (k00 * k22 - k02 * k20) * id;
    wsf[KINV + 5] = -(k00 * k12 - k02 * k10) * id;
    wsf[KINV + 6] =  (k10 * k21 - k11 * k20) * id;
    wsf[KINV + 7] = -(k00 * k21 - k01 * k20) * id;
    wsf[KINV + 8] =  (k00 * k11 - k01 * k10) * id;
  }
  if (t < 32) {
    wsf[NV4 + t * 4 + 0] = bc1[t];
    wsf[NV4 + t * 4 + 1] = Wc1[32 * 32 + t];
    wsf[NV4 + t * 4 + 2] = Wc1[33 * 32 + t];
    wsf[NV4 + t * 4 + 3] = Wc1[34 * 32 + t];
  }
  if (t < 64) {
    const int m = t & 15, q = t >> 4;
    // Wd1 A-frags (natural k order, bias at k=3, zeros k>=4)
    {
      uint4* fr = (uint4*)((char*)wsf + WS_F_WD1);
#pragma unroll
      for (int nt = 0; nt < 2; ++nt) {
        const int n = nt * 16 + m;
        uint32_t hw[4];
#pragma unroll
        for (int j2 = 0; j2 < 4; ++j2) {
          const int k = q * 8 + j2 * 2;
          hw[j2] = (uint32_t)f2h(wd1_val(Wd1, bd1, k, n))
                 | ((uint32_t)f2h(wd1_val(Wd1, bd1, k + 1, n)) << 16);
        }
        fr[t * 2 + nt] = make_uint4(hw[0], hw[1], hw[2], hw[3]);
      }
    }
    // Wc1 A-frags, k-PERMUTED to match B2 (built from density acc0/acc1)
    {
      uint4* fr = (uint4*)((char*)wsf + WS_F_WC1);
#pragma unroll
      for (int nt = 0; nt < 2; ++nt) {
        const int n = nt * 16 + m;
        uint32_t hw[4];
#pragma unroll
        for (int j2 = 0; j2 < 4; ++j2) {
          const int kkA = kperm(q, j2 * 2), kkB = kperm(q, j2 * 2 + 1);
          hw[j2] = (uint32_t)f2h(Wc1[kkA * 32 + n])
                 | ((uint32_t)f2h(Wc1[kkB * 32 + n]) << 16);
        }
        fr[t * 2 + nt] = make_uint4(hw[0], hw[1], hw[2], hw[3]);
      }
    }
    // Wd2 A-frag: row 0 = Wd2 (k-permuted), rows 1-15 zero
    {
      uint32_t hw[4];
#pragma unroll
      for (int j2 = 0; j2 < 4; ++j2) {
        const int kkA = kperm(q, j2 * 2), kkB = kperm(q, j2 * 2 + 1);
        const float va = (m == 0) ? Wd2[kkA] : 0.0f;
        const float vb = (m == 0) ? Wd2[kkB] : 0.0f;
        hw[j2] = (uint32_t)f2h(va) | ((uint32_t)f2h(vb) << 16);
      }
      ((uint4*)((char*)wsf + WS_F_WD2))[t] = make_uint4(hw[0], hw[1], hw[2], hw[3]);
    }
    // Wc2 A-frag: rows 0-2 = Wc2 (k-permuted, matches B3 from color acc0/acc1)
    {
      uint32_t hw[4];
#pragma unroll
      for (int j2 = 0; j2 < 4; ++j2) {
        const int kkA = kperm(q, j2 * 2), kkB = kperm(q, j2 * 2 + 1);
        const float va = (m < 3) ? Wc2[kkA * 3 + m] : 0.0f;
        const float vb = (m < 3) ? Wc2[kkB * 3 + m] : 0.0f;
        hw[j2] = (uint32_t)f2h(va) | ((uint32_t)f2h(vb) << 16);
      }
      ((uint4*)((char*)wsf + WS_F_W2))[t] = make_uint4(hw[0], hw[1], hw[2], hw[3]);
    }
  }
}

template <bool USE_WS>
__global__ __launch_bounds__(NT, 8) void nerf_fwd(
    const float* __restrict__ hh, const float* __restrict__ ww,
    const float* __restrict__ K, const float* __restrict__ E,
    const float* __restrict__ bg,
    const float* __restrict__ Wd1, const float* __restrict__ bd1,
    const float* __restrict__ Wd2, const float* __restrict__ bd2,
    const float* __restrict__ Wc1, const float* __restrict__ bc1,
    const float* __restrict__ Wc2, const float* __restrict__ bc2,
    const float* __restrict__ wsf,
    float* __restrict__ out, int n_rays) {
  const int ray = blockIdx.x;
  const int t = threadIdx.x;
  const int lane = t & 63;
  const int wv = t >> 6;   // 0 or 1
  const int quad = lane >> 4;

  __shared__ __align__(16) float sw[SWTOT];
  // union region: coarse {s_w[192], s_cdf[192]} ; fine {s_p[128]x8B, s_sig[128]}
  __shared__ __align__(16) float u2[768];
  float* const s_w   = u2;            // [0..191]
  float* const s_cdf = u2 + 192;      // [192..383]  (live through sampling)
  uint2* const s_p   = (uint2*)(u2 + 384);  // [384..639] 128 x 8B fp16 {x,y | z,1}
  float* const s_sig = u2 + 640;      // [640..767]
  __shared__ float s_rgb[SF * RGBS];
  __shared__ float s_zlf[SF];
  __shared__ float s_tot[8];
  __shared__ float s_red[16];

  // ---- stage weight image + tables into LDS ----
  if constexpr (USE_WS) {
    const float4* wsrc = (const float4*)wsf;
    float4* sdst = (float4*)sw;
    for (int i = t; i < SWTOT / 4; i += NT) sdst[i] = wsrc[i];
  } else {
    for (int i = t; i < 96; i += NT) sw[WD1 + i] = Wd1[i];
    for (int i = t; i < 32; i += NT) { sw[BD1 + i] = bd1[i]; sw[WD2 + i] = Wd2[i]; }
    for (int i = t; i < 192; i += NT) {
      sw[ZD + 2 * i + 0] = exp10_f(zlog_c(i));
      sw[ZD + 2 * i + 1] = delta_c(i);
      sw[ZMID + i] = (i < 191) ? 0.5f * (zlog_c(i) + zlog_c(i + 1)) : 0.0f;
    }
    if (t == 0) {
      sw[BD2] = bd2[0];
      sw[BC2 + 0] = bc2[0]; sw[BC2 + 1] = bc2[1]; sw[BC2 + 2] = bc2[2];
    }
    if (t < 32) {
      sw[NV4 + t * 4 + 0] = bc1[t];
      sw[NV4 + t * 4 + 1] = Wc1[32 * 32 + t];
      sw[NV4 + t * 4 + 2] = Wc1[33 * 32 + t];
      sw[NV4 + t * 4 + 3] = Wc1[34 * 32 + t];
    }
  }

  // ---- ray setup (block-uniform) ----
  float i00, i01, i02, i10, i11, i12, i20, i21, i22;
  if constexpr (USE_WS) {
    i00 = wsf[KINV + 0]; i01 = wsf[KINV + 1]; i02 = wsf[KINV + 2];
    i10 = wsf[KINV + 3]; i11 = wsf[KINV + 4]; i12 = wsf[KINV + 5];
    i20 = wsf[KINV + 6]; i21 = wsf[KINV + 7]; i22 = wsf[KINV + 8];
  } else {
    const float k00 = K[0], k01 = K[1], k02 = K[2];
    const float k10 = K[3], k11 = K[4], k12 = K[5];
    const float k20 = K[6], k21 = K[7], k22 = K[8];
    const float det = k00 * (k11 * k22 - k12 * k21)
                    - k01 * (k10 * k22 - k12 * k20)
                    + k02 * (k10 * k21 - k11 * k20);
    const float id = 1.0f / det;
    i00 =  (k11 * k22 - k12 * k21) * id;
    i01 = -(k01 * k22 - k02 * k21) * id;
    i02 =  (k01 * k12 - k02 * k11) * id;
    i10 = -(k10 * k22 - k12 * k20) * id;
    i11 =  (k00 * k22 - k02 * k20) * id;
    i12 = -(k00 * k12 - k02 * k10) * id;
    i20 =  (k10 * k21 - k11 * k20) * id;
    i21 = -(k00 * k21 - k01 * k20) * id;
    i22 =  (k00 * k11 - k01 * k10) * id;
  }

  const float dwx = ww[ray] + 0.5f;
  const float dwy = hh[ray] + 0.5f;
  const float cx = i00 * dwx + i01 * dwy + i02;
  const float cy = i10 * dwx + i11 * dwy + i12;
  const float cz = i20 * dwx + i21 * dwy + i22;
  const float* Er = E + (size_t)ray * 16;
  const float ox = Er[3], oy = Er[7], oz = Er[11];
  const float dx = Er[0] * cx + Er[1] * cy + Er[2] * cz;
  const float dy = Er[4] * cx + Er[5] * cy + Er[6] * cz;
  const float dz = Er[8] * cx + Er[9] * cy + Er[10] * cz;
  const float inv_nrm = fast_rsq(dx * dx + dy * dy + dz * dz);
  const float ndx = dx * inv_nrm, ndy = dy * inv_nrm, ndz = dz * inv_nrm;

  __syncthreads();   // weights + tables staged

  // ---- coarse pass (fp32, bitwise-identical to R4) ----
  const float bd2v = sw[BD2];
  const float2 zdA = *(const float2*)(sw + ZD + 2 * t);
  float2 zdB = make_float2(0.0f, 0.0f);
  float v0, v1e = 1.0f;
  {
    float px0, py0, pz0, px1 = 0.f, py1 = 0.f, pz1 = 0.f;
    {
      const float z = zdA.x;
      px0 = ox + dx * z; py0 = oy + dy * z; pz0 = oz + dz * z;
      const float d2 = px0 * px0 + py0 * py0 + pz0 * pz0;
      if (d2 > 1.0f) {
        const float invd = fast_rsq(d2);
        const float sc = (2.0f - invd) * invd;
        px0 *= sc; py0 *= sc; pz0 *= sc;
      }
    }
    if (wv == 0) {
      zdB = *(const float2*)(sw + ZD + 2 * (128 + t));
      const float z = zdB.x;
      px1 = ox + dx * z; py1 = oy + dy * z; pz1 = oz + dz * z;
      const float d2 = px1 * px1 + py1 * py1 + pz1 * pz1;
      if (d2 > 1.0f) {
        const float invd = fast_rsq(d2);
        const float sc = (2.0f - invd) * invd;
        px1 *= sc; py1 *= sc; pz1 *= sc;
      }
    }
    const f32x2 px0p = {px0, px0}, py0p = {py0, py0}, pz0p = {pz0, pz0};
    f32x2 a0P = {bd2v, 0.0f};
    if (wv == 0) {
      const f32x2 px1p = {px1, px1}, py1p = {py1, py1}, pz1p = {pz1, pz1};
      f32x2 a1P = {bd2v, 0.0f};
#pragma unroll
      for (int c = 0; c < 8; ++c) {
        const int k4 = c * 4;
        const f32x4 w0 = ldsv4(sw + WD1 + k4);
        const f32x4 w1 = ldsv4(sw + WD1 + 32 + k4);
        const f32x4 w2 = ldsv4(sw + WD1 + 64 + k4);
        const f32x4 b  = ldsv4(sw + BD1 + k4);
        const f32x4 wd = ldsv4(sw + WD2 + k4);
        f32x2 v, h;
        v = pk_fma(pz0p, LO2(w2), pk_fma(py0p, LO2(w1), pk_fma(px0p, LO2(w0), LO2(b))));
        h.x = fmaxf(v.x, 0.0f); h.y = fmaxf(v.y, 0.0f);
        a0P = pk_fma(h, LO2(wd), a0P);
        v = pk_fma(pz0p, HI2(w2), pk_fma(py0p, HI2(w1), pk_fma(px0p, HI2(w0), HI2(b))));
        h.x = fmaxf(v.x, 0.0f); h.y = fmaxf(v.y, 0.0f);
        a0P = pk_fma(h, HI2(wd), a0P);
        v = pk_fma(pz1p, LO2(w2), pk_fma(py1p, LO2(w1), pk_fma(px1p, LO2(w0), LO2(b))));
        h.x = fmaxf(v.x, 0.0f); h.y = fmaxf(v.y, 0.0f);
        a1P = pk_fma(h, LO2(wd), a1P);
        v = pk_fma(pz1p, HI2(w2), pk_fma(py1p, HI2(w1), pk_fma(px1p, HI2(w0), HI2(b))));
        h.x = fmaxf(v.x, 0.0f); h.y = fmaxf(v.y, 0.0f);
        a1P = pk_fma(h, HI2(wd), a1P);
      }
      v1e = __expf(-softplus_f(a1P.x + a1P.y) * zdB.y);
    } else {
#pragma unroll
      for (int c = 0; c < 8; ++c) {
        const int k4 = c * 4;
        const f32x4 w0 = ldsv4(sw + WD1 + k4);
        const f32x4 w1 = ldsv4(sw + WD1 + 32 + k4);
        const f32x4 w2 = ldsv4(sw + WD1 + 64 + k4);
        const f32x4 b  = ldsv4(sw + BD1 + k4);
        const f32x4 wd = ldsv4(sw + WD2 + k4);
        f32x2 v, h;
        v = pk_fma(pz0p, LO2(w2), pk_fma(py0p, LO2(w1), pk_fma(px0p, LO2(w0), LO2(b))));
        h.x = fmaxf(v.x, 0.0f); h.y = fmaxf(v.y, 0.0f);
        a0P = pk_fma(h, LO2(wd), a0P);
        v = pk_fma(pz0p, HI2(w2), pk_fma(py0p, HI2(w1), pk_fma(px0p, HI2(w0), HI2(b))));
        h.x = fmaxf(v.x, 0.0f); h.y = fmaxf(v.y, 0.0f);
        a0P = pk_fma(h, HI2(wd), a0P);
      }
    }
    v0 = __expf(-softplus_f(a0P.x + a0P.y) * zdA.y);
  }

  float i0 = dpp_scan_mul(v0);
  float i1 = 1.0f;
  if (wv == 0) i1 = dpp_scan_mul(v1e);
  if (lane == 63) s_tot[wv] = i0;
  if (wv == 0 && lane == 63) s_tot[2] = i1;
  __syncthreads();
  {
    const float preC1 = s_tot[0];
    const float preC2 = s_tot[0] * s_tot[1];
    s_w[t] = (fast_rcp(v0) - 1.0f) * i0 * (wv ? preC1 : 1.0f);
    if (wv == 0) {
      s_w[128 + t] = (fast_rcp(v1e) - 1.0f) * i1 * preC2;
    }
  }
  __syncthreads();

  // reweight
  float wre0, wre1 = 0.0f;
  {
    const float wm = (t > 0) ? s_w[t - 1] : 0.0f;
    const float w0 = s_w[t];
    const float wp = s_w[t + 1];
    wre0 = 0.5f * (fmaxf(wm, w0) + fmaxf(w0, wp)) + (0.02f / 192.0f);
    wre0 *= (t < 128) ? (128.0f / 192.0f) : (64.0f / 192.0f);
  }
  if (wv == 0) {
    const int e = 128 + t;
    const float wm = s_w[e - 1];
    const float w0 = s_w[e];
    const float wp = (e < SC - 1) ? s_w[e + 1] : 0.0f;
    wre1 = 0.5f * (fmaxf(wm, w0) + fmaxf(w0, wp)) + (0.02f / 192.0f);
    wre1 *= (64.0f / 192.0f);
  }

  float s0 = dpp_scan_add(wre0);
  float s1 = 0.0f;
  if (wv == 0) s1 = dpp_scan_add(wre1);
  if (lane == 63) s_tot[4 + wv] = s0;
  if (wv == 0 && lane == 63) s_tot[6] = s1;
  __syncthreads();
  {
    const float T0 = s_tot[4], T1 = s_tot[5], T2 = s_tot[6];
    const float inv_total = fast_rcp(T0 + T1 + T2);
    s_cdf[t] = (s0 + (wv ? T0 : 0.0f)) * inv_total;
    if (wv == 0) s_cdf[128 + t] = (s1 + T0 + T1) * inv_total;
  }
  __syncthreads();

  // ---- importance sampling + fine point pack ----
  float zlf, zf;
  {
    float cA[7];
#pragma unroll
    for (int i = 0; i < 7; ++i) cA[i] = s_cdf[24 * i + 24];

    const uint32_t total = (uint32_t)n_rays * 128u;
    const uint32_t halfc = total >> 1;
    const uint32_t j = (uint32_t)ray * 128u + (uint32_t)t;
    uint32_t x0, x1;
    const bool first = (j < halfc);
    if (first) { x0 = j; x1 = j + halfc; } else { x0 = j - halfc; x1 = j; }
    threefry2x32_k42(x0, x1);
    const uint32_t bits = first ? x0 : x1;
    const float fr = __uint_as_float((bits >> 9) | 0x3f800000u) - 1.0f;

    float u = (float)t * 0.0078125f + fr * 0.0078125f;
    u = u * (s_cdf[190] - s_cdf[1]) + s_cdf[1];

    int start = 0;
#pragma unroll
    for (int i = 0; i < 7; ++i) start += (cA[i] <= u) ? 24 : 0;
    float cB[7];
#pragma unroll
    for (int i = 0; i < 7; ++i) cB[i] = s_cdf[start + 3 * i + 3];
    int st2 = start;
#pragma unroll
    for (int i = 0; i < 7; ++i) st2 += (cB[i] <= u) ? 3 : 0;
    const float p0 = s_cdf[st2];
    const float p1 = s_cdf[st2 + 1];
    const float p2 = s_cdf[st2 + 2];
    const float p3 = s_cdf[st2 + 3];
    const int k = ((p1 <= u) ? 1 : 0) + ((p2 <= u) ? 1 : 0);
    const int lo = st2 + k;
    const int inds = lo + 1;
    const float cb = (k == 0) ? p0 : ((k == 1) ? p1 : p2);
    const float ca = (k == 0) ? p1 : ((k == 1) ? p2 : p3);
    const float tt = (u - cb) * fast_rcp(ca - cb);
    const float zb = sw[ZMID + inds - 1];
    const float za = sw[ZMID + inds];
    zlf = zb + (za - zb) * tt;
    s_zlf[t] = zlf;
    zf = exp10_f(zlf);

    // fine point (mip-scaled), packed fp16 {x,y | z,1} -> s_p
    float px = ox + dx * zf, py = oy + dy * zf, pz = oz + dz * zf;
    const float d2 = px * px + py * py + pz * pz;
    if (d2 > 1.0f) {
      const float invd = fast_rsq(d2);
      const float sc = (2.0f - invd) * invd;
      px *= sc; py *= sc; pz *= sc;
    }
    s_p[t] = make_uint2(pk2h(px, py), pk2h(pz, 1.0f));
  }
  __syncthreads();   // s_cdf done; s_p + s_zlf staged

  // ---- A-frags (fp16) ----
  half8 FD0, FD1, FC0, FC1, FS, F2;
  if constexpr (USE_WS) {
    const uint4* fd = (const uint4*)((const char*)wsf + WS_F_WD1);
    const uint4* fc = (const uint4*)((const char*)wsf + WS_F_WC1);
    uint4 q0 = fd[lane * 2 + 0], q1 = fd[lane * 2 + 1];
    uint4 q2 = fc[lane * 2 + 0], q3 = fc[lane * 2 + 1];
    uint4 q4 = ((const uint4*)((const char*)wsf + WS_F_WD2))[lane];
    uint4 q5 = ((const uint4*)((const char*)wsf + WS_F_W2))[lane];
    __builtin_memcpy(&FD0, &q0, 16);
    __builtin_memcpy(&FD1, &q1, 16);
    __builtin_memcpy(&FC0, &q2, 16);
    __builtin_memcpy(&FC1, &q3, 16);
    __builtin_memcpy(&FS, &q4, 16);
    __builtin_memcpy(&F2, &q5, 16);
  } else {
    const int m = lane & 15;
    uint32_t hw[4];
#pragma unroll
    for (int nt = 0; nt < 2; ++nt) {
      const int n = nt * 16 + m;
#pragma unroll
      for (int j2 = 0; j2 < 4; ++j2) {
        const int k = quad * 8 + j2 * 2;
        hw[j2] = (uint32_t)f2h(wd1_val(Wd1, bd1, k, n))
               | ((uint32_t)f2h(wd1_val(Wd1, bd1, k + 1, n)) << 16);
      }
      uint4 q = make_uint4(hw[0], hw[1], hw[2], hw[3]);
      if (nt == 0) __builtin_memcpy(&FD0, &q, 16);
      else         __builtin_memcpy(&FD1, &q, 16);
    }
#pragma unroll
    for (int nt = 0; nt < 2; ++nt) {
      const int n = nt * 16 + m;
#pragma unroll
      for (int j2 = 0; j2 < 4; ++j2) {
        const int kkA = kperm(quad, j2 * 2), kkB = kperm(quad, j2 * 2 + 1);
        hw[j2] = (uint32_t)f2h(Wc1[kkA * 32 + n])
               | ((uint32_t)f2h(Wc1[kkB * 32 + n]) << 16);
      }
      uint4 q = make_uint4(hw[0], hw[1], hw[2], hw[3]);
      if (nt == 0) __builtin_memcpy(&FC0, &q, 16);
      else         __builtin_memcpy(&FC1, &q, 16);
    }
#pragma unroll
    for (int j2 = 0; j2 < 4; ++j2) {
      const int kkA = kperm(quad, j2 * 2), kkB = kperm(quad, j2 * 2 + 1);
      const float va = (m == 0) ? Wd2[kkA] : 0.0f;
      const float vb = (m == 0) ? Wd2[kkB] : 0.0f;
      hw[j2] = (uint32_t)f2h(va) | ((uint32_t)f2h(vb) << 16);
    }
    { uint4 q = make_uint4(hw[0], hw[1], hw[2], hw[3]); __builtin_memcpy(&FS, &q, 16); }
#pragma unroll
    for (int j2 = 0; j2 < 4; ++j2) {
      const int kkA = kperm(quad, j2 * 2), kkB = kperm(quad, j2 * 2 + 1);
      const float va = (m < 3) ? Wc2[kkA * 3 + m] : 0.0f;
      const float vb = (m < 3) ? Wc2[kkB * 3 + m] : 0.0f;
      hw[j2] = (uint32_t)f2h(va) | ((uint32_t)f2h(vb) << 16);
    }
    { uint4 q = make_uint4(hw[0], hw[1], hw[2], hw[3]); __builtin_memcpy(&F2, &q, 16); }
  }

  // ---- fused fine density + color via MFMA chain (4 tiles/wave) ----
  {
    float dvv[2][4];
#pragma unroll
    for (int nt = 0; nt < 2; ++nt)
#pragma unroll
      for (int r = 0; r < 4; ++r) {
        const int n = nt * 16 + quad * 4 + r;
        const float4 nv = ldsf4(sw + NV4 + n * 4);
        dvv[nt][r] = nv.x + ndx * nv.y + ndy * nv.z + ndz * nv.w;
      }
    f32x4 c2init, sInit;
    {
      const float b0 = sw[BC2 + 0], b1 = sw[BC2 + 1], b2 = sw[BC2 + 2];
      const bool q0 = (quad == 0);
      c2init[0] = q0 ? b0 : 0.0f;
      c2init[1] = q0 ? b1 : 0.0f;
      c2init[2] = q0 ? b2 : 0.0f;
      c2init[3] = 0.0f;
      sInit[0] = q0 ? bd2v : 0.0f;
      sInit[1] = 0.0f; sInit[2] = 0.0f; sInit[3] = 0.0f;
    }

#pragma unroll
    for (int mt = 0; mt < 4; ++mt) {
      const int sbase = wv * 64 + mt * 16;
      // B-frag: point coords at k=0..3 (quad0 lanes), zeros elsewhere
      const uint2 pr = s_p[sbase + (lane & 15)];
      const uint32_t b0 = (quad == 0) ? pr.x : 0u;
      const uint32_t b1 = (quad == 0) ? pr.y : 0u;
      const uint4 bq = make_uint4(b0, b1, 0u, 0u);
      half8 Bp; __builtin_memcpy(&Bp, &bq, 16);

      const f32x4 z4 = {0.f, 0.f, 0.f, 0.f};
      f32x4 ad0 = __builtin_amdgcn_mfma_f32_16x16x32_f16(FD0, Bp, z4, 0, 0, 0);
      f32x4 ad1 = __builtin_amdgcn_mfma_f32_16x16x32_f16(FD1, Bp, z4, 0, 0, 0);

      // relu + pack density hidden -> B2 (k-permuted layout)
      const uint4 qb2 = make_uint4(
          pk2h(fmaxf(ad0[0], 0.0f), fmaxf(ad0[1], 0.0f)),
          pk2h(fmaxf(ad0[2], 0.0f), fmaxf(ad0[3], 0.0f)),
          pk2h(fmaxf(ad1[0], 0.0f), fmaxf(ad1[1], 0.0f)),
          pk2h(fmaxf(ad1[2], 0.0f), fmaxf(ad1[3], 0.0f)));
      half8 B2; __builtin_memcpy(&B2, &qb2, 16);

      // sigma row + color layer-1 (dv in acc init)
      f32x4 aS = __builtin_amdgcn_mfma_f32_16x16x32_f16(FS, B2, sInit, 0, 0, 0);
      f32x4 ac0 = {dvv[0][0], dvv[0][1], dvv[0][2], dvv[0][3]};
      f32x4 ac1 = {dvv[1][0], dvv[1][1], dvv[1][2], dvv[1][3]};
      ac0 = __builtin_amdgcn_mfma_f32_16x16x32_f16(FC0, B2, ac0, 0, 0, 0);
      ac1 = __builtin_amdgcn_mfma_f32_16x16x32_f16(FC1, B2, ac1, 0, 0, 0);

      const uint4 qb3 = make_uint4(
          pk2h(fmaxf(ac0[0], 0.0f), fmaxf(ac0[1], 0.0f)),
          pk2h(fmaxf(ac0[2], 0.0f), fmaxf(ac0[3], 0.0f)),
          pk2h(fmaxf(ac1[0], 0.0f), fmaxf(ac1[1], 0.0f)),
          pk2h(fmaxf(ac1[2], 0.0f), fmaxf(ac1[3], 0.0f)));
      half8 B3; __builtin_memcpy(&B3, &qb3, 16);

      f32x4 aC = __builtin_amdgcn_mfma_f32_16x16x32_f16(F2, B3, c2init, 0, 0, 0);

      if (quad == 0) {
        const int s = sbase + (lane & 15);
        s_sig[s] = aS[0];
        float4 og;
        og.x = fast_rcp(1.0f + __expf(-aC[0]));
        og.y = fast_rcp(1.0f + __expf(-aC[1]));
        og.z = fast_rcp(1.0f + __expf(-aC[2]));
        og.w = 0.0f;
        *(float4*)(s_rgb + s * RGBS) = og;
      }
    }
  }
  __syncthreads();   // s_sig + s_rgb staged

  // ---- fine alpha + parallel cumprod over 128 (DPP scan) ----
  const float sigf = softplus_f(s_sig[t]);
  const float deltaf = (t < SF - 1) ? (s_zlf[t + 1] - zlf) : 0.0f;
  const float vf = __expf(-sigf * deltaf);
  float fi = dpp_scan_mul(vf);
  if (lane == 63) s_tot[wv] = fi;
  __syncthreads();
  const float wf = (fast_rcp(vf) - 1.0f) * fi * (wv ? s_tot[0] : 1.0f);

  // ---- outputs ----
  float* o_img = out;
  float* o_w   = out + (size_t)n_rays * 3;
  float* o_z   = out + (size_t)n_rays * (3 + 128);
  float* o_inv = out + (size_t)n_rays * (3 + 256);

  o_w[(size_t)ray * 128 + t] = wf;
  o_z[(size_t)ray * 128 + t] = (zlf + 1.0f) * 0.5f;

  const float4 rg = *(const float4*)(s_rgb + t * RGBS);
  float r0 = wf * rg.x;
  float r1 = wf * rg.y;
  float r2 = wf * rg.z;
  float r3 = wf, r4 = wf * fast_rcp(zf);
  r0 = dpp_scan_add(r0);
  r1 = dpp_scan_add(r1);
  r2 = dpp_scan_add(r2);
  r3 = dpp_scan_add(r3);
  r4 = dpp_scan_add(r4);
  if (lane == 63) {
    float* p = &s_red[wv * 5];
    p[0] = r0; p[1] = r1; p[2] = r2; p[3] = r3; p[4] = r4;
  }
  __syncthreads();
  if (t == 0) {
    const float accw = s_red[3] + s_red[8];
    const float bgw = 1.0f - accw;
    o_img[(size_t)ray * 3 + 0] = (s_red[0] + s_red[5]) + bgw * bg[0];
    o_img[(size_t)ray * 3 + 1] = (s_red[1] + s_red[6]) + bgw * bg[1];
    o_img[(size_t)ray * 3 + 2] = (s_red[2] + s_red[7]) + bgw * bg[2];
    o_inv[ray] = s_red[4] + s_red[9];
  }
}

extern "C" void kernel_launch(void* const* d_in, const int* in_sizes, int n_in,
                              void* d_out, int out_size, void* d_ws, size_t ws_size,
                              hipStream_t stream) {
  const float* h   = (const float*)d_in[1];
  const float* w   = (const float*)d_in[2];
  const float* K   = (const float*)d_in[3];
  const float* E   = (const float*)d_in[4];
  const float* bg  = (const float*)d_in[5];
  const float* Wd1 = (const float*)d_in[6];
  const float* bd1 = (const float*)d_in[7];
  const float* Wd2 = (const float*)d_in[8];
  const float* bd2 = (const float*)d_in[9];
  const float* Wc1 = (const float*)d_in[10];
  const float* bc1 = (const float*)d_in[11];
  const float* Wc2 = (const float*)d_in[12];
  const float* bc2 = (const float*)d_in[13];
  const int n_rays = in_sizes[1];
  float* wsf = (float*)d_ws;

  if (ws_size >= WS_NEED) {
    pack_weights<<<1, PACK_NT, 0, stream>>>(K, Wd1, bd1, Wd2, bd2, Wc1, bc1, Wc2, bc2, wsf);
    nerf_fwd<true><<<n_rays, NT, 0, stream>>>(h, w, K, E, bg, Wd1, bd1, Wd2, bd2,
                                              Wc1, bc1, Wc2, bc2, wsf,
                                              (float*)d_out, n_rays);
  } else {
    nerf_fwd<false><<<n_rays, NT, 0, stream>>>(h, w, K, E, bg, Wd1, bd1, Wd2, bd2,
                                               Wc1, bc1, Wc2, bc2, nullptr,
                                               (float*)d_out, n_rays);
  }
}

// Round 6
// 141.698 us; speedup vs baseline: 1.0865x; 1.0189x over previous
//
#include <hip/hip_runtime.h>
#include <stdint.h>

#define SC 192      // coarse samples (128 + 64)
#define SF 128      // fine (importance) samples
#define NT 128      // threads per block = 2 waves
#define PACK_NT 128

// LDS weight-image offsets (floats)
#define BD2   0     // 1
#define BC2   1     // 3
#define NV4   4     // 32 x float4: (bc1[n], Wc1[32][n], Wc1[33][n], Wc1[34][n])
#define ZD    132   // 192 x float2: (z = 10^zlog_c(i), delta_c(i))
#define ZMID  516   // 192 floats: 0.5*(zlog_c(i)+zlog_c(i+1)) for i<191
#define SWTOT 708   // staged floats (177 float4s)

#define KINV  708   // ws float offset: 9 floats, row-major inv(K)
// fp16 MFMA A-frag tables in d_ws (64 lanes each)
#define WS_F_WD1 4096   // 128 x uint4: lane*2 -> {Wd1 units 0-15, units 16-31}, bias at k=3
#define WS_F_WC1 6144   // 128 x uint4: k-permuted Wc1 frags (match B2 layout)
#define WS_F_WD2 8192   // 64 x uint4: row0 = Wd2 k-permuted
#define WS_F_W2  9216   // 64 x uint4: rows 0-2 = Wc2 k-permuted
#define WS_NEED  10240

#define RGBS 4

using half8 = __attribute__((ext_vector_type(8))) _Float16;
using f32x4 = __attribute__((ext_vector_type(4))) float;
using f32x2 = __attribute__((ext_vector_type(2))) float;

__device__ __forceinline__ float zlog_c(int t) {
  return (t < 128) ? (-1.0f + (float)t * 0.0078125f)
                   : ((float)(t - 128) * 0.015625f);
}
__device__ __forceinline__ float delta_c(int t) {
  if (t >= SC - 1) return 0.0f;
  return zlog_c(t + 1) - zlog_c(t);
}

__device__ __forceinline__ float fast_rcp(float x) { return __builtin_amdgcn_rcpf(x); }
__device__ __forceinline__ float fast_rsq(float x) { return __builtin_amdgcn_rsqf(x); }
__device__ __forceinline__ float exp10_f(float x) { return __expf(x * 2.30258509299f); }
__device__ __forceinline__ float softplus_f(float x) {
  return fmaxf(x, 0.0f) + __logf(1.0f + __expf(-fabsf(x)));
}

// fp16 helpers
__device__ __forceinline__ uint32_t pk2h(float a, float b) {
  auto p = __builtin_amdgcn_cvt_pkrtz(a, b);
  uint32_t u; __builtin_memcpy(&u, &p, 4); return u;
}
__device__ __forceinline__ unsigned short f2h(float f) {
  _Float16 h = (_Float16)f;
  unsigned short us; __builtin_memcpy(&us, &h, 2); return us;
}

__device__ __forceinline__ float4 ldsf4(const float* p) { return *(const float4*)p; }

// k-permutation shared by all layer-2-style A-frags: frag position (q, j)
// holds source index (j<4 ? 4q+j : 16+4q+(j-4)) — matches B2 built from acc0/acc1.
__device__ __forceinline__ int kperm(int q, int j) {
  return (j < 4) ? (q * 4 + j) : (16 + q * 4 + (j - 4));
}

// ---- DPP cross-lane scans ----
template <int CTRL, int RMASK, int BMASK>
__device__ __forceinline__ float dpp_mov(float x, float oldv) {
  return __int_as_float(__builtin_amdgcn_update_dpp(
      __float_as_int(oldv), __float_as_int(x), CTRL, RMASK, BMASK, false));
}
__device__ __forceinline__ float dpp_scan_add(float v) {
  v += dpp_mov<0x111, 0xf, 0xf>(v, 0.0f);
  v += dpp_mov<0x112, 0xf, 0xf>(v, 0.0f);
  v += dpp_mov<0x114, 0xf, 0xf>(v, 0.0f);
  v += dpp_mov<0x118, 0xf, 0xf>(v, 0.0f);
  v += dpp_mov<0x142, 0xa, 0xf>(v, 0.0f);
  v += dpp_mov<0x143, 0xc, 0xf>(v, 0.0f);
  return v;
}
__device__ __forceinline__ float dpp_scan_mul(float v) {
  v *= dpp_mov<0x111, 0xf, 0xf>(v, 1.0f);
  v *= dpp_mov<0x112, 0xf, 0xf>(v, 1.0f);
  v *= dpp_mov<0x114, 0xf, 0xf>(v, 1.0f);
  v *= dpp_mov<0x118, 0xf, 0xf>(v, 1.0f);
  v *= dpp_mov<0x142, 0xa, 0xf>(v, 1.0f);
  v *= dpp_mov<0x143, 0xc, 0xf>(v, 1.0f);
  return v;
}

// JAX threefry2x32 with key = (0, 42)
__device__ __forceinline__ void threefry2x32_k42(uint32_t& x0, uint32_t& x1) {
  const uint32_t ks0 = 0u, ks1 = 42u;
  const uint32_t ks2 = ks0 ^ ks1 ^ 0x1BD11BDAu;
  const uint32_t ks[3] = {ks0, ks1, ks2};
  const int rot[2][4] = {{13, 15, 26, 6}, {17, 29, 16, 24}};
  x0 += ks[0];
  x1 += ks[1];
#pragma unroll
  for (int i = 0; i < 5; ++i) {
#pragma unroll
    for (int j = 0; j < 4; ++j) {
      x0 += x1;
      const int r = rot[i & 1][j];
      x1 = (x1 << r) | (x1 >> (32 - r));
      x1 ^= x0;
    }
    x0 += ks[(i + 1) % 3];
    x1 += ks[(i + 2) % 3] + (uint32_t)(i + 1);
  }
}

// value of Wd1-layer A-frag at (k, unit): k<3 -> Wd1[k][n], k==3 -> bd1[n], else 0
__device__ __forceinline__ float wd1_val(const float* Wd1, const float* bd1, int k, int n) {
  if (k < 3) return Wd1[k * 32 + n];
  if (k == 3) return bd1[n];
  return 0.0f;
}

// ---- pre-pack kernel ----
__global__ __launch_bounds__(PACK_NT) void pack_weights(
    const float* __restrict__ K,
    const float* __restrict__ Wd1, const float* __restrict__ bd1,
    const float* __restrict__ Wd2, const float* __restrict__ bd2,
    const float* __restrict__ Wc1, const float* __restrict__ bc1,
    const float* __restrict__ Wc2, const float* __restrict__ bc2,
    float* __restrict__ wsf) {
  const int t = threadIdx.x;
  for (int i = t; i < 192; i += PACK_NT) {
    wsf[ZD + 2 * i + 0] = exp10_f(zlog_c(i));
    wsf[ZD + 2 * i + 1] = delta_c(i);
    wsf[ZMID + i] = (i < 191) ? 0.5f * (zlog_c(i) + zlog_c(i + 1)) : 0.0f;
  }
  if (t == 0) {
    wsf[BD2] = bd2[0];
    wsf[BC2 + 0] = bc2[0]; wsf[BC2 + 1] = bc2[1]; wsf[BC2 + 2] = bc2[2];
    const float k00 = K[0], k01 = K[1], k02 = K[2];
    const float k10 = K[3], k11 = K[4], k12 = K[5];
    const float k20 = K[6], k21 = K[7], k22 = K[8];
    const float det = k00 * (k11 * k22 - k12 * k21)
                    - k01 * (k10 * k22 - k12 * k20)
                    + k02 * (k10 * k21 - k11 * k20);
    const float id = 1.0f / det;
    wsf[KINV + 0] =  (k11 * k22 - k12 * k21) * id;
    wsf[KINV + 1] = -(k01 * k22 - k02 * k21) * id;
    wsf[KINV + 2] =  (k01 * k12 - k02 * k11) * id;
    wsf[KINV + 3] = -(k10 * k22 - k12 * k20) * id;
    wsf[KINV + 4] =  (k00 * k22 - k02 * k20) * id;
    wsf[KINV + 5] = -(k00 * k12 - k02 * k10) * id;
    wsf[KINV + 6] =  (k10 * k21 - k11 * k20) * id;
    wsf[KINV + 7] = -(k00 * k21 - k01 * k20) * id;
    wsf[KINV + 8] =  (k00 * k11 - k01 * k10) * id;
  }
  if (t < 32) {
    wsf[NV4 + t * 4 + 0] = bc1[t];
    wsf[NV4 + t * 4 + 1] = Wc1[32 * 32 + t];
    wsf[NV4 + t * 4 + 2] = Wc1[33 * 32 + t];
    wsf[NV4 + t * 4 + 3] = Wc1[34 * 32 + t];
  }
  if (t < 64) {
    const int m = t & 15, q = t >> 4;
    // Wd1 A-frags (natural k order, bias at k=3, zeros k>=4)
    {
      uint4* fr = (uint4*)((char*)wsf + WS_F_WD1);
#pragma unroll
      for (int nt = 0; nt < 2; ++nt) {
        const int n = nt * 16 + m;
        uint32_t hw[4];
#pragma unroll
        for (int j2 = 0; j2 < 4; ++j2) {
          const int k = q * 8 + j2 * 2;
          hw[j2] = (uint32_t)f2h(wd1_val(Wd1, bd1, k, n))
                 | ((uint32_t)f2h(wd1_val(Wd1, bd1, k + 1, n)) << 16);
        }
        fr[t * 2 + nt] = make_uint4(hw[0], hw[1], hw[2], hw[3]);
      }
    }
    // Wc1 A-frags, k-PERMUTED to match B2 (built from density acc0/acc1)
    {
      uint4* fr = (uint4*)((char*)wsf + WS_F_WC1);
#pragma unroll
      for (int nt = 0; nt < 2; ++nt) {
        const int n = nt * 16 + m;
        uint32_t hw[4];
#pragma unroll
        for (int j2 = 0; j2 < 4; ++j2) {
          const int kkA = kperm(q, j2 * 2), kkB = kperm(q, j2 * 2 + 1);
          hw[j2] = (uint32_t)f2h(Wc1[kkA * 32 + n])
                 | ((uint32_t)f2h(Wc1[kkB * 32 + n]) << 16);
        }
        fr[t * 2 + nt] = make_uint4(hw[0], hw[1], hw[2], hw[3]);
      }
    }
    // Wd2 A-frag: row 0 = Wd2 (k-permuted), rows 1-15 zero
    {
      uint32_t hw[4];
#pragma unroll
      for (int j2 = 0; j2 < 4; ++j2) {
        const int kkA = kperm(q, j2 * 2), kkB = kperm(q, j2 * 2 + 1);
        const float va = (m == 0) ? Wd2[kkA] : 0.0f;
        const float vb = (m == 0) ? Wd2[kkB] : 0.0f;
        hw[j2] = (uint32_t)f2h(va) | ((uint32_t)f2h(vb) << 16);
      }
      ((uint4*)((char*)wsf + WS_F_WD2))[t] = make_uint4(hw[0], hw[1], hw[2], hw[3]);
    }
    // Wc2 A-frag: rows 0-2 = Wc2 (k-permuted, matches B3 from color acc0/acc1)
    {
      uint32_t hw[4];
#pragma unroll
      for (int j2 = 0; j2 < 4; ++j2) {
        const int kkA = kperm(q, j2 * 2), kkB = kperm(q, j2 * 2 + 1);
        const float va = (m < 3) ? Wc2[kkA * 3 + m] : 0.0f;
        const float vb = (m < 3) ? Wc2[kkB * 3 + m] : 0.0f;
        hw[j2] = (uint32_t)f2h(va) | ((uint32_t)f2h(vb) << 16);
      }
      ((uint4*)((char*)wsf + WS_F_W2))[t] = make_uint4(hw[0], hw[1], hw[2], hw[3]);
    }
  }
}

template <bool USE_WS>
__global__ __launch_bounds__(NT, 8) void nerf_fwd(
    const float* __restrict__ hh, const float* __restrict__ ww,
    const float* __restrict__ K, const float* __restrict__ E,
    const float* __restrict__ bg,
    const float* __restrict__ Wd1, const float* __restrict__ bd1,
    const float* __restrict__ Wd2, const float* __restrict__ bd2,
    const float* __restrict__ Wc1, const float* __restrict__ bc1,
    const float* __restrict__ Wc2, const float* __restrict__ bc2,
    const float* __restrict__ wsf,
    float* __restrict__ out, int n_rays) {
  const int ray = blockIdx.x;
  const int t = threadIdx.x;
  const int lane = t & 63;
  const int wv = t >> 6;   // 0 or 1
  const int quad = lane >> 4;

  __shared__ __align__(16) float sw[SWTOT];
  // union region (768 floats):
  //   coarse A: s_pc[192]x8B (u2[0..383]) + s_sigc[192] (u2[384..575])
  //   coarse B: s_w[192] (u2[0..191]) + s_cdf[192] (u2[192..383])
  //   fine:     s_p[128]x8B (u2[384..639]) + s_sig[128] (u2[640..767])
  __shared__ __align__(16) float u2[768];
  uint2* const s_pc   = (uint2*)u2;
  float* const s_sigc = u2 + 384;
  float* const s_w    = u2;
  float* const s_cdf  = u2 + 192;
  uint2* const s_p    = (uint2*)(u2 + 384);
  float* const s_sig  = u2 + 640;
  __shared__ float s_rgb[SF * RGBS];
  __shared__ float s_zlf[SF];
  __shared__ float s_tot[8];
  __shared__ float s_red[16];

  // ---- stage weight image + tables into LDS ----
  if constexpr (USE_WS) {
    const float4* wsrc = (const float4*)wsf;
    float4* sdst = (float4*)sw;
    for (int i = t; i < SWTOT / 4; i += NT) sdst[i] = wsrc[i];
  } else {
    for (int i = t; i < 192; i += NT) {
      sw[ZD + 2 * i + 0] = exp10_f(zlog_c(i));
      sw[ZD + 2 * i + 1] = delta_c(i);
      sw[ZMID + i] = (i < 191) ? 0.5f * (zlog_c(i) + zlog_c(i + 1)) : 0.0f;
    }
    if (t == 0) {
      sw[BD2] = bd2[0];
      sw[BC2 + 0] = bc2[0]; sw[BC2 + 1] = bc2[1]; sw[BC2 + 2] = bc2[2];
    }
    if (t < 32) {
      sw[NV4 + t * 4 + 0] = bc1[t];
      sw[NV4 + t * 4 + 1] = Wc1[32 * 32 + t];
      sw[NV4 + t * 4 + 2] = Wc1[33 * 32 + t];
      sw[NV4 + t * 4 + 3] = Wc1[34 * 32 + t];
    }
  }

  // ---- ray setup (block-uniform) ----
  float i00, i01, i02, i10, i11, i12, i20, i21, i22;
  if constexpr (USE_WS) {
    i00 = wsf[KINV + 0]; i01 = wsf[KINV + 1]; i02 = wsf[KINV + 2];
    i10 = wsf[KINV + 3]; i11 = wsf[KINV + 4]; i12 = wsf[KINV + 5];
    i20 = wsf[KINV + 6]; i21 = wsf[KINV + 7]; i22 = wsf[KINV + 8];
  } else {
    const float k00 = K[0], k01 = K[1], k02 = K[2];
    const float k10 = K[3], k11 = K[4], k12 = K[5];
    const float k20 = K[6], k21 = K[7], k22 = K[8];
    const float det = k00 * (k11 * k22 - k12 * k21)
                    - k01 * (k10 * k22 - k12 * k20)
                    + k02 * (k10 * k21 - k11 * k20);
    const float id = 1.0f / det;
    i00 =  (k11 * k22 - k12 * k21) * id;
    i01 = -(k01 * k22 - k02 * k21) * id;
    i02 =  (k01 * k12 - k02 * k11) * id;
    i10 = -(k10 * k22 - k12 * k20) * id;
    i11 =  (k00 * k22 - k02 * k20) * id;
    i12 = -(k00 * k12 - k02 * k10) * id;
    i20 =  (k10 * k21 - k11 * k20) * id;
    i21 = -(k00 * k21 - k01 * k20) * id;
    i22 =  (k00 * k11 - k01 * k10) * id;
  }

  const float dwx = ww[ray] + 0.5f;
  const float dwy = hh[ray] + 0.5f;
  const float cx = i00 * dwx + i01 * dwy + i02;
  const float cy = i10 * dwx + i11 * dwy + i12;
  const float cz = i20 * dwx + i21 * dwy + i22;
  const float* Er = E + (size_t)ray * 16;
  const float ox = Er[3], oy = Er[7], oz = Er[11];
  const float dx = Er[0] * cx + Er[1] * cy + Er[2] * cz;
  const float dy = Er[4] * cx + Er[5] * cy + Er[6] * cz;
  const float dz = Er[8] * cx + Er[9] * cy + Er[10] * cz;
  const float inv_nrm = fast_rsq(dx * dx + dy * dy + dz * dz);
  const float ndx = dx * inv_nrm, ndy = dy * inv_nrm, ndz = dz * inv_nrm;

  // ---- density A-frags (needed for coarse AND fine) ----
  half8 FD0, FD1, FS;
  if constexpr (USE_WS) {
    const uint4* fd = (const uint4*)((const char*)wsf + WS_F_WD1);
    uint4 q0 = fd[lane * 2 + 0], q1 = fd[lane * 2 + 1];
    uint4 q4 = ((const uint4*)((const char*)wsf + WS_F_WD2))[lane];
    __builtin_memcpy(&FD0, &q0, 16);
    __builtin_memcpy(&FD1, &q1, 16);
    __builtin_memcpy(&FS, &q4, 16);
  } else {
    const int m = lane & 15;
    uint32_t hw[4];
#pragma unroll
    for (int nt = 0; nt < 2; ++nt) {
      const int n = nt * 16 + m;
#pragma unroll
      for (int j2 = 0; j2 < 4; ++j2) {
        const int k = quad * 8 + j2 * 2;
        hw[j2] = (uint32_t)f2h(wd1_val(Wd1, bd1, k, n))
               | ((uint32_t)f2h(wd1_val(Wd1, bd1, k + 1, n)) << 16);
      }
      uint4 q = make_uint4(hw[0], hw[1], hw[2], hw[3]);
      if (nt == 0) __builtin_memcpy(&FD0, &q, 16);
      else         __builtin_memcpy(&FD1, &q, 16);
    }
#pragma unroll
    for (int j2 = 0; j2 < 4; ++j2) {
      const int kkA = kperm(quad, j2 * 2), kkB = kperm(quad, j2 * 2 + 1);
      const float va = (m == 0) ? Wd2[kkA] : 0.0f;
      const float vb = (m == 0) ? Wd2[kkB] : 0.0f;
      hw[j2] = (uint32_t)f2h(va) | ((uint32_t)f2h(vb) << 16);
    }
    { uint4 q = make_uint4(hw[0], hw[1], hw[2], hw[3]); __builtin_memcpy(&FS, &q, 16); }
  }

  __syncthreads();   // sw staged

  // ---- coarse points: e0 = t (all); e1 = 128+t (wave 0), packed fp16 -> s_pc ----
  const float2 zdA = *(const float2*)(sw + ZD + 2 * t);
  float2 zdB = make_float2(0.0f, 0.0f);
  {
    const float z = zdA.x;
    float px = ox + dx * z, py = oy + dy * z, pz = oz + dz * z;
    const float d2 = px * px + py * py + pz * pz;
    if (d2 > 1.0f) {
      const float invd = fast_rsq(d2);
      const float sc = (2.0f - invd) * invd;
      px *= sc; py *= sc; pz *= sc;
    }
    s_pc[t] = make_uint2(pk2h(px, py), pk2h(pz, 1.0f));
  }
  if (wv == 0) {
    zdB = *(const float2*)(sw + ZD + 2 * (128 + t));
    const float z = zdB.x;
    float px = ox + dx * z, py = oy + dy * z, pz = oz + dz * z;
    const float d2 = px * px + py * py + pz * pz;
    if (d2 > 1.0f) {
      const float invd = fast_rsq(d2);
      const float sc = (2.0f - invd) * invd;
      px *= sc; py *= sc; pz *= sc;
    }
    s_pc[128 + t] = make_uint2(pk2h(px, py), pk2h(pz, 1.0f));
  }
  const float bd2v = sw[BD2];
  __syncthreads();   // s_pc staged

  // ---- coarse density via MFMA: 12 tiles of 16 samples, 6 per wave ----
  {
    f32x4 sInit;
    sInit[0] = (quad == 0) ? bd2v : 0.0f;
    sInit[1] = 0.0f; sInit[2] = 0.0f; sInit[3] = 0.0f;
#pragma unroll
    for (int c6 = 0; c6 < 6; ++c6) {
      const int sbase = wv * 96 + c6 * 16;
      const uint2 pr = s_pc[sbase + (lane & 15)];
      const uint32_t b0 = (quad == 0) ? pr.x : 0u;
      const uint32_t b1 = (quad == 0) ? pr.y : 0u;
      const uint4 bq = make_uint4(b0, b1, 0u, 0u);
      half8 Bp; __builtin_memcpy(&Bp, &bq, 16);

      const f32x4 z4 = {0.f, 0.f, 0.f, 0.f};
      f32x4 ad0 = __builtin_amdgcn_mfma_f32_16x16x32_f16(FD0, Bp, z4, 0, 0, 0);
      f32x4 ad1 = __builtin_amdgcn_mfma_f32_16x16x32_f16(FD1, Bp, z4, 0, 0, 0);

      const uint4 qb2 = make_uint4(
          pk2h(fmaxf(ad0[0], 0.0f), fmaxf(ad0[1], 0.0f)),
          pk2h(fmaxf(ad0[2], 0.0f), fmaxf(ad0[3], 0.0f)),
          pk2h(fmaxf(ad1[0], 0.0f), fmaxf(ad1[1], 0.0f)),
          pk2h(fmaxf(ad1[2], 0.0f), fmaxf(ad1[3], 0.0f)));
      half8 B2; __builtin_memcpy(&B2, &qb2, 16);

      f32x4 aS = __builtin_amdgcn_mfma_f32_16x16x32_f16(FS, B2, sInit, 0, 0, 0);
      if (quad == 0) s_sigc[sbase + (lane & 15)] = aS[0];
    }
  }
  __syncthreads();   // s_sigc staged

  // ---- per-thread coarse alpha ----
  float v0, v1e = 1.0f;
  v0 = __expf(-softplus_f(s_sigc[t]) * zdA.y);
  if (wv == 0) v1e = __expf(-softplus_f(s_sigc[128 + t]) * zdB.y);

  // parallel cumprod of (1-alpha) — DPP scan
  float i0 = dpp_scan_mul(v0);
  float i1 = 1.0f;
  if (wv == 0) i1 = dpp_scan_mul(v1e);
  if (lane == 63) s_tot[wv] = i0;
  if (wv == 0 && lane == 63) s_tot[2] = i1;
  __syncthreads();
  {
    const float preC1 = s_tot[0];
    const float preC2 = s_tot[0] * s_tot[1];
    s_w[t] = (fast_rcp(v0) - 1.0f) * i0 * (wv ? preC1 : 1.0f);
    if (wv == 0) {
      s_w[128 + t] = (fast_rcp(v1e) - 1.0f) * i1 * preC2;
    }
  }
  __syncthreads();

  // reweight
  float wre0, wre1 = 0.0f;
  {
    const float wm = (t > 0) ? s_w[t - 1] : 0.0f;
    const float w0 = s_w[t];
    const float wp = s_w[t + 1];
    wre0 = 0.5f * (fmaxf(wm, w0) + fmaxf(w0, wp)) + (0.02f / 192.0f);
    wre0 *= (t < 128) ? (128.0f / 192.0f) : (64.0f / 192.0f);
  }
  if (wv == 0) {
    const int e = 128 + t;
    const float wm = s_w[e - 1];
    const float w0 = s_w[e];
    const float wp = (e < SC - 1) ? s_w[e + 1] : 0.0f;
    wre1 = 0.5f * (fmaxf(wm, w0) + fmaxf(w0, wp)) + (0.02f / 192.0f);
    wre1 *= (64.0f / 192.0f);
  }

  float s0 = dpp_scan_add(wre0);
  float s1 = 0.0f;
  if (wv == 0) s1 = dpp_scan_add(wre1);
  if (lane == 63) s_tot[4 + wv] = s0;
  if (wv == 0 && lane == 63) s_tot[6] = s1;
  __syncthreads();
  {
    const float T0 = s_tot[4], T1 = s_tot[5], T2 = s_tot[6];
    const float inv_total = fast_rcp(T0 + T1 + T2);
    s_cdf[t] = (s0 + (wv ? T0 : 0.0f)) * inv_total;
    if (wv == 0) s_cdf[128 + t] = (s1 + T0 + T1) * inv_total;
  }
  __syncthreads();

  // ---- importance sampling + fine point pack ----
  float zlf, zf;
  {
    float cA[7];
#pragma unroll
    for (int i = 0; i < 7; ++i) cA[i] = s_cdf[24 * i + 24];

    const uint32_t total = (uint32_t)n_rays * 128u;
    const uint32_t halfc = total >> 1;
    const uint32_t j = (uint32_t)ray * 128u + (uint32_t)t;
    uint32_t x0, x1;
    const bool first = (j < halfc);
    if (first) { x0 = j; x1 = j + halfc; } else { x0 = j - halfc; x1 = j; }
    threefry2x32_k42(x0, x1);
    const uint32_t bits = first ? x0 : x1;
    const float fr = __uint_as_float((bits >> 9) | 0x3f800000u) - 1.0f;

    float u = (float)t * 0.0078125f + fr * 0.0078125f;
    u = u * (s_cdf[190] - s_cdf[1]) + s_cdf[1];

    int start = 0;
#pragma unroll
    for (int i = 0; i < 7; ++i) start += (cA[i] <= u) ? 24 : 0;
    float cB[7];
#pragma unroll
    for (int i = 0; i < 7; ++i) cB[i] = s_cdf[start + 3 * i + 3];
    int st2 = start;
#pragma unroll
    for (int i = 0; i < 7; ++i) st2 += (cB[i] <= u) ? 3 : 0;
    const float p0 = s_cdf[st2];
    const float p1 = s_cdf[st2 + 1];
    const float p2 = s_cdf[st2 + 2];
    const float p3 = s_cdf[st2 + 3];
    const int k = ((p1 <= u) ? 1 : 0) + ((p2 <= u) ? 1 : 0);
    const int lo = st2 + k;
    const int inds = lo + 1;
    const float cb = (k == 0) ? p0 : ((k == 1) ? p1 : p2);
    const float ca = (k == 0) ? p1 : ((k == 1) ? p2 : p3);
    const float tt = (u - cb) * fast_rcp(ca - cb);
    const float zb = sw[ZMID + inds - 1];
    const float za = sw[ZMID + inds];
    zlf = zb + (za - zb) * tt;
    s_zlf[t] = zlf;
    zf = exp10_f(zlf);
  }
  __syncthreads();   // s_cdf reads done — region reusable for s_p
  {
    float px = ox + dx * zf, py = oy + dy * zf, pz = oz + dz * zf;
    const float d2 = px * px + py * py + pz * pz;
    if (d2 > 1.0f) {
      const float invd = fast_rsq(d2);
      const float sc = (2.0f - invd) * invd;
      px *= sc; py *= sc; pz *= sc;
    }
    s_p[t] = make_uint2(pk2h(px, py), pk2h(pz, 1.0f));
  }

  // ---- color A-frags (fp16) ----
  half8 FC0, FC1, F2;
  if constexpr (USE_WS) {
    const uint4* fc = (const uint4*)((const char*)wsf + WS_F_WC1);
    uint4 q2 = fc[lane * 2 + 0], q3 = fc[lane * 2 + 1];
    uint4 q5 = ((const uint4*)((const char*)wsf + WS_F_W2))[lane];
    __builtin_memcpy(&FC0, &q2, 16);
    __builtin_memcpy(&FC1, &q3, 16);
    __builtin_memcpy(&F2, &q5, 16);
  } else {
    const int m = lane & 15;
    uint32_t hw[4];
#pragma unroll
    for (int nt = 0; nt < 2; ++nt) {
      const int n = nt * 16 + m;
#pragma unroll
      for (int j2 = 0; j2 < 4; ++j2) {
        const int kkA = kperm(quad, j2 * 2), kkB = kperm(quad, j2 * 2 + 1);
        hw[j2] = (uint32_t)f2h(Wc1[kkA * 32 + n])
               | ((uint32_t)f2h(Wc1[kkB * 32 + n]) << 16);
      }
      uint4 q = make_uint4(hw[0], hw[1], hw[2], hw[3]);
      if (nt == 0) __builtin_memcpy(&FC0, &q, 16);
      else         __builtin_memcpy(&FC1, &q, 16);
    }
#pragma unroll
    for (int j2 = 0; j2 < 4; ++j2) {
      const int kkA = kperm(quad, j2 * 2), kkB = kperm(quad, j2 * 2 + 1);
      const float va = (m < 3) ? Wc2[kkA * 3 + m] : 0.0f;
      const float vb = (m < 3) ? Wc2[kkB * 3 + m] : 0.0f;
      hw[j2] = (uint32_t)f2h(va) | ((uint32_t)f2h(vb) << 16);
    }
    { uint4 q = make_uint4(hw[0], hw[1], hw[2], hw[3]); __builtin_memcpy(&F2, &q, 16); }
  }
  __syncthreads();   // s_p staged

  // ---- fused fine density + color via MFMA chain (4 tiles/wave) ----
  {
    float dvv[2][4];
#pragma unroll
    for (int nt = 0; nt < 2; ++nt)
#pragma unroll
      for (int r = 0; r < 4; ++r) {
        const int n = nt * 16 + quad * 4 + r;
        const float4 nv = ldsf4(sw + NV4 + n * 4);
        dvv[nt][r] = nv.x + ndx * nv.y + ndy * nv.z + ndz * nv.w;
      }
    f32x4 c2init, sInit;
    {
      const float b0 = sw[BC2 + 0], b1 = sw[BC2 + 1], b2 = sw[BC2 + 2];
      const bool q0 = (quad == 0);
      c2init[0] = q0 ? b0 : 0.0f;
      c2init[1] = q0 ? b1 : 0.0f;
      c2init[2] = q0 ? b2 : 0.0f;
      c2init[3] = 0.0f;
      sInit[0] = q0 ? bd2v : 0.0f;
      sInit[1] = 0.0f; sInit[2] = 0.0f; sInit[3] = 0.0f;
    }

#pragma unroll
    for (int mt = 0; mt < 4; ++mt) {
      const int sbase = wv * 64 + mt * 16;
      const uint2 pr = s_p[sbase + (lane & 15)];
      const uint32_t b0 = (quad == 0) ? pr.x : 0u;
      const uint32_t b1 = (quad == 0) ? pr.y : 0u;
      const uint4 bq = make_uint4(b0, b1, 0u, 0u);
      half8 Bp; __builtin_memcpy(&Bp, &bq, 16);

      const f32x4 z4 = {0.f, 0.f, 0.f, 0.f};
      f32x4 ad0 = __builtin_amdgcn_mfma_f32_16x16x32_f16(FD0, Bp, z4, 0, 0, 0);
      f32x4 ad1 = __builtin_amdgcn_mfma_f32_16x16x32_f16(FD1, Bp, z4, 0, 0, 0);

      const uint4 qb2 = make_uint4(
          pk2h(fmaxf(ad0[0], 0.0f), fmaxf(ad0[1], 0.0f)),
          pk2h(fmaxf(ad0[2], 0.0f), fmaxf(ad0[3], 0.0f)),
          pk2h(fmaxf(ad1[0], 0.0f), fmaxf(ad1[1], 0.0f)),
          pk2h(fmaxf(ad1[2], 0.0f), fmaxf(ad1[3], 0.0f)));
      half8 B2; __builtin_memcpy(&B2, &qb2, 16);

      f32x4 aS = __builtin_amdgcn_mfma_f32_16x16x32_f16(FS, B2, sInit, 0, 0, 0);
      f32x4 ac0 = {dvv[0][0], dvv[0][1], dvv[0][2], dvv[0][3]};
      f32x4 ac1 = {dvv[1][0], dvv[1][1], dvv[1][2], dvv[1][3]};
      ac0 = __builtin_amdgcn_mfma_f32_16x16x32_f16(FC0, B2, ac0, 0, 0, 0);
      ac1 = __builtin_amdgcn_mfma_f32_16x16x32_f16(FC1, B2, ac1, 0, 0, 0);

      const uint4 qb3 = make_uint4(
          pk2h(fmaxf(ac0[0], 0.0f), fmaxf(ac0[1], 0.0f)),
          pk2h(fmaxf(ac0[2], 0.0f), fmaxf(ac0[3], 0.0f)),
          pk2h(fmaxf(ac1[0], 0.0f), fmaxf(ac1[1], 0.0f)),
          pk2h(fmaxf(ac1[2], 0.0f), fmaxf(ac1[3], 0.0f)));
      half8 B3; __builtin_memcpy(&B3, &qb3, 16);

      f32x4 aC = __builtin_amdgcn_mfma_f32_16x16x32_f16(F2, B3, c2init, 0, 0, 0);

      if (quad == 0) {
        const int s = sbase + (lane & 15);
        s_sig[s] = aS[0];
        float4 og;
        og.x = fast_rcp(1.0f + __expf(-aC[0]));
        og.y = fast_rcp(1.0f + __expf(-aC[1]));
        og.z = fast_rcp(1.0f + __expf(-aC[2]));
        og.w = 0.0f;
        *(float4*)(s_rgb + s * RGBS) = og;
      }
    }
  }
  __syncthreads();   // s_sig + s_rgb staged

  // ---- fine alpha + parallel cumprod over 128 (DPP scan) ----
  const float sigf = softplus_f(s_sig[t]);
  const float deltaf = (t < SF - 1) ? (s_zlf[t + 1] - zlf) : 0.0f;
  const float vf = __expf(-sigf * deltaf);
  float fi = dpp_scan_mul(vf);
  if (lane == 63) s_tot[wv] = fi;
  __syncthreads();
  const float wf = (fast_rcp(vf) - 1.0f) * fi * (wv ? s_tot[0] : 1.0f);

  // ---- outputs ----
  float* o_img = out;
  float* o_w   = out + (size_t)n_rays * 3;
  float* o_z   = out + (size_t)n_rays * (3 + 128);
  float* o_inv = out + (size_t)n_rays * (3 + 256);

  o_w[(size_t)ray * 128 + t] = wf;
  o_z[(size_t)ray * 128 + t] = (zlf + 1.0f) * 0.5f;

  const float4 rg = *(const float4*)(s_rgb + t * RGBS);
  float r0 = wf * rg.x;
  float r1 = wf * rg.y;
  float r2 = wf * rg.z;
  float r3 = wf, r4 = wf * fast_rcp(zf);
  r0 = dpp_scan_add(r0);
  r1 = dpp_scan_add(r1);
  r2 = dpp_scan_add(r2);
  r3 = dpp_scan_add(r3);
  r4 = dpp_scan_add(r4);
  if (lane == 63) {
    float* p = &s_red[wv * 5];
    p[0] = r0; p[1] = r1; p[2] = r2; p[3] = r3; p[4] = r4;
  }
  __syncthreads();
  if (t == 0) {
    const float accw = s_red[3] + s_red[8];
    const float bgw = 1.0f - accw;
    o_img[(size_t)ray * 3 + 0] = (s_red[0] + s_red[5]) + bgw * bg[0];
    o_img[(size_t)ray * 3 + 1] = (s_red[1] + s_red[6]) + bgw * bg[1];
    o_img[(size_t)ray * 3 + 2] = (s_red[2] + s_red[7]) + bgw * bg[2];
    o_inv[ray] = s_red[4] + s_red[9];
  }
}

extern "C" void kernel_launch(void* const* d_in, const int* in_sizes, int n_in,
                              void* d_out, int out_size, void* d_ws, size_t ws_size,
                              hipStream_t stream) {
  const float* h   = (const float*)d_in[1];
  const float* w   = (const float*)d_in[2];
  const float* K   = (const float*)d_in[3];
  const float* E   = (const float*)d_in[4];
  const float* bg  = (const float*)d_in[5];
  const float* Wd1 = (const float*)d_in[6];
  const float* bd1 = (const float*)d_in[7];
  const float* Wd2 = (const float*)d_in[8];
  const float* bd2 = (const float*)d_in[9];
  const float* Wc1 = (const float*)d_in[10];
  const float* bc1 = (const float*)d_in[11];
  const float* Wc2 = (const float*)d_in[12];
  const float* bc2 = (const float*)d_in[13];
  const int n_rays = in_sizes[1];
  float* wsf = (float*)d_ws;

  if (ws_size >= WS_NEED) {
    pack_weights<<<1, PACK_NT, 0, stream>>>(K, Wd1, bd1, Wd2, bd2, Wc1, bc1, Wc2, bc2, wsf);
    nerf_fwd<true><<<n_rays, NT, 0, stream>>>(h, w, K, E, bg, Wd1, bd1, Wd2, bd2,
                                              Wc1, bc1, Wc2, bc2, wsf,
                                              (float*)d_out, n_rays);
  } else {
    nerf_fwd<false><<<n_rays, NT, 0, stream>>>(h, w, K, E, bg, Wd1, bd1, Wd2, bd2,
                                               Wc1, bc1, Wc2, bc2, nullptr,
                                               (float*)d_out, n_rays);
  }
}

// Round 7
// 141.161 us; speedup vs baseline: 1.0907x; 1.0038x over previous
//
#include <hip/hip_runtime.h>
#include <stdint.h>

#define SC 192      // coarse samples (128 + 64)
#define SF 128      // fine (importance) samples
#define NT 128      // threads per block = 2 waves = 2 rays (one ray per wave)
#define PACK_NT 128

// LDS weight-image offsets (floats)
#define BD2   0     // 1
#define BC2   1     // 3
#define NV4   4     // 32 x float4: (bc1[n], Wc1[32][n], Wc1[33][n], Wc1[34][n])
#define ZD    132   // 192 x float2: (z = 10^zlog_c(i), delta_c(i))
#define ZMID  516   // 192 floats: 0.5*(zlog_c(i)+zlog_c(i+1)) for i<191
#define SWTOT 708   // staged floats (177 float4s)

#define KINV  708   // ws float offset: 9 floats, row-major inv(K)
// fp16 MFMA A-frag tables in d_ws (64 lanes each)
#define WS_F_WD1 4096   // 128 x uint4: lane*2 -> {Wd1 units 0-15, units 16-31}, bias at k=3
#define WS_F_WC1 6144   // 128 x uint4: k-permuted Wc1 frags (match B2 layout)
#define WS_F_WD2 8192   // 64 x uint4: row0 = Wd2 k-permuted
#define WS_F_W2  9216   // 64 x uint4: rows 0-2 = Wc2 k-permuted
#define WS_NEED  10240

#define RGBS 4
// per-ray LDS region (bytes): [0..1535] coarse pts / aliased sigc,w,cdf,p,sig
// [1792..2303] zlf, [2304..4351] rgb
#define RAYB 4352

using half8 = __attribute__((ext_vector_type(8))) _Float16;
using f32x4 = __attribute__((ext_vector_type(4))) float;

__device__ __forceinline__ float zlog_c(int t) {
  return (t < 128) ? (-1.0f + (float)t * 0.0078125f)
                   : ((float)(t - 128) * 0.015625f);
}
__device__ __forceinline__ float delta_c(int t) {
  if (t >= SC - 1) return 0.0f;
  return zlog_c(t + 1) - zlog_c(t);
}

__device__ __forceinline__ float fast_rcp(float x) { return __builtin_amdgcn_rcpf(x); }
__device__ __forceinline__ float fast_rsq(float x) { return __builtin_amdgcn_rsqf(x); }
__device__ __forceinline__ float exp10_f(float x) { return __expf(x * 2.30258509299f); }
__device__ __forceinline__ float softplus_f(float x) {
  return fmaxf(x, 0.0f) + __logf(1.0f + __expf(-fabsf(x)));
}

// fp16 helpers
__device__ __forceinline__ uint32_t pk2h(float a, float b) {
  auto p = __builtin_amdgcn_cvt_pkrtz(a, b);
  uint32_t u; __builtin_memcpy(&u, &p, 4); return u;
}
__device__ __forceinline__ unsigned short f2h(float f) {
  _Float16 h = (_Float16)f;
  unsigned short us; __builtin_memcpy(&us, &h, 2); return us;
}

__device__ __forceinline__ float4 ldsf4(const float* p) { return *(const float4*)p; }

// k-permutation shared by all layer-2-style A-frags (matches B2 from acc0/acc1)
__device__ __forceinline__ int kperm(int q, int j) {
  return (j < 4) ? (q * 4 + j) : (16 + q * 4 + (j - 4));
}

// ---- DPP cross-lane scans (VALU pipe) ----
template <int CTRL, int RMASK, int BMASK>
__device__ __forceinline__ float dpp_mov(float x, float oldv) {
  return __int_as_float(__builtin_amdgcn_update_dpp(
      __float_as_int(oldv), __float_as_int(x), CTRL, RMASK, BMASK, false));
}
__device__ __forceinline__ float dpp_scan_add(float v) {
  v += dpp_mov<0x111, 0xf, 0xf>(v, 0.0f);
  v += dpp_mov<0x112, 0xf, 0xf>(v, 0.0f);
  v += dpp_mov<0x114, 0xf, 0xf>(v, 0.0f);
  v += dpp_mov<0x118, 0xf, 0xf>(v, 0.0f);
  v += dpp_mov<0x142, 0xa, 0xf>(v, 0.0f);
  v += dpp_mov<0x143, 0xc, 0xf>(v, 0.0f);
  return v;
}
__device__ __forceinline__ float dpp_scan_mul(float v) {
  v *= dpp_mov<0x111, 0xf, 0xf>(v, 1.0f);
  v *= dpp_mov<0x112, 0xf, 0xf>(v, 1.0f);
  v *= dpp_mov<0x114, 0xf, 0xf>(v, 1.0f);
  v *= dpp_mov<0x118, 0xf, 0xf>(v, 1.0f);
  v *= dpp_mov<0x142, 0xa, 0xf>(v, 1.0f);
  v *= dpp_mov<0x143, 0xc, 0xf>(v, 1.0f);
  return v;
}
__device__ __forceinline__ float readlane_f(float v, int l) {
  return __int_as_float(__builtin_amdgcn_readlane(__float_as_int(v), l));
}

// JAX threefry2x32 with key = (0, 42)
__device__ __forceinline__ void threefry2x32_k42(uint32_t& x0, uint32_t& x1) {
  const uint32_t ks0 = 0u, ks1 = 42u;
  const uint32_t ks2 = ks0 ^ ks1 ^ 0x1BD11BDAu;
  const uint32_t ks[3] = {ks0, ks1, ks2};
  const int rot[2][4] = {{13, 15, 26, 6}, {17, 29, 16, 24}};
  x0 += ks[0];
  x1 += ks[1];
#pragma unroll
  for (int i = 0; i < 5; ++i) {
#pragma unroll
    for (int j = 0; j < 4; ++j) {
      x0 += x1;
      const int r = rot[i & 1][j];
      x1 = (x1 << r) | (x1 >> (32 - r));
      x1 ^= x0;
    }
    x0 += ks[(i + 1) % 3];
    x1 += ks[(i + 2) % 3] + (uint32_t)(i + 1);
  }
}

// value of Wd1-layer A-frag at (k, unit): k<3 -> Wd1[k][n], k==3 -> bd1[n], else 0
__device__ __forceinline__ float wd1_val(const float* Wd1, const float* bd1, int k, int n) {
  if (k < 3) return Wd1[k * 32 + n];
  if (k == 3) return bd1[n];
  return 0.0f;
}

// ---- pre-pack kernel (unchanged from R6) ----
__global__ __launch_bounds__(PACK_NT) void pack_weights(
    const float* __restrict__ K,
    const float* __restrict__ Wd1, const float* __restrict__ bd1,
    const float* __restrict__ Wd2, const float* __restrict__ bd2,
    const float* __restrict__ Wc1, const float* __restrict__ bc1,
    const float* __restrict__ Wc2, const float* __restrict__ bc2,
    float* __restrict__ wsf) {
  const int t = threadIdx.x;
  for (int i = t; i < 192; i += PACK_NT) {
    wsf[ZD + 2 * i + 0] = exp10_f(zlog_c(i));
    wsf[ZD + 2 * i + 1] = delta_c(i);
    wsf[ZMID + i] = (i < 191) ? 0.5f * (zlog_c(i) + zlog_c(i + 1)) : 0.0f;
  }
  if (t == 0) {
    wsf[BD2] = bd2[0];
    wsf[BC2 + 0] = bc2[0]; wsf[BC2 + 1] = bc2[1]; wsf[BC2 + 2] = bc2[2];
    const float k00 = K[0], k01 = K[1], k02 = K[2];
    const float k10 = K[3], k11 = K[4], k12 = K[5];
    const float k20 = K[6], k21 = K[7], k22 = K[8];
    const float det = k00 * (k11 * k22 - k12 * k21)
                    - k01 * (k10 * k22 - k12 * k20)
                    + k02 * (k10 * k21 - k11 * k20);
    const float id = 1.0f / det;
    wsf[KINV + 0] =  (k11 * k22 - k12 * k21) * id;
    wsf[KINV + 1] = -(k01 * k22 - k02 * k21) * id;
    wsf[KINV + 2] =  (k01 * k12 - k02 * k11) * id;
    wsf[KINV + 3] = -(k10 * k22 - k12 * k20) * id;
    wsf[KINV + 4] =  (k00 * k22 - k02 * k20) * id;
    wsf[KINV + 5] = -(k00 * k12 - k02 * k10) * id;
    wsf[KINV + 6] =  (k10 * k21 - k11 * k20) * id;
    wsf[KINV + 7] = -(k00 * k21 - k01 * k20) * id;
    wsf[KINV + 8] =  (k00 * k11 - k01 * k10) * id;
  }
  if (t < 32) {
    wsf[NV4 + t * 4 + 0] = bc1[t];
    wsf[NV4 + t * 4 + 1] = Wc1[32 * 32 + t];
    wsf[NV4 + t * 4 + 2] = Wc1[33 * 32 + t];
    wsf[NV4 + t * 4 + 3] = Wc1[34 * 32 + t];
  }
  if (t < 64) {
    const int m = t & 15, q = t >> 4;
    {
      uint4* fr = (uint4*)((char*)wsf + WS_F_WD1);
#pragma unroll
      for (int nt = 0; nt < 2; ++nt) {
        const int n = nt * 16 + m;
        uint32_t hw[4];
#pragma unroll
        for (int j2 = 0; j2 < 4; ++j2) {
          const int k = q * 8 + j2 * 2;
          hw[j2] = (uint32_t)f2h(wd1_val(Wd1, bd1, k, n))
                 | ((uint32_t)f2h(wd1_val(Wd1, bd1, k + 1, n)) << 16);
        }
        fr[t * 2 + nt] = make_uint4(hw[0], hw[1], hw[2], hw[3]);
      }
    }
    {
      uint4* fr = (uint4*)((char*)wsf + WS_F_WC1);
#pragma unroll
      for (int nt = 0; nt < 2; ++nt) {
        const int n = nt * 16 + m;
        uint32_t hw[4];
#pragma unroll
        for (int j2 = 0; j2 < 4; ++j2) {
          const int kkA = kperm(q, j2 * 2), kkB = kperm(q, j2 * 2 + 1);
          hw[j2] = (uint32_t)f2h(Wc1[kkA * 32 + n])
                 | ((uint32_t)f2h(Wc1[kkB * 32 + n]) << 16);
        }
        fr[t * 2 + nt] = make_uint4(hw[0], hw[1], hw[2], hw[3]);
      }
    }
    {
      uint32_t hw[4];
#pragma unroll
      for (int j2 = 0; j2 < 4; ++j2) {
        const int kkA = kperm(q, j2 * 2), kkB = kperm(q, j2 * 2 + 1);
        const float va = (m == 0) ? Wd2[kkA] : 0.0f;
        const float vb = (m == 0) ? Wd2[kkB] : 0.0f;
        hw[j2] = (uint32_t)f2h(va) | ((uint32_t)f2h(vb) << 16);
      }
      ((uint4*)((char*)wsf + WS_F_WD2))[t] = make_uint4(hw[0], hw[1], hw[2], hw[3]);
    }
    {
      uint32_t hw[4];
#pragma unroll
      for (int j2 = 0; j2 < 4; ++j2) {
        const int kkA = kperm(q, j2 * 2), kkB = kperm(q, j2 * 2 + 1);
        const float va = (m < 3) ? Wc2[kkA * 3 + m] : 0.0f;
        const float vb = (m < 3) ? Wc2[kkB * 3 + m] : 0.0f;
        hw[j2] = (uint32_t)f2h(va) | ((uint32_t)f2h(vb) << 16);
      }
      ((uint4*)((char*)wsf + WS_F_W2))[t] = make_uint4(hw[0], hw[1], hw[2], hw[3]);
    }
  }
}

template <bool USE_WS>
__global__ __launch_bounds__(NT, 6) void nerf_fwd(
    const float* __restrict__ hh, const float* __restrict__ ww,
    const float* __restrict__ K, const float* __restrict__ E,
    const float* __restrict__ bg,
    const float* __restrict__ Wd1, const float* __restrict__ bd1,
    const float* __restrict__ Wd2, const float* __restrict__ bd2,
    const float* __restrict__ Wc1, const float* __restrict__ bc1,
    const float* __restrict__ Wc2, const float* __restrict__ bc2,
    const float* __restrict__ wsf,
    float* __restrict__ out, int n_rays) {
  const int t = threadIdx.x;
  const int lane = t & 63;
  const int wv = t >> 6;   // wave = ray within block
  const int quad = lane >> 4;

  __shared__ __align__(16) float sw[SWTOT];
  __shared__ __align__(16) unsigned char ubuf[2][RAYB];

  unsigned char* const rb = ubuf[wv];
  uint2* const s_pc   = (uint2*)rb;             // coarse pts 192x8B [0..1535]
  float* const s_sigc = (float*)rb;             // 192x4 (aliases pc low; per-tile safe)
  float* const s_w    = (float*)(rb + 768);     // 192x4 (pc dead)
  float* const s_cdf  = (float*)rb;             // 192x4 (sigc dead)
  uint2* const s_p    = (uint2*)(rb + 768);     // fine pts 128x8B (w dead)
  float* const s_sig  = (float*)rb;             // 128x4 (cdf dead)
  float* const s_zlf  = (float*)(rb + 1792);    // 128x4
  float* const s_rgb  = (float*)(rb + 2304);    // 128x16B

  // ---- stage weight image + tables into LDS (both waves cooperate) ----
  if constexpr (USE_WS) {
    const float4* wsrc = (const float4*)wsf;
    float4* sdst = (float4*)sw;
    for (int i = t; i < SWTOT / 4; i += NT) sdst[i] = wsrc[i];
  } else {
    for (int i = t; i < 192; i += NT) {
      sw[ZD + 2 * i + 0] = exp10_f(zlog_c(i));
      sw[ZD + 2 * i + 1] = delta_c(i);
      sw[ZMID + i] = (i < 191) ? 0.5f * (zlog_c(i) + zlog_c(i + 1)) : 0.0f;
    }
    if (t == 0) {
      sw[BD2] = bd2[0];
      sw[BC2 + 0] = bc2[0]; sw[BC2 + 1] = bc2[1]; sw[BC2 + 2] = bc2[2];
    }
    if (t < 32) {
      sw[NV4 + t * 4 + 0] = bc1[t];
      sw[NV4 + t * 4 + 1] = Wc1[32 * 32 + t];
      sw[NV4 + t * 4 + 2] = Wc1[33 * 32 + t];
      sw[NV4 + t * 4 + 3] = Wc1[34 * 32 + t];
    }
  }

  // ---- ray id (wave-uniform, forced scalar) ----
  int ray_ = blockIdx.x * 2 + wv;
  if (ray_ >= n_rays) ray_ = n_rays - 1;
  const int ray = __builtin_amdgcn_readfirstlane(ray_);

  // ---- ray setup ----
  float i00, i01, i02, i10, i11, i12, i20, i21, i22;
  if constexpr (USE_WS) {
    i00 = wsf[KINV + 0]; i01 = wsf[KINV + 1]; i02 = wsf[KINV + 2];
    i10 = wsf[KINV + 3]; i11 = wsf[KINV + 4]; i12 = wsf[KINV + 5];
    i20 = wsf[KINV + 6]; i21 = wsf[KINV + 7]; i22 = wsf[KINV + 8];
  } else {
    const float k00 = K[0], k01 = K[1], k02 = K[2];
    const float k10 = K[3], k11 = K[4], k12 = K[5];
    const float k20 = K[6], k21 = K[7], k22 = K[8];
    const float det = k00 * (k11 * k22 - k12 * k21)
                    - k01 * (k10 * k22 - k12 * k20)
                    + k02 * (k10 * k21 - k11 * k20);
    const float id = 1.0f / det;
    i00 =  (k11 * k22 - k12 * k21) * id;
    i01 = -(k01 * k22 - k02 * k21) * id;
    i02 =  (k01 * k12 - k02 * k11) * id;
    i10 = -(k10 * k22 - k12 * k20) * id;
    i11 =  (k00 * k22 - k02 * k20) * id;
    i12 = -(k00 * k12 - k02 * k10) * id;
    i20 =  (k10 * k21 - k11 * k20) * id;
    i21 = -(k00 * k21 - k01 * k20) * id;
    i22 =  (k00 * k11 - k01 * k10) * id;
  }

  const float dwx = ww[ray] + 0.5f;
  const float dwy = hh[ray] + 0.5f;
  const float cx = i00 * dwx + i01 * dwy + i02;
  const float cy = i10 * dwx + i11 * dwy + i12;
  const float cz = i20 * dwx + i21 * dwy + i22;
  const float* Er = E + (size_t)ray * 16;
  const float ox = Er[3], oy = Er[7], oz = Er[11];
  const float dx = Er[0] * cx + Er[1] * cy + Er[2] * cz;
  const float dy = Er[4] * cx + Er[5] * cy + Er[6] * cz;
  const float dz = Er[8] * cx + Er[9] * cy + Er[10] * cz;
  const float inv_nrm = fast_rsq(dx * dx + dy * dy + dz * dz);
  const float ndx = dx * inv_nrm, ndy = dy * inv_nrm, ndz = dz * inv_nrm;

  // ---- density A-frags (coarse + fine) ----
  half8 FD0, FD1, FS;
  if constexpr (USE_WS) {
    const uint4* fd = (const uint4*)((const char*)wsf + WS_F_WD1);
    uint4 q0 = fd[lane * 2 + 0], q1 = fd[lane * 2 + 1];
    uint4 q4 = ((const uint4*)((const char*)wsf + WS_F_WD2))[lane];
    __builtin_memcpy(&FD0, &q0, 16);
    __builtin_memcpy(&FD1, &q1, 16);
    __builtin_memcpy(&FS, &q4, 16);
  } else {
    const int m = lane & 15;
    uint32_t hw[4];
#pragma unroll
    for (int nt = 0; nt < 2; ++nt) {
      const int n = nt * 16 + m;
#pragma unroll
      for (int j2 = 0; j2 < 4; ++j2) {
        const int k = quad * 8 + j2 * 2;
        hw[j2] = (uint32_t)f2h(wd1_val(Wd1, bd1, k, n))
               | ((uint32_t)f2h(wd1_val(Wd1, bd1, k + 1, n)) << 16);
      }
      uint4 q = make_uint4(hw[0], hw[1], hw[2], hw[3]);
      if (nt == 0) __builtin_memcpy(&FD0, &q, 16);
      else         __builtin_memcpy(&FD1, &q, 16);
    }
#pragma unroll
    for (int j2 = 0; j2 < 4; ++j2) {
      const int kkA = kperm(quad, j2 * 2), kkB = kperm(quad, j2 * 2 + 1);
      const float va = (m == 0) ? Wd2[kkA] : 0.0f;
      const float vb = (m == 0) ? Wd2[kkB] : 0.0f;
      hw[j2] = (uint32_t)f2h(va) | ((uint32_t)f2h(vb) << 16);
    }
    { uint4 q = make_uint4(hw[0], hw[1], hw[2], hw[3]); __builtin_memcpy(&FS, &q, 16); }
  }

  __syncthreads();   // the ONLY barrier: sw staged

  const float bd2v = sw[BD2];

  // ---- coarse points: lane owns e = lane, lane+64, lane+128 ----
  float2 zd[3];
#pragma unroll
  for (int q3 = 0; q3 < 3; ++q3) {
    const int e = lane + 64 * q3;
    zd[q3] = *(const float2*)(sw + ZD + 2 * e);
    const float z = zd[q3].x;
    float px = ox + dx * z, py = oy + dy * z, pz = oz + dz * z;
    const float d2 = px * px + py * py + pz * pz;
    if (d2 > 1.0f) {
      const float invd = fast_rsq(d2);
      const float sc = (2.0f - invd) * invd;
      px *= sc; py *= sc; pz *= sc;
    }
    s_pc[e] = make_uint2(pk2h(px, py), pk2h(pz, 1.0f));
  }

  // ---- coarse density via MFMA: 12 tiles per wave (same-wave LDS, no barrier) ----
  {
    f32x4 sInit;
    sInit[0] = (quad == 0) ? bd2v : 0.0f;
    sInit[1] = 0.0f; sInit[2] = 0.0f; sInit[3] = 0.0f;
#pragma unroll
    for (int T = 0; T < 12; ++T) {
      const int sbase = T * 16;
      const uint2 pr = s_pc[sbase + (lane & 15)];
      const uint32_t b0 = (quad == 0) ? pr.x : 0u;
      const uint32_t b1 = (quad == 0) ? pr.y : 0u;
      const uint4 bq = make_uint4(b0, b1, 0u, 0u);
      half8 Bp; __builtin_memcpy(&Bp, &bq, 16);

      const f32x4 z4 = {0.f, 0.f, 0.f, 0.f};
      f32x4 ad0 = __builtin_amdgcn_mfma_f32_16x16x32_f16(FD0, Bp, z4, 0, 0, 0);
      f32x4 ad1 = __builtin_amdgcn_mfma_f32_16x16x32_f16(FD1, Bp, z4, 0, 0, 0);

      const uint4 qb2 = make_uint4(
          pk2h(fmaxf(ad0[0], 0.0f), fmaxf(ad0[1], 0.0f)),
          pk2h(fmaxf(ad0[2], 0.0f), fmaxf(ad0[3], 0.0f)),
          pk2h(fmaxf(ad1[0], 0.0f), fmaxf(ad1[1], 0.0f)),
          pk2h(fmaxf(ad1[2], 0.0f), fmaxf(ad1[3], 0.0f)));
      half8 B2; __builtin_memcpy(&B2, &qb2, 16);

      f32x4 aS = __builtin_amdgcn_mfma_f32_16x16x32_f16(FS, B2, sInit, 0, 0, 0);
      if (quad == 0) s_sigc[sbase + (lane & 15)] = aS[0];
    }
  }

  // ---- coarse alpha (3 per lane) ----
  float v3[3];
#pragma unroll
  for (int q3 = 0; q3 < 3; ++q3) {
    const int e = lane + 64 * q3;
    v3[q3] = __expf(-softplus_f(s_sigc[e]) * zd[q3].y);
  }

  // cumprod over 192: three 64-wide DPP scans + readlane carries (R6 association)
  {
    const float s0 = dpp_scan_mul(v3[0]);
    const float c0 = readlane_f(s0, 63);
    const float s1 = dpp_scan_mul(v3[1]);
    const float c01 = c0 * readlane_f(s1, 63);
    const float s2 = dpp_scan_mul(v3[2]);
    s_w[lane]       = (fast_rcp(v3[0]) - 1.0f) * s0 * 1.0f;
    s_w[lane + 64]  = (fast_rcp(v3[1]) - 1.0f) * s1 * c0;
    s_w[lane + 128] = (fast_rcp(v3[2]) - 1.0f) * s2 * c01;
  }

  // reweight (3 per lane, neighbor reads via same-wave LDS)
  float wre[3];
#pragma unroll
  for (int q3 = 0; q3 < 3; ++q3) {
    const int e = lane + 64 * q3;
    const float wm = (e > 0) ? s_w[e - 1] : 0.0f;
    const float w0 = s_w[e];
    const float wp = (e < SC - 1) ? s_w[e + 1] : 0.0f;
    wre[q3] = 0.5f * (fmaxf(wm, w0) + fmaxf(w0, wp)) + (0.02f / 192.0f);
    wre[q3] *= (e < 128) ? (128.0f / 192.0f) : (64.0f / 192.0f);
  }

  // cumsum over 192 -> normalized CDF (R6 association)
  {
    const float a0 = dpp_scan_add(wre[0]);
    const float T0 = readlane_f(a0, 63);
    const float a1 = dpp_scan_add(wre[1]);
    const float T1 = readlane_f(a1, 63);
    const float a2 = dpp_scan_add(wre[2]);
    const float T2 = readlane_f(a2, 63);
    const float inv_total = fast_rcp(T0 + T1 + T2);
    s_cdf[lane]       = (a0 + 0.0f) * inv_total;
    s_cdf[lane + 64]  = (a1 + T0) * inv_total;
    s_cdf[lane + 128] = (a2 + T0 + T1) * inv_total;
  }

  // ---- importance sampling: lane owns s = lane, lane+64 ----
  float zlfv[2], zfv[2];
  {
    float cA[7];
#pragma unroll
    for (int i = 0; i < 7; ++i) cA[i] = s_cdf[24 * i + 24];
    const float cdf1 = s_cdf[1], cdf190 = s_cdf[190];
    const uint32_t total = (uint32_t)n_rays * 128u;
    const uint32_t halfc = total >> 1;

#pragma unroll
    for (int h2 = 0; h2 < 2; ++h2) {
      const int s = lane + 64 * h2;
      const uint32_t j = (uint32_t)ray * 128u + (uint32_t)s;
      uint32_t x0, x1;
      const bool first = (j < halfc);
      if (first) { x0 = j; x1 = j + halfc; } else { x0 = j - halfc; x1 = j; }
      threefry2x32_k42(x0, x1);
      const uint32_t bits = first ? x0 : x1;
      const float fr = __uint_as_float((bits >> 9) | 0x3f800000u) - 1.0f;

      float u = (float)s * 0.0078125f + fr * 0.0078125f;
      u = u * (cdf190 - cdf1) + cdf1;

      int start = 0;
#pragma unroll
      for (int i = 0; i < 7; ++i) start += (cA[i] <= u) ? 24 : 0;
      float cB[7];
#pragma unroll
      for (int i = 0; i < 7; ++i) cB[i] = s_cdf[start + 3 * i + 3];
      int st2 = start;
#pragma unroll
      for (int i = 0; i < 7; ++i) st2 += (cB[i] <= u) ? 3 : 0;
      const float p0 = s_cdf[st2];
      const float p1 = s_cdf[st2 + 1];
      const float p2 = s_cdf[st2 + 2];
      const float p3 = s_cdf[st2 + 3];
      const int k = ((p1 <= u) ? 1 : 0) + ((p2 <= u) ? 1 : 0);
      const int lo = st2 + k;
      const int inds = lo + 1;
      const float cb = (k == 0) ? p0 : ((k == 1) ? p1 : p2);
      const float ca = (k == 0) ? p1 : ((k == 1) ? p2 : p3);
      const float tt = (u - cb) * fast_rcp(ca - cb);
      const float zb = sw[ZMID + inds - 1];
      const float za = sw[ZMID + inds];
      const float zl = zb + (za - zb) * tt;
      zlfv[h2] = zl;
      s_zlf[s] = zl;
      const float zf = exp10_f(zl);
      zfv[h2] = zf;

      float px = ox + dx * zf, py = oy + dy * zf, pz = oz + dz * zf;
      const float d2 = px * px + py * py + pz * pz;
      if (d2 > 1.0f) {
        const float invd = fast_rsq(d2);
        const float sc = (2.0f - invd) * invd;
        px *= sc; py *= sc; pz *= sc;
      }
      s_p[s] = make_uint2(pk2h(px, py), pk2h(pz, 1.0f));
    }
  }

  // ---- color A-frags ----
  half8 FC0, FC1, F2;
  if constexpr (USE_WS) {
    const uint4* fc = (const uint4*)((const char*)wsf + WS_F_WC1);
    uint4 q2 = fc[lane * 2 + 0], q3 = fc[lane * 2 + 1];
    uint4 q5 = ((const uint4*)((const char*)wsf + WS_F_W2))[lane];
    __builtin_memcpy(&FC0, &q2, 16);
    __builtin_memcpy(&FC1, &q3, 16);
    __builtin_memcpy(&F2, &q5, 16);
  } else {
    const int m = lane & 15;
    uint32_t hw[4];
#pragma unroll
    for (int nt = 0; nt < 2; ++nt) {
      const int n = nt * 16 + m;
#pragma unroll
      for (int j2 = 0; j2 < 4; ++j2) {
        const int kkA = kperm(quad, j2 * 2), kkB = kperm(quad, j2 * 2 + 1);
        hw[j2] = (uint32_t)f2h(Wc1[kkA * 32 + n])
               | ((uint32_t)f2h(Wc1[kkB * 32 + n]) << 16);
      }
      uint4 q = make_uint4(hw[0], hw[1], hw[2], hw[3]);
      if (nt == 0) __builtin_memcpy(&FC0, &q, 16);
      else         __builtin_memcpy(&FC1, &q, 16);
    }
#pragma unroll
    for (int j2 = 0; j2 < 4; ++j2) {
      const int kkA = kperm(quad, j2 * 2), kkB = kperm(quad, j2 * 2 + 1);
      const float va = (m < 3) ? Wc2[kkA * 3 + m] : 0.0f;
      const float vb = (m < 3) ? Wc2[kkB * 3 + m] : 0.0f;
      hw[j2] = (uint32_t)f2h(va) | ((uint32_t)f2h(vb) << 16);
    }
    { uint4 q = make_uint4(hw[0], hw[1], hw[2], hw[3]); __builtin_memcpy(&F2, &q, 16); }
  }

  // ---- fused fine density + color via MFMA chain: 8 tiles per wave ----
  {
    float dvv[2][4];
#pragma unroll
    for (int nt = 0; nt < 2; ++nt)
#pragma unroll
      for (int r = 0; r < 4; ++r) {
        const int n = nt * 16 + quad * 4 + r;
        const float4 nv = ldsf4(sw + NV4 + n * 4);
        dvv[nt][r] = nv.x + ndx * nv.y + ndy * nv.z + ndz * nv.w;
      }
    f32x4 c2init, sInit;
    {
      const float b0 = sw[BC2 + 0], b1 = sw[BC2 + 1], b2 = sw[BC2 + 2];
      const bool q0 = (quad == 0);
      c2init[0] = q0 ? b0 : 0.0f;
      c2init[1] = q0 ? b1 : 0.0f;
      c2init[2] = q0 ? b2 : 0.0f;
      c2init[3] = 0.0f;
      sInit[0] = q0 ? bd2v : 0.0f;
      sInit[1] = 0.0f; sInit[2] = 0.0f; sInit[3] = 0.0f;
    }

#pragma unroll
    for (int mt = 0; mt < 8; ++mt) {
      const int sbase = mt * 16;
      const uint2 pr = s_p[sbase + (lane & 15)];
      const uint32_t b0 = (quad == 0) ? pr.x : 0u;
      const uint32_t b1 = (quad == 0) ? pr.y : 0u;
      const uint4 bq = make_uint4(b0, b1, 0u, 0u);
      half8 Bp; __builtin_memcpy(&Bp, &bq, 16);

      const f32x4 z4 = {0.f, 0.f, 0.f, 0.f};
      f32x4 ad0 = __builtin_amdgcn_mfma_f32_16x16x32_f16(FD0, Bp, z4, 0, 0, 0);
      f32x4 ad1 = __builtin_amdgcn_mfma_f32_16x16x32_f16(FD1, Bp, z4, 0, 0, 0);

      const uint4 qb2 = make_uint4(
          pk2h(fmaxf(ad0[0], 0.0f), fmaxf(ad0[1], 0.0f)),
          pk2h(fmaxf(ad0[2], 0.0f), fmaxf(ad0[3], 0.0f)),
          pk2h(fmaxf(ad1[0], 0.0f), fmaxf(ad1[1], 0.0f)),
          pk2h(fmaxf(ad1[2], 0.0f), fmaxf(ad1[3], 0.0f)));
      half8 B2; __builtin_memcpy(&B2, &qb2, 16);

      f32x4 aS = __builtin_amdgcn_mfma_f32_16x16x32_f16(FS, B2, sInit, 0, 0, 0);
      f32x4 ac0 = {dvv[0][0], dvv[0][1], dvv[0][2], dvv[0][3]};
      f32x4 ac1 = {dvv[1][0], dvv[1][1], dvv[1][2], dvv[1][3]};
      ac0 = __builtin_amdgcn_mfma_f32_16x16x32_f16(FC0, B2, ac0, 0, 0, 0);
      ac1 = __builtin_amdgcn_mfma_f32_16x16x32_f16(FC1, B2, ac1, 0, 0, 0);

      const uint4 qb3 = make_uint4(
          pk2h(fmaxf(ac0[0], 0.0f), fmaxf(ac0[1], 0.0f)),
          pk2h(fmaxf(ac0[2], 0.0f), fmaxf(ac0[3], 0.0f)),
          pk2h(fmaxf(ac1[0], 0.0f), fmaxf(ac1[1], 0.0f)),
          pk2h(fmaxf(ac1[2], 0.0f), fmaxf(ac1[3], 0.0f)));
      half8 B3; __builtin_memcpy(&B3, &qb3, 16);

      f32x4 aC = __builtin_amdgcn_mfma_f32_16x16x32_f16(F2, B3, c2init, 0, 0, 0);

      if (quad == 0) {
        const int s = sbase + (lane & 15);
        s_sig[s] = aS[0];
        float4 og;
        og.x = fast_rcp(1.0f + __expf(-aC[0]));
        og.y = fast_rcp(1.0f + __expf(-aC[1]));
        og.z = fast_rcp(1.0f + __expf(-aC[2]));
        og.w = 0.0f;
        *(float4*)(s_rgb + s * RGBS) = og;
      }
    }
  }

  // ---- fine alpha + cumprod over 128 (2 segments + carry) ----
  const float sg0 = softplus_f(s_sig[lane]);
  const float sg1 = softplus_f(s_sig[lane + 64]);
  const float dl0 = s_zlf[lane + 1] - zlfv[0];                       // lane<63 in-seg; lane=63 -> s_zlf[64]
  const float dl1 = (lane < 63) ? (s_zlf[lane + 65] - zlfv[1]) : 0.0f;
  const float vf0 = __expf(-sg0 * dl0);
  const float vf1 = __expf(-sg1 * dl1);
  float wf0, wf1;
  {
    const float f0 = dpp_scan_mul(vf0);
    const float cf = readlane_f(f0, 63);
    const float f1 = dpp_scan_mul(vf1);
    wf0 = (fast_rcp(vf0) - 1.0f) * f0 * 1.0f;
    wf1 = (fast_rcp(vf1) - 1.0f) * f1 * cf;
  }

  // ---- outputs ----
  float* o_img = out;
  float* o_w   = out + (size_t)n_rays * 3;
  float* o_z   = out + (size_t)n_rays * (3 + 128);
  float* o_inv = out + (size_t)n_rays * (3 + 256);

  o_w[(size_t)ray * 128 + lane]      = wf0;
  o_w[(size_t)ray * 128 + lane + 64] = wf1;
  o_z[(size_t)ray * 128 + lane]      = (zlfv[0] + 1.0f) * 0.5f;
  o_z[(size_t)ray * 128 + lane + 64] = (zlfv[1] + 1.0f) * 0.5f;

  const float4 rg0 = *(const float4*)(s_rgb + lane * RGBS);
  const float4 rg1 = *(const float4*)(s_rgb + (lane + 64) * RGBS);
  float r0 = wf0 * rg0.x + wf1 * rg1.x;
  float r1 = wf0 * rg0.y + wf1 * rg1.y;
  float r2 = wf0 * rg0.z + wf1 * rg1.z;
  float r3 = wf0 + wf1;
  float r4 = wf0 * fast_rcp(zfv[0]) + wf1 * fast_rcp(zfv[1]);
  r0 = dpp_scan_add(r0);
  r1 = dpp_scan_add(r1);
  r2 = dpp_scan_add(r2);
  r3 = dpp_scan_add(r3);
  r4 = dpp_scan_add(r4);
  if (lane == 63) {
    const float bgw = 1.0f - r3;
    o_img[(size_t)ray * 3 + 0] = r0 + bgw * bg[0];
    o_img[(size_t)ray * 3 + 1] = r1 + bgw * bg[1];
    o_img[(size_t)ray * 3 + 2] = r2 + bgw * bg[2];
    o_inv[ray] = r4;
  }
}

extern "C" void kernel_launch(void* const* d_in, const int* in_sizes, int n_in,
                              void* d_out, int out_size, void* d_ws, size_t ws_size,
                              hipStream_t stream) {
  const float* h   = (const float*)d_in[1];
  const float* w   = (const float*)d_in[2];
  const float* K   = (const float*)d_in[3];
  const float* E   = (const float*)d_in[4];
  const float* bg  = (const float*)d_in[5];
  const float* Wd1 = (const float*)d_in[6];
  const float* bd1 = (const float*)d_in[7];
  const float* Wd2 = (const float*)d_in[8];
  const float* bd2 = (const float*)d_in[9];
  const float* Wc1 = (const float*)d_in[10];
  const float* bc1 = (const float*)d_in[11];
  const float* Wc2 = (const float*)d_in[12];
  const float* bc2 = (const float*)d_in[13];
  const int n_rays = in_sizes[1];
  float* wsf = (float*)d_ws;
  const int nblk = (n_rays + 1) / 2;

  if (ws_size >= WS_NEED) {
    pack_weights<<<1, PACK_NT, 0, stream>>>(K, Wd1, bd1, Wd2, bd2, Wc1, bc1, Wc2, bc2, wsf);
    nerf_fwd<true><<<nblk, NT, 0, stream>>>(h, w, K, E, bg, Wd1, bd1, Wd2, bd2,
                                            Wc1, bc1, Wc2, bc2, wsf,
                                            (float*)d_out, n_rays);
  } else {
    nerf_fwd<false><<<nblk, NT, 0, stream>>>(h, w, K, E, bg, Wd1, bd1, Wd2, bd2,
                                             Wc1, bc1, Wc2, bc2, nullptr,
                                             (float*)d_out, n_rays);
  }
}

// Round 9
// 141.121 us; speedup vs baseline: 1.0910x; 1.0003x over previous
//
#include <hip/hip_runtime.h>
#include <stdint.h>

#define SC 192      // coarse samples (128 + 64)
#define SF 128      // fine (importance) samples
#define NT 128      // threads per block = 2 waves = 2 rays (one ray per wave)
#define PACK_NT 128

// d_ws float offsets (weight image lives in GLOBAL, read via L1 — no LDS staging)
#define BD2   0     // 1
#define BC2   1     // 3
#define NV4   4     // 32 x float4: (bc1[n], Wc1[32][n], Wc1[33][n], Wc1[34][n])
#define ZD    132   // 192 x float2: (z = 10^zlog_c(i), delta_c(i))
#define ZMID  516   // 192 floats: 0.5*(zlog_c(i)+zlog_c(i+1)) for i<191
#define KINV  708   // 9 floats, row-major inv(K)
// fp16 MFMA A-frag tables in d_ws (64 lanes each)
#define WS_F_WD1 4096   // 128 x uint4: lane*2 -> {Wd1 units 0-15, units 16-31}, bias at k=3
#define WS_F_WC1 6144   // 128 x uint4: k-permuted Wc1 frags (match B2 layout)
#define WS_F_WD2 8192   // 64 x uint4: row0 = Wd2 k-permuted
#define WS_F_W2  9216   // 64 x uint4: rows 0-2 = Wc2 k-permuted
#define WS_NEED  10240

using half8 = __attribute__((ext_vector_type(8))) _Float16;
using f32x4 = __attribute__((ext_vector_type(4))) float;

__device__ __forceinline__ float zlog_c(int t) {
  return (t < 128) ? (-1.0f + (float)t * 0.0078125f)
                   : ((float)(t - 128) * 0.015625f);
}
__device__ __forceinline__ float delta_c(int t) {
  if (t >= SC - 1) return 0.0f;
  return zlog_c(t + 1) - zlog_c(t);
}
__device__ __forceinline__ float zmid_c(int i) {
  return 0.5f * (zlog_c(i) + zlog_c(i + 1));
}

__device__ __forceinline__ float fast_rcp(float x) { return __builtin_amdgcn_rcpf(x); }
__device__ __forceinline__ float fast_rsq(float x) { return __builtin_amdgcn_rsqf(x); }
__device__ __forceinline__ float exp10_f(float x) { return __expf(x * 2.30258509299f); }
__device__ __forceinline__ float softplus_f(float x) {
  return fmaxf(x, 0.0f) + __logf(1.0f + __expf(-fabsf(x)));
}

// Compiler memory fence (zero ISA bytes). Within a wave, HW processes DS ops in
// order and lanes are lockstep — the ONLY reordering hazard for cross-lane LDS
// dataflow is the compiler's per-thread alias analysis. This pins emission order.
__device__ __forceinline__ void lds_fence() { asm volatile("" ::: "memory"); }

// fp16 helpers
__device__ __forceinline__ uint32_t pk2h(float a, float b) {
  auto p = __builtin_amdgcn_cvt_pkrtz(a, b);
  uint32_t u; __builtin_memcpy(&u, &p, 4); return u;
}
__device__ __forceinline__ unsigned short f2h(float f) {
  _Float16 h = (_Float16)f;
  unsigned short us; __builtin_memcpy(&us, &h, 2); return us;
}

// k-permutation shared by all layer-2-style A-frags (matches B2 from acc0/acc1)
__device__ __forceinline__ int kperm(int q, int j) {
  return (j < 4) ? (q * 4 + j) : (16 + q * 4 + (j - 4));
}

// ---- DPP cross-lane scans (VALU pipe) ----
template <int CTRL, int RMASK, int BMASK>
__device__ __forceinline__ float dpp_mov(float x, float oldv) {
  return __int_as_float(__builtin_amdgcn_update_dpp(
      __float_as_int(oldv), __float_as_int(x), CTRL, RMASK, BMASK, false));
}
__device__ __forceinline__ float dpp_scan_add(float v) {
  v += dpp_mov<0x111, 0xf, 0xf>(v, 0.0f);
  v += dpp_mov<0x112, 0xf, 0xf>(v, 0.0f);
  v += dpp_mov<0x114, 0xf, 0xf>(v, 0.0f);
  v += dpp_mov<0x118, 0xf, 0xf>(v, 0.0f);
  v += dpp_mov<0x142, 0xa, 0xf>(v, 0.0f);
  v += dpp_mov<0x143, 0xc, 0xf>(v, 0.0f);
  return v;
}
__device__ __forceinline__ float dpp_scan_mul(float v) {
  v *= dpp_mov<0x111, 0xf, 0xf>(v, 1.0f);
  v *= dpp_mov<0x112, 0xf, 0xf>(v, 1.0f);
  v *= dpp_mov<0x114, 0xf, 0xf>(v, 1.0f);
  v *= dpp_mov<0x118, 0xf, 0xf>(v, 1.0f);
  v *= dpp_mov<0x142, 0xa, 0xf>(v, 1.0f);
  v *= dpp_mov<0x143, 0xc, 0xf>(v, 1.0f);
  return v;
}
__device__ __forceinline__ float readlane_f(float v, int l) {
  return __int_as_float(__builtin_amdgcn_readlane(__float_as_int(v), l));
}

// JAX threefry2x32 with key = (0, 42)
__device__ __forceinline__ void threefry2x32_k42(uint32_t& x0, uint32_t& x1) {
  const uint32_t ks0 = 0u, ks1 = 42u;
  const uint32_t ks2 = ks0 ^ ks1 ^ 0x1BD11BDAu;
  const uint32_t ks[3] = {ks0, ks1, ks2};
  const int rot[2][4] = {{13, 15, 26, 6}, {17, 29, 16, 24}};
  x0 += ks[0];
  x1 += ks[1];
#pragma unroll
  for (int i = 0; i < 5; ++i) {
#pragma unroll
    for (int j = 0; j < 4; ++j) {
      x0 += x1;
      const int r = rot[i & 1][j];
      x1 = (x1 << r) | (x1 >> (32 - r));
      x1 ^= x0;
    }
    x0 += ks[(i + 1) % 3];
    x1 += ks[(i + 2) % 3] + (uint32_t)(i + 1);
  }
}

// value of Wd1-layer A-frag at (k, unit): k<3 -> Wd1[k][n], k==3 -> bd1[n], else 0
__device__ __forceinline__ float wd1_val(const float* Wd1, const float* bd1, int k, int n) {
  if (k < 3) return Wd1[k * 32 + n];
  if (k == 3) return bd1[n];
  return 0.0f;
}

// ---- pre-pack kernel (layout unchanged) ----
__global__ __launch_bounds__(PACK_NT) void pack_weights(
    const float* __restrict__ K,
    const float* __restrict__ Wd1, const float* __restrict__ bd1,
    const float* __restrict__ Wd2, const float* __restrict__ bd2,
    const float* __restrict__ Wc1, const float* __restrict__ bc1,
    const float* __restrict__ Wc2, const float* __restrict__ bc2,
    float* __restrict__ wsf) {
  const int t = threadIdx.x;
  for (int i = t; i < 192; i += PACK_NT) {
    wsf[ZD + 2 * i + 0] = exp10_f(zlog_c(i));
    wsf[ZD + 2 * i + 1] = delta_c(i);
    wsf[ZMID + i] = (i < 191) ? 0.5f * (zlog_c(i) + zlog_c(i + 1)) : 0.0f;
  }
  if (t == 0) {
    wsf[BD2] = bd2[0];
    wsf[BC2 + 0] = bc2[0]; wsf[BC2 + 1] = bc2[1]; wsf[BC2 + 2] = bc2[2];
    const float k00 = K[0], k01 = K[1], k02 = K[2];
    const float k10 = K[3], k11 = K[4], k12 = K[5];
    const float k20 = K[6], k21 = K[7], k22 = K[8];
    const float det = k00 * (k11 * k22 - k12 * k21)
                    - k01 * (k10 * k22 - k12 * k20)
                    + k02 * (k10 * k21 - k11 * k20);
    const float id = 1.0f / det;
    wsf[KINV + 0] =  (k11 * k22 - k12 * k21) * id;
    wsf[KINV + 1] = -(k01 * k22 - k02 * k21) * id;
    wsf[KINV + 2] =  (k01 * k12 - k02 * k11) * id;
    wsf[KINV + 3] = -(k10 * k22 - k12 * k20) * id;
    wsf[KINV + 4] =  (k00 * k22 - k02 * k20) * id;
    wsf[KINV + 5] = -(k00 * k12 - k02 * k10) * id;
    wsf[KINV + 6] =  (k10 * k21 - k11 * k20) * id;
    wsf[KINV + 7] = -(k00 * k21 - k01 * k20) * id;
    wsf[KINV + 8] =  (k00 * k11 - k01 * k10) * id;
  }
  if (t < 64) {
    const int m = t & 15, q = t >> 4;
    {
      uint4* fr = (uint4*)((char*)wsf + WS_F_WD1);
#pragma unroll
      for (int nt = 0; nt < 2; ++nt) {
        const int n = nt * 16 + m;
        uint32_t hw[4];
#pragma unroll
        for (int j2 = 0; j2 < 4; ++j2) {
          const int k = q * 8 + j2 * 2;
          hw[j2] = (uint32_t)f2h(wd1_val(Wd1, bd1, k, n))
                 | ((uint32_t)f2h(wd1_val(Wd1, bd1, k + 1, n)) << 16);
        }
        fr[t * 2 + nt] = make_uint4(hw[0], hw[1], hw[2], hw[3]);
      }
    }
    {
      uint4* fr = (uint4*)((char*)wsf + WS_F_WC1);
#pragma unroll
      for (int nt = 0; nt < 2; ++nt) {
        const int n = nt * 16 + m;
        uint32_t hw[4];
#pragma unroll
        for (int j2 = 0; j2 < 4; ++j2) {
          const int kkA = kperm(q, j2 * 2), kkB = kperm(q, j2 * 2 + 1);
          hw[j2] = (uint32_t)f2h(Wc1[kkA * 32 + n])
                 | ((uint32_t)f2h(Wc1[kkB * 32 + n]) << 16);
        }
        fr[t * 2 + nt] = make_uint4(hw[0], hw[1], hw[2], hw[3]);
      }
    }
    {
      uint32_t hw[4];
#pragma unroll
      for (int j2 = 0; j2 < 4; ++j2) {
        const int kkA = kperm(q, j2 * 2), kkB = kperm(q, j2 * 2 + 1);
        const float va = (m == 0) ? Wd2[kkA] : 0.0f;
        const float vb = (m == 0) ? Wd2[kkB] : 0.0f;
        hw[j2] = (uint32_t)f2h(va) | ((uint32_t)f2h(vb) << 16);
      }
      ((uint4*)((char*)wsf + WS_F_WD2))[t] = make_uint4(hw[0], hw[1], hw[2], hw[3]);
    }
    {
      uint32_t hw[4];
#pragma unroll
      for (int j2 = 0; j2 < 4; ++j2) {
        const int kkA = kperm(q, j2 * 2), kkB = kperm(q, j2 * 2 + 1);
        const float va = (m < 3) ? Wc2[kkA * 3 + m] : 0.0f;
        const float vb = (m < 3) ? Wc2[kkB * 3 + m] : 0.0f;
        hw[j2] = (uint32_t)f2h(va) | ((uint32_t)f2h(vb) << 16);
      }
      ((uint4*)((char*)wsf + WS_F_W2))[t] = make_uint4(hw[0], hw[1], hw[2], hw[3]);
    }
  }
  if (t < 32) {
    wsf[NV4 + t * 4 + 0] = bc1[t];
    wsf[NV4 + t * 4 + 1] = Wc1[32 * 32 + t];
    wsf[NV4 + t * 4 + 2] = Wc1[33 * 32 + t];
    wsf[NV4 + t * 4 + 3] = Wc1[34 * 32 + t];
  }
}

template <bool USE_WS>
__global__ __launch_bounds__(NT, 8) void nerf_fwd(
    const float* __restrict__ hh, const float* __restrict__ ww,
    const float* __restrict__ K, const float* __restrict__ E,
    const float* __restrict__ bg,
    const float* __restrict__ Wd1, const float* __restrict__ bd1,
    const float* __restrict__ Wd2, const float* __restrict__ bd2,
    const float* __restrict__ Wc1, const float* __restrict__ bc1,
    const float* __restrict__ Wc2, const float* __restrict__ bc2,
    const float* __restrict__ wsf,
    float* __restrict__ out, int n_rays) {
  const int t = threadIdx.x;
  const int lane = t & 63;
  const int wv = t >> 6;   // wave = ray within block
  const int quad = lane >> 4;

  // Per-wave slices; zero block barriers. Cross-lane LDS dataflow within a wave
  // is protected by lds_fence() (emission order) + HW in-order DS + lockstep.
  __shared__ __align__(16) uint2 s_pc[2][192];    // coarse pts; [0..127] reused for fine pts
  __shared__ __align__(16) float s_wc[2][192];    // reweighted weights
  __shared__ __align__(16) float s_cdfA[2][196];  // normalized CDF (dedicated; +pad for OOB-safe probe)
  __shared__ __align__(16) float s_zlf[2][128];
  __shared__ __align__(16) float s_rx[2][512];    // coarse sigma [0..191]; then 128 x float4 {rgb, sig}

  uint2* const pc  = s_pc[wv];
  float* const wc  = s_wc[wv];
  float* const cdf = s_cdfA[wv];
  float* const zlA = s_zlf[wv];
  float* const rx  = s_rx[wv];

  // ---- ray id (wave-uniform, forced scalar) ----
  int ray_ = blockIdx.x * 2 + wv;
  if (ray_ >= n_rays) ray_ = n_rays - 1;
  const int ray = __builtin_amdgcn_readfirstlane(ray_);

  // ---- ray setup ----
  float i00, i01, i02, i10, i11, i12, i20, i21, i22;
  if constexpr (USE_WS) {
    i00 = wsf[KINV + 0]; i01 = wsf[KINV + 1]; i02 = wsf[KINV + 2];
    i10 = wsf[KINV + 3]; i11 = wsf[KINV + 4]; i12 = wsf[KINV + 5];
    i20 = wsf[KINV + 6]; i21 = wsf[KINV + 7]; i22 = wsf[KINV + 8];
  } else {
    const float k00 = K[0], k01 = K[1], k02 = K[2];
    const float k10 = K[3], k11 = K[4], k12 = K[5];
    const float k20 = K[6], k21 = K[7], k22 = K[8];
    const float det = k00 * (k11 * k22 - k12 * k21)
                    - k01 * (k10 * k22 - k12 * k20)
                    + k02 * (k10 * k21 - k11 * k20);
    const float id = 1.0f / det;
    i00 =  (k11 * k22 - k12 * k21) * id;
    i01 = -(k01 * k22 - k02 * k21) * id;
    i02 =  (k01 * k12 - k02 * k11) * id;
    i10 = -(k10 * k22 - k12 * k20) * id;
    i11 =  (k00 * k22 - k02 * k20) * id;
    i12 = -(k00 * k12 - k02 * k10) * id;
    i20 =  (k10 * k21 - k11 * k20) * id;
    i21 = -(k00 * k21 - k01 * k20) * id;
    i22 =  (k00 * k11 - k01 * k10) * id;
  }

  const float dwx = ww[ray] + 0.5f;
  const float dwy = hh[ray] + 0.5f;
  const float cx = i00 * dwx + i01 * dwy + i02;
  const float cy = i10 * dwx + i11 * dwy + i12;
  const float cz = i20 * dwx + i21 * dwy + i22;
  const float* Er = E + (size_t)ray * 16;
  const float ox = Er[3], oy = Er[7], oz = Er[11];
  const float dx = Er[0] * cx + Er[1] * cy + Er[2] * cz;
  const float dy = Er[4] * cx + Er[5] * cy + Er[6] * cz;
  const float dz = Er[8] * cx + Er[9] * cy + Er[10] * cz;
  const float inv_nrm = fast_rsq(dx * dx + dy * dy + dz * dz);
  const float ndx = dx * inv_nrm, ndy = dy * inv_nrm, ndz = dz * inv_nrm;

  const float bd2v = USE_WS ? wsf[BD2] : bd2[0];

  // ---- density A-frags (coarse + fine) ----
  half8 FD0, FD1, FS;
  if constexpr (USE_WS) {
    const uint4* fd = (const uint4*)((const char*)wsf + WS_F_WD1);
    uint4 q0 = fd[lane * 2 + 0], q1 = fd[lane * 2 + 1];
    uint4 q4 = ((const uint4*)((const char*)wsf + WS_F_WD2))[lane];
    __builtin_memcpy(&FD0, &q0, 16);
    __builtin_memcpy(&FD1, &q1, 16);
    __builtin_memcpy(&FS, &q4, 16);
  } else {
    const int m = lane & 15;
    uint32_t hw[4];
#pragma unroll
    for (int nt = 0; nt < 2; ++nt) {
      const int n = nt * 16 + m;
#pragma unroll
      for (int j2 = 0; j2 < 4; ++j2) {
        const int k = quad * 8 + j2 * 2;
        hw[j2] = (uint32_t)f2h(wd1_val(Wd1, bd1, k, n))
               | ((uint32_t)f2h(wd1_val(Wd1, bd1, k + 1, n)) << 16);
      }
      uint4 q = make_uint4(hw[0], hw[1], hw[2], hw[3]);
      if (nt == 0) __builtin_memcpy(&FD0, &q, 16);
      else         __builtin_memcpy(&FD1, &q, 16);
    }
#pragma unroll
    for (int j2 = 0; j2 < 4; ++j2) {
      const int kkA = kperm(quad, j2 * 2), kkB = kperm(quad, j2 * 2 + 1);
      const float va = (m == 0) ? Wd2[kkA] : 0.0f;
      const float vb = (m == 0) ? Wd2[kkB] : 0.0f;
      hw[j2] = (uint32_t)f2h(va) | ((uint32_t)f2h(vb) << 16);
    }
    { uint4 q = make_uint4(hw[0], hw[1], hw[2], hw[3]); __builtin_memcpy(&FS, &q, 16); }
  }

  // ---- coarse points: lane owns e = lane, lane+64, lane+128 ----
  float2 zd[3];
#pragma unroll
  for (int q3 = 0; q3 < 3; ++q3) {
    const int e = lane + 64 * q3;
    if constexpr (USE_WS) {
      zd[q3] = *(const float2*)(wsf + ZD + 2 * e);
    } else {
      zd[q3] = make_float2(exp10_f(zlog_c(e)), delta_c(e));
    }
    const float z = zd[q3].x;
    float px = ox + dx * z, py = oy + dy * z, pz = oz + dz * z;
    const float d2 = px * px + py * py + pz * pz;
    if (d2 > 1.0f) {
      const float invd = fast_rsq(d2);
      const float sc = (2.0f - invd) * invd;
      px *= sc; py *= sc; pz *= sc;
    }
    pc[e] = make_uint2(pk2h(px, py), pk2h(pz, 1.0f));
  }
  lds_fence();   // pc writes -> MFMA reads (cross-lane)

  // ---- coarse density via MFMA: 12 independent tiles ----
  {
    f32x4 sInit;
    sInit[0] = (quad == 0) ? bd2v : 0.0f;
    sInit[1] = 0.0f; sInit[2] = 0.0f; sInit[3] = 0.0f;
#pragma unroll
    for (int T = 0; T < 12; ++T) {
      const int sbase = T * 16;
      const uint2 pr = pc[sbase + (lane & 15)];
      const uint32_t b0 = (quad == 0) ? pr.x : 0u;
      const uint32_t b1 = (quad == 0) ? pr.y : 0u;
      const uint4 bq = make_uint4(b0, b1, 0u, 0u);
      half8 Bp; __builtin_memcpy(&Bp, &bq, 16);

      const f32x4 z4 = {0.f, 0.f, 0.f, 0.f};
      f32x4 ad0 = __builtin_amdgcn_mfma_f32_16x16x32_f16(FD0, Bp, z4, 0, 0, 0);
      f32x4 ad1 = __builtin_amdgcn_mfma_f32_16x16x32_f16(FD1, Bp, z4, 0, 0, 0);

      const uint4 qb2 = make_uint4(
          pk2h(fmaxf(ad0[0], 0.0f), fmaxf(ad0[1], 0.0f)),
          pk2h(fmaxf(ad0[2], 0.0f), fmaxf(ad0[3], 0.0f)),
          pk2h(fmaxf(ad1[0], 0.0f), fmaxf(ad1[1], 0.0f)),
          pk2h(fmaxf(ad1[2], 0.0f), fmaxf(ad1[3], 0.0f)));
      half8 B2; __builtin_memcpy(&B2, &qb2, 16);

      f32x4 aS = __builtin_amdgcn_mfma_f32_16x16x32_f16(FS, B2, sInit, 0, 0, 0);
      if (quad == 0) rx[sbase + (lane & 15)] = aS[0];
    }
  }
  lds_fence();   // sigma writes -> alpha reads (cross-lane)

  // ---- coarse alpha (3 per lane) ----
  float v3[3];
#pragma unroll
  for (int q3 = 0; q3 < 3; ++q3) {
    const int e = lane + 64 * q3;
    v3[q3] = __expf(-softplus_f(rx[e]) * zd[q3].y);
  }

  // cumprod over 192: three 64-wide DPP scans + readlane carries
  {
    const float s0 = dpp_scan_mul(v3[0]);
    const float c0 = readlane_f(s0, 63);
    const float s1 = dpp_scan_mul(v3[1]);
    const float c01 = c0 * readlane_f(s1, 63);
    const float s2 = dpp_scan_mul(v3[2]);
    wc[lane]       = (fast_rcp(v3[0]) - 1.0f) * s0 * 1.0f;
    wc[lane + 64]  = (fast_rcp(v3[1]) - 1.0f) * s1 * c0;
    wc[lane + 128] = (fast_rcp(v3[2]) - 1.0f) * s2 * c01;
  }
  lds_fence();   // w writes -> reweight neighbor reads (cross-lane)

  // reweight (3 per lane)
  float wre[3];
#pragma unroll
  for (int q3 = 0; q3 < 3; ++q3) {
    const int e = lane + 64 * q3;
    const float wm = (e > 0) ? wc[e - 1] : 0.0f;
    const float w0 = wc[e];
    const float wp = (e < SC - 1) ? wc[e + 1] : 0.0f;
    wre[q3] = 0.5f * (fmaxf(wm, w0) + fmaxf(w0, wp)) + (0.02f / 192.0f);
    wre[q3] *= (e < 128) ? (128.0f / 192.0f) : (64.0f / 192.0f);
  }

  // cumsum over 192 -> normalized CDF (dedicated array: no in-place reuse)
  {
    const float a0 = dpp_scan_add(wre[0]);
    const float T0 = readlane_f(a0, 63);
    const float a1 = dpp_scan_add(wre[1]);
    const float T1 = readlane_f(a1, 63);
    const float a2 = dpp_scan_add(wre[2]);
    const float inv_total = fast_rcp(T0 + T1 + readlane_f(a2, 63));
    cdf[lane]       = a0 * inv_total;
    cdf[lane + 64]  = (a1 + T0) * inv_total;
    cdf[lane + 128] = (a2 + T0 + T1) * inv_total;
    if (lane < 4) cdf[192 + lane] = 1.0f;   // pad: OOB-safe probe target (value never selected)
  }
  lds_fence();   // cdf writes -> search reads (cross-lane)

  // ---- importance sampling: lane owns s = lane, lane+64 ----
  float zlfv[2], zfv[2];
  {
    float cA[7];
#pragma unroll
    for (int i = 0; i < 7; ++i) cA[i] = cdf[24 * i + 24];
    const float cdf1 = cdf[1], cdf190 = cdf[190];
    const uint32_t total = (uint32_t)n_rays * 128u;
    const uint32_t halfc = total >> 1;

#pragma unroll
    for (int h2 = 0; h2 < 2; ++h2) {
      const int s = lane + 64 * h2;
      const uint32_t j = (uint32_t)ray * 128u + (uint32_t)s;
      uint32_t x0, x1;
      const bool first = (j < halfc);
      if (first) { x0 = j; x1 = j + halfc; } else { x0 = j - halfc; x1 = j; }
      threefry2x32_k42(x0, x1);
      const uint32_t bits = first ? x0 : x1;
      const float fr = __uint_as_float((bits >> 9) | 0x3f800000u) - 1.0f;

      float u = (float)s * 0.0078125f + fr * 0.0078125f;
      u = u * (cdf190 - cdf1) + cdf1;

      int start = 0;
#pragma unroll
      for (int i = 0; i < 7; ++i) start += (cA[i] <= u) ? 24 : 0;
      float cB[7];
#pragma unroll
      for (int i = 0; i < 7; ++i) cB[i] = cdf[start + 3 * i + 3];
      int st2 = start;
#pragma unroll
      for (int i = 0; i < 7; ++i) st2 += (cB[i] <= u) ? 3 : 0;
      const float p0 = cdf[st2];
      const float p1 = cdf[st2 + 1];
      const float p2 = cdf[st2 + 2];
      const float p3 = cdf[st2 + 3];
      const int k = ((p1 <= u) ? 1 : 0) + ((p2 <= u) ? 1 : 0);
      const int lo = st2 + k;
      const int inds = lo + 1;
      const float cb = (k == 0) ? p0 : ((k == 1) ? p1 : p2);
      const float ca = (k == 0) ? p1 : ((k == 1) ? p2 : p3);
      const float tt = (u - cb) * fast_rcp(ca - cb);
      float zb, za;
      if constexpr (USE_WS) {
        zb = wsf[ZMID + inds - 1];
        za = wsf[ZMID + inds];
      } else {
        zb = zmid_c(inds - 1);
        za = zmid_c(inds);
      }
      const float zl = zb + (za - zb) * tt;
      zlfv[h2] = zl;
      zlA[s] = zl;
      const float zf = exp10_f(zl);
      zfv[h2] = zf;

      float px = ox + dx * zf, py = oy + dy * zf, pz = oz + dz * zf;
      const float d2 = px * px + py * py + pz * pz;
      if (d2 > 1.0f) {
        const float invd = fast_rsq(d2);
        const float sc = (2.0f - invd) * invd;
        px *= sc; py *= sc; pz *= sc;
      }
      pc[s] = make_uint2(pk2h(px, py), pk2h(pz, 1.0f));
    }
  }
  lds_fence();   // fine pts + zlf writes -> MFMA / alpha reads (cross-lane)

  // ---- color A-frags ----
  half8 FC0, FC1, F2;
  if constexpr (USE_WS) {
    const uint4* fc = (const uint4*)((const char*)wsf + WS_F_WC1);
    uint4 q2 = fc[lane * 2 + 0], q3 = fc[lane * 2 + 1];
    uint4 q5 = ((const uint4*)((const char*)wsf + WS_F_W2))[lane];
    __builtin_memcpy(&FC0, &q2, 16);
    __builtin_memcpy(&FC1, &q3, 16);
    __builtin_memcpy(&F2, &q5, 16);
  } else {
    const int m = lane & 15;
    uint32_t hw[4];
#pragma unroll
    for (int nt = 0; nt < 2; ++nt) {
      const int n = nt * 16 + m;
#pragma unroll
      for (int j2 = 0; j2 < 4; ++j2) {
        const int kkA = kperm(quad, j2 * 2), kkB = kperm(quad, j2 * 2 + 1);
        hw[j2] = (uint32_t)f2h(Wc1[kkA * 32 + n])
               | ((uint32_t)f2h(Wc1[kkB * 32 + n]) << 16);
      }
      uint4 q = make_uint4(hw[0], hw[1], hw[2], hw[3]);
      if (nt == 0) __builtin_memcpy(&FC0, &q, 16);
      else         __builtin_memcpy(&FC1, &q, 16);
    }
#pragma unroll
    for (int j2 = 0; j2 < 4; ++j2) {
      const int kkA = kperm(quad, j2 * 2), kkB = kperm(quad, j2 * 2 + 1);
      const float va = (m < 3) ? Wc2[kkA * 3 + m] : 0.0f;
      const float vb = (m < 3) ? Wc2[kkB * 3 + m] : 0.0f;
      hw[j2] = (uint32_t)f2h(va) | ((uint32_t)f2h(vb) << 16);
    }
    { uint4 q = make_uint4(hw[0], hw[1], hw[2], hw[3]); __builtin_memcpy(&F2, &q, 16); }
  }

  // ---- fused fine density + color via MFMA chain: 8 independent tiles ----
  {
    float dvv[2][4];
#pragma unroll
    for (int nt = 0; nt < 2; ++nt)
#pragma unroll
      for (int r = 0; r < 4; ++r) {
        const int n = nt * 16 + quad * 4 + r;
        float4 nv;
        if constexpr (USE_WS) {
          nv = *(const float4*)(wsf + NV4 + n * 4);
        } else {
          nv = make_float4(bc1[n], Wc1[32 * 32 + n], Wc1[33 * 32 + n], Wc1[34 * 32 + n]);
        }
        dvv[nt][r] = nv.x + ndx * nv.y + ndy * nv.z + ndz * nv.w;
      }
    f32x4 c2init, sInit;
    {
      float b0, b1, b2;
      if constexpr (USE_WS) { b0 = wsf[BC2 + 0]; b1 = wsf[BC2 + 1]; b2 = wsf[BC2 + 2]; }
      else                  { b0 = bc2[0]; b1 = bc2[1]; b2 = bc2[2]; }
      const bool q0 = (quad == 0);
      c2init[0] = q0 ? b0 : 0.0f;
      c2init[1] = q0 ? b1 : 0.0f;
      c2init[2] = q0 ? b2 : 0.0f;
      c2init[3] = 0.0f;
      sInit[0] = q0 ? bd2v : 0.0f;
      sInit[1] = 0.0f; sInit[2] = 0.0f; sInit[3] = 0.0f;
    }

#pragma unroll
    for (int mt = 0; mt < 8; ++mt) {
      const int sbase = mt * 16;
      const uint2 pr = pc[sbase + (lane & 15)];
      const uint32_t b0 = (quad == 0) ? pr.x : 0u;
      const uint32_t b1 = (quad == 0) ? pr.y : 0u;
      const uint4 bq = make_uint4(b0, b1, 0u, 0u);
      half8 Bp; __builtin_memcpy(&Bp, &bq, 16);

      const f32x4 z4 = {0.f, 0.f, 0.f, 0.f};
      f32x4 ad0 = __builtin_amdgcn_mfma_f32_16x16x32_f16(FD0, Bp, z4, 0, 0, 0);
      f32x4 ad1 = __builtin_amdgcn_mfma_f32_16x16x32_f16(FD1, Bp, z4, 0, 0, 0);

      const uint4 qb2 = make_uint4(
          pk2h(fmaxf(ad0[0], 0.0f), fmaxf(ad0[1], 0.0f)),
          pk2h(fmaxf(ad0[2], 0.0f), fmaxf(ad0[3], 0.0f)),
          pk2h(fmaxf(ad1[0], 0.0f), fmaxf(ad1[1], 0.0f)),
          pk2h(fmaxf(ad1[2], 0.0f), fmaxf(ad1[3], 0.0f)));
      half8 B2; __builtin_memcpy(&B2, &qb2, 16);

      f32x4 aS = __builtin_amdgcn_mfma_f32_16x16x32_f16(FS, B2, sInit, 0, 0, 0);
      f32x4 ac0 = {dvv[0][0], dvv[0][1], dvv[0][2], dvv[0][3]};
      f32x4 ac1 = {dvv[1][0], dvv[1][1], dvv[1][2], dvv[1][3]};
      ac0 = __builtin_amdgcn_mfma_f32_16x16x32_f16(FC0, B2, ac0, 0, 0, 0);
      ac1 = __builtin_amdgcn_mfma_f32_16x16x32_f16(FC1, B2, ac1, 0, 0, 0);

      const uint4 qb3 = make_uint4(
          pk2h(fmaxf(ac0[0], 0.0f), fmaxf(ac0[1], 0.0f)),
          pk2h(fmaxf(ac0[2], 0.0f), fmaxf(ac0[3], 0.0f)),
          pk2h(fmaxf(ac1[0], 0.0f), fmaxf(ac1[1], 0.0f)),
          pk2h(fmaxf(ac1[2], 0.0f), fmaxf(ac1[3], 0.0f)));
      half8 B3; __builtin_memcpy(&B3, &qb3, 16);

      f32x4 aC = __builtin_amdgcn_mfma_f32_16x16x32_f16(F2, B3, c2init, 0, 0, 0);

      if (quad == 0) {
        const int s = sbase + (lane & 15);
        float4 og;
        og.x = fast_rcp(1.0f + __expf(-aC[0]));
        og.y = fast_rcp(1.0f + __expf(-aC[1]));
        og.z = fast_rcp(1.0f + __expf(-aC[2]));
        og.w = aS[0];   // raw sigma rides in .w (one b128 write)
        *(float4*)(rx + 4 * s) = og;
      }
    }
  }
  lds_fence();   // rgba/sigma writes -> final reads (cross-lane)

  // ---- fine alpha + cumprod over 128 (2 segments + carry) ----
  const float4 rg0 = *(const float4*)(rx + 4 * lane);
  const float4 rg1 = *(const float4*)(rx + 4 * (lane + 64));
  const float sg0 = softplus_f(rg0.w);
  const float sg1 = softplus_f(rg1.w);
  const float dl0 = zlA[lane + 1] - zlfv[0];
  const float dl1 = (lane < 63) ? (zlA[lane + 65] - zlfv[1]) : 0.0f;
  const float vf0 = __expf(-sg0 * dl0);
  const float vf1 = __expf(-sg1 * dl1);
  float wf0, wf1;
  {
    const float f0 = dpp_scan_mul(vf0);
    const float cf = readlane_f(f0, 63);
    const float f1 = dpp_scan_mul(vf1);
    wf0 = (fast_rcp(vf0) - 1.0f) * f0 * 1.0f;
    wf1 = (fast_rcp(vf1) - 1.0f) * f1 * cf;
  }

  // ---- outputs ----
  float* o_img = out;
  float* o_w   = out + (size_t)n_rays * 3;
  float* o_z   = out + (size_t)n_rays * (3 + 128);
  float* o_inv = out + (size_t)n_rays * (3 + 256);

  o_w[(size_t)ray * 128 + lane]      = wf0;
  o_w[(size_t)ray * 128 + lane + 64] = wf1;
  o_z[(size_t)ray * 128 + lane]      = (zlfv[0] + 1.0f) * 0.5f;
  o_z[(size_t)ray * 128 + lane + 64] = (zlfv[1] + 1.0f) * 0.5f;

  float r0 = wf0 * rg0.x + wf1 * rg1.x;
  float r1 = wf0 * rg0.y + wf1 * rg1.y;
  float r2 = wf0 * rg0.z + wf1 * rg1.z;
  float r3 = wf0 + wf1;
  float r4 = wf0 * fast_rcp(zfv[0]) + wf1 * fast_rcp(zfv[1]);
  r0 = dpp_scan_add(r0);
  r1 = dpp_scan_add(r1);
  r2 = dpp_scan_add(r2);
  r3 = dpp_scan_add(r3);
  r4 = dpp_scan_add(r4);
  if (lane == 63) {
    const float bgw = 1.0f - r3;
    o_img[(size_t)ray * 3 + 0] = r0 + bgw * bg[0];
    o_img[(size_t)ray * 3 + 1] = r1 + bgw * bg[1];
    o_img[(size_t)ray * 3 + 2] = r2 + bgw * bg[2];
    o_inv[ray] = r4;
  }
}

extern "C" void kernel_launch(void* const* d_in, const int* in_sizes, int n_in,
                              void* d_out, int out_size, void* d_ws, size_t ws_size,
                              hipStream_t stream) {
  const float* h   = (const float*)d_in[1];
  const float* w   = (const float*)d_in[2];
  const float* K   = (const float*)d_in[3];
  const float* E   = (const float*)d_in[4];
  const float* bg  = (const float*)d_in[5];
  const float* Wd1 = (const float*)d_in[6];
  const float* bd1 = (const float*)d_in[7];
  const float* Wd2 = (const float*)d_in[8];
  const float* bd2 = (const float*)d_in[9];
  const float* Wc1 = (const float*)d_in[10];
  const float* bc1 = (const float*)d_in[11];
  const float* Wc2 = (const float*)d_in[12];
  const float* bc2 = (const float*)d_in[13];
  const int n_rays = in_sizes[1];
  float* wsf = (float*)d_ws;
  const int nblk = (n_rays + 1) / 2;

  if (ws_size >= WS_NEED) {
    pack_weights<<<1, PACK_NT, 0, stream>>>(K, Wd1, bd1, Wd2, bd2, Wc1, bc1, Wc2, bc2, wsf);
    nerf_fwd<true><<<nblk, NT, 0, stream>>>(h, w, K, E, bg, Wd1, bd1, Wd2, bd2,
                                            Wc1, bc1, Wc2, bc2, wsf,
                                            (float*)d_out, n_rays);
  } else {
    nerf_fwd<false><<<nblk, NT, 0, stream>>>(h, w, K, E, bg, Wd1, bd1, Wd2, bd2,
                                             Wc1, bc1, Wc2, bc2, nullptr,
                                             (float*)d_out, n_rays);
  }
}